// Round 9
// baseline (565.170 us; speedup 1.0000x reference)
//
#include <hip/hip_runtime.h>
#include <hip/hip_bf16.h>

#define B_   2
#define C_   64
#define H_   48
#define W_   48
#define N_   (H_*W_)     // 2304
#define NH_  8
#define HD_  8
#define EPS_ 1e-5f
#define S2_  0.125f      // scale^2 = 1/hd
#define LOG2E_ 1.44269504f
#define FS_  (S2_ * LOG2E_)
#define S_   ((size_t)B_ * C_ * N_)   // 294912 floats per workspace slot
#define CN_  ((size_t)C_ * N_)        // 147456 floats per image
#define ROWP_ 52                      // padded LDS row: 48 data + 4 zeros
#define BUFSZ_ 336                    // 6*52=312 + slack for idle-lane reads

typedef unsigned short u16;
typedef __attribute__((ext_vector_type(8))) short short8v;
typedef __attribute__((ext_vector_type(4))) float f32x4;
union F8 { uint4 u4; short8v s; unsigned int w[4]; };

__device__ __forceinline__ float wsum64(float v) {
#pragma unroll
  for (int o = 32; o > 0; o >>= 1) v += __shfl_xor(v, o, 64);
  return v;
}

__device__ __forceinline__ float ln_val(float t, float g, float b) {
  float mu  = wsum64(t) * (1.0f / 64.0f);
  float d   = t - mu;
  float var = wsum64(d * d) * (1.0f / 64.0f);
  return d * rsqrtf(var + EPS_) * g + b;
}

// round-to-nearest-even f32 -> bf16 (finite inputs only)
__device__ __forceinline__ u16 f2bf(float x) {
  union { float f; unsigned int u; } a; a.f = x;
  unsigned int r = a.u + 0x7fffu + ((a.u >> 16) & 1u);
  return (u16)(r >> 16);
}

// lane c gets lane c-1's value within 16-lane group; c==0 -> 0.0f
__device__ __forceinline__ float dpp_shr1(float v) {
  int i = __builtin_bit_cast(int, v);
  int o = __builtin_amdgcn_update_dpp(0, i, 0x111, 0xf, 0xf, true);
  return __builtin_bit_cast(float, o);
}
// lane c gets lane c+1's value within 16-lane group; c==15 -> 0.0f
__device__ __forceinline__ float dpp_shl1(float v) {
  int i = __builtin_bit_cast(int, v);
  int o = __builtin_amdgcn_update_dpp(0, i, 0x101, 0xf, 0xf, true);
  return __builtin_bit_cast(float, o);
}

// ---- fused 1x1 pconv + BN + 3x LayerNorm; v2: 16 rows/block, LDS pw^T ----
__global__ __launch_bounds__(1024) void k_pre(
    const float* __restrict__ x, const float* __restrict__ y,
    const float* __restrict__ pw, const float* __restrict__ pb,
    const float* g, const float* bb, const float* m, const float* v,
    const float* lnxg, const float* lnxb,
    const float* lnyg, const float* lnyb,
    const float* lnzg, const float* lnzb,
    float* __restrict__ xl, float* __restrict__ yl, float* __restrict__ zl) {
  __shared__ float4 pwT[32][64];           // pwT[i4][c] = pw[c][4*i4..+3]
  __shared__ float xs[16][64], ys[16][64];
  int w = threadIdx.x >> 6, c = threadIdx.x & 63;
  for (int idx = threadIdx.x; idx < 2048; idx += 1024) {
    int cc = idx & 63, i4 = idx >> 6;
    pwT[i4][cc] = *(const float4*)(pw + (size_t)cc * 2 * C_ + i4 * 4);
  }
  int row = blockIdx.x * 16 + w;           // b*N + n
  int b = row / N_, n = row % N_;
  float xv = x[(size_t)(b * C_ + c) * N_ + n];
  float yv = y[(size_t)(b * C_ + c) * N_ + n];
  xs[w][c] = xv; ys[w][c] = yv;
  __syncthreads();
  const float4* xw = (const float4*)xs[w];
  const float4* yw = (const float4*)ys[w];
  float acc = pb[c];
#pragma unroll
  for (int t = 0; t < 16; ++t) {
    float4 a = xw[t], wv = pwT[t][c];
    acc += a.x * wv.x + a.y * wv.y + a.z * wv.z + a.w * wv.w;
  }
#pragma unroll
  for (int t = 0; t < 16; ++t) {
    float4 a = yw[t], wv = pwT[16 + t][c];
    acc += a.x * wv.x + a.y * wv.y + a.z * wv.z + a.w * wv.w;
  }
  float s  = g[c] * rsqrtf(v[c] + EPS_);
  float sh = bb[c] - m[c] * s;
  float tx = xv * s + sh;
  xl[(size_t)row * C_ + c] = ln_val(tx, lnxg[c], lnxb[c]);
  float ty = yv * s + sh;
  yl[(size_t)row * C_ + c] = ln_val(ty, lnyg[c], lnyb[c]);
  float tz = acc * s + sh;
  zl[(size_t)row * C_ + c] = ln_val(tz, lnzg[c], lnzb[c]);
}

// ------------- qv/k projection v2: lane = row, uniform weights ------------
__global__ __launch_bounds__(64) void k_qvk(
    const float* __restrict__ xl, const float* __restrict__ yl,
    const float* __restrict__ zl,
    const float* __restrict__ qvw, const float* __restrict__ qvb,
    const float* __restrict__ kw, const float* __restrict__ kb,
    u16* __restrict__ qxb, u16* __restrict__ qyb,
    u16* __restrict__ kbf, u16* __restrict__ vt) {
  int l = threadIdx.x;
  int part = blockIdx.y >> 2;
  int j0 = (blockIdx.y & 3) * 16;
  int row = blockIdx.x * 64 + l;
  int b = row / N_, n = row % N_;
  const float* inp = (part < 2) ? xl : (part < 4) ? yl : zl;
  float4 in[16];
  const float4* ir = (const float4*)(inp + (size_t)row * C_);
#pragma unroll
  for (int t = 0; t < 16; ++t) in[t] = ir[t];

  const float* wb   = (part == 4) ? kw : qvw;
  const float* bias = (part == 4) ? kb : qvb;
  int joff = (part == 1 || part == 3) ? 64 : 0;

  if (part == 1 || part == 3) {
    int vbase = (part == 1) ? 0 : 8;
#pragma unroll
    for (int jj = 0; jj < 16; ++jj) {
      int j = j0 + jj;
      const float4* wr = (const float4*)(wb + (size_t)(joff + j) * C_);
      float acc = bias[joff + j];
#pragma unroll
      for (int t = 0; t < 16; ++t) {
        float4 a = in[t], wv = wr[t];
        acc += a.x * wv.x + a.y * wv.y + a.z * wv.z + a.w * wv.w;
      }
      int h = j >> 3, d = j & 7;
      vt[((size_t)((b * NH_ + h) * 16 + vbase + d)) * N_ + n] = f2bf(acc);
    }
  } else {
    u16* dst = (part == 0) ? qxb : (part == 2) ? qyb : kbf;
#pragma unroll
    for (int gg = 0; gg < 2; ++gg) {
      int h = (j0 >> 3) + gg;
      union { uint4 u4; u16 s[8]; } pk;
#pragma unroll
      for (int d = 0; d < 8; ++d) {
        int j = h * 8 + d;
        const float4* wr = (const float4*)(wb + (size_t)(joff + j) * C_);
        float acc = bias[joff + j];
#pragma unroll
        for (int t = 0; t < 16; ++t) {
          float4 a = in[t], wv = wr[t];
          acc += a.x * wv.x + a.y * wv.y + a.z * wv.z + a.w * wv.w;
        }
        if (part == 0) acc *= FS_;
        pk.s[d] = f2bf(acc);
      }
      *(uint4*)(dst + ((size_t)(b * NH_ + h) * N_ + n) * 8) = pk.u4;
    }
  }
}

// ---------------- attention v8: MFMA flash, 16-q tile, dual-branch --------
__global__ __launch_bounds__(128, 5) void k_attn8(
    const u16* __restrict__ qx, const u16* __restrict__ qy,
    const u16* __restrict__ kk, const u16* __restrict__ vt,
    float* __restrict__ outx, float* __restrict__ outy) {
  __shared__ float sAcc[2][4][64];
  __shared__ float sL[2][16];
  int qt = blockIdx.x, bh = blockIdx.y;
  int tid = threadIdx.x;
  int lane = tid & 63;
  int wave = tid >> 6;
  int l15 = lane & 15;
  int q0 = qt * 16;

  F8 qxf, qyf;
  size_t qoff = ((size_t)bh * N_ + q0 + l15) * 8;
  qxf.u4 = *(const uint4*)(qx + qoff);
  qyf.u4 = *(const uint4*)(qy + qoff);
  if (lane >= 16) {
    qxf.u4 = make_uint4(0u, 0u, 0u, 0u);
    qyf.u4 = make_uint4(0u, 0u, 0u, 0u);
  }

  int key0 = wave * (N_ / 2);
  const uint4* kp = (const uint4*)(kk + (size_t)bh * N_ * 8) + key0 + l15;
  const uint4* vp = (const uint4*)(vt + ((size_t)bh * 16 + l15) * N_ + key0)
                    + (lane >> 4);
  int addr0 = (((lane >> 4) & 1) * 32 + l15) * 4;
  int addr1 = addr0 + 64;
  int thi = lane >> 5;

  f32x4 acc = {0.f, 0.f, 0.f, 0.f};
  const f32x4 z4 = {0.f, 0.f, 0.f, 0.f};
  float lsum = 0.f;

  F8 ka, kb2, vf;
  ka.u4 = kp[0]; kb2.u4 = kp[16]; vf.u4 = *vp;
  for (int c = 0; c < 36; ++c) {
    F8 kaC = ka, kbC = kb2, vfC = vf;
    kp += 32; vp += 4;
    ka.u4 = kp[0]; kb2.u4 = kp[16]; vf.u4 = *vp;   // prefetch next chunk

    f32x4 s1a = __builtin_amdgcn_mfma_f32_16x16x32_bf16(kaC.s, qxf.s, z4, 0, 0, 0);
    f32x4 s2a = __builtin_amdgcn_mfma_f32_16x16x32_bf16(kaC.s, qyf.s, z4, 0, 0, 0);
    f32x4 s1b = __builtin_amdgcn_mfma_f32_16x16x32_bf16(kbC.s, qxf.s, z4, 0, 0, 0);
    f32x4 s2b = __builtin_amdgcn_mfma_f32_16x16x32_bf16(kbC.s, qyf.s, z4, 0, 0, 0);

    float p00 = exp2f(s1a[0] * s2a[0]), p01 = exp2f(s1a[1] * s2a[1]);
    float p02 = exp2f(s1a[2] * s2a[2]), p03 = exp2f(s1a[3] * s2a[3]);
    float p10 = exp2f(s1b[0] * s2b[0]), p11 = exp2f(s1b[1] * s2b[1]);
    float p12 = exp2f(s1b[2] * s2b[2]), p13 = exp2f(s1b[3] * s2b[3]);
    lsum += ((p00 + p01) + (p02 + p03)) + ((p10 + p11) + (p12 + p13));

    unsigned int pk00, pk10, pk01, pk11;
    asm("v_cvt_pk_bf16_f32 %0, %1, %2" : "=v"(pk00) : "v"(p00), "v"(p01));
    asm("v_cvt_pk_bf16_f32 %0, %1, %2" : "=v"(pk10) : "v"(p02), "v"(p03));
    asm("v_cvt_pk_bf16_f32 %0, %1, %2" : "=v"(pk01) : "v"(p10), "v"(p11));
    asm("v_cvt_pk_bf16_f32 %0, %1, %2" : "=v"(pk11) : "v"(p12), "v"(p13));

    int b00 = __builtin_amdgcn_ds_bpermute(addr0, (int)pk00);
    int b01 = __builtin_amdgcn_ds_bpermute(addr0, (int)pk01);
    int b10 = __builtin_amdgcn_ds_bpermute(addr0, (int)pk10);
    int b11 = __builtin_amdgcn_ds_bpermute(addr0, (int)pk11);
    int c00 = __builtin_amdgcn_ds_bpermute(addr1, (int)pk00);
    int c01 = __builtin_amdgcn_ds_bpermute(addr1, (int)pk01);
    int c10 = __builtin_amdgcn_ds_bpermute(addr1, (int)pk10);
    int c11 = __builtin_amdgcn_ds_bpermute(addr1, (int)pk11);

    F8 pf;
    pf.w[0] = (unsigned int)(thi ? b01 : b00);
    pf.w[1] = (unsigned int)(thi ? b11 : b10);
    pf.w[2] = (unsigned int)(thi ? c01 : c00);
    pf.w[3] = (unsigned int)(thi ? c11 : c10);
    acc = __builtin_amdgcn_mfma_f32_16x16x32_bf16(pf.s, vfC.s, acc, 0, 0, 0);
  }

  lsum += __shfl_xor(lsum, 16, 64);
  lsum += __shfl_xor(lsum, 32, 64);
  if (lane < 16) sL[wave][lane] = lsum;
#pragma unroll
  for (int r = 0; r < 4; ++r) sAcc[wave][r][lane] = acc[r];
  __syncthreads();
  if (wave == 0) {
    float Linv = 1.f / (sL[0][l15] + sL[1][l15]);
    int b = bh >> 3, h = bh & 7;
    int d = l15 & 7;
    float* ob = (l15 < 8) ? outx : outy;
    size_t cbase = (size_t)b * N_ * C_ + (size_t)h * 8 + d;
#pragma unroll
    for (int r = 0; r < 4; ++r) {
      int qrow = 4 * (lane >> 4) + r;
      float li = __shfl(Linv, qrow, 64);
      float a = sAcc[0][r][lane] + sAcc[1][r][lane];
      ob[cbase + (size_t)(q0 + qrow) * C_] = a * li;
    }
  }
}

// -------- proj v2: 2 couts + 2 px per thread (att rows shared) ------------
__global__ __launch_bounds__(64) void k_proj2(
    const float* __restrict__ attbase,
    const float* __restrict__ x, const float* __restrict__ y,
    const float* bg, const float* bb2, const float* bm, const float* bv,
    const float* __restrict__ pw, const float* __restrict__ pbias,
    float* __restrict__ outbase) {
  int p = blockIdx.x * 128 + threadIdx.x * 2;
  int c0 = blockIdx.y * 2;
  int z = blockIdx.z;
  int branch = z >> 1, b = z & 1;
  const float* att = attbase + branch * S_ + (size_t)b * N_ * C_;
  const float4* w0 = (const float4*)(pw + (size_t)c0 * C_);
  const float4* w1 = (const float4*)(pw + (size_t)(c0 + 1) * C_);
  const float4* ar0 = (const float4*)(att + (size_t)p * C_);
  const float4* ar1 = (const float4*)(att + (size_t)(p + 1) * C_);
  float bias0 = pbias[c0], bias1 = pbias[c0 + 1];
  float a00 = bias0, a01 = bias0, a10 = bias1, a11 = bias1;
#pragma unroll
  for (int t = 0; t < 16; ++t) {
    float4 v0 = ar0[t], v1 = ar1[t];
    float4 u = w0[t], w = w1[t];
    a00 += v0.x*u.x + v0.y*u.y + v0.z*u.z + v0.w*u.w;
    a01 += v1.x*u.x + v1.y*u.y + v1.z*u.z + v1.w*u.w;
    a10 += v0.x*w.x + v0.y*w.y + v0.z*w.z + v0.w*w.w;
    a11 += v1.x*w.x + v1.y*w.y + v1.z*w.z + v1.w*w.w;
  }
  float s0  = bg[c0] * rsqrtf(bv[c0] + EPS_);
  float sh0 = bb2[c0] - bm[c0] * s0;
  float s1  = bg[c0+1] * rsqrtf(bv[c0+1] + EPS_);
  float sh1 = bb2[c0+1] - bm[c0+1] * s1;
  const float* xin = branch ? y : x;
  float2 r0 = *(const float2*)(xin + ((size_t)b * C_ + c0) * N_ + p);
  float2 r1 = *(const float2*)(xin + ((size_t)b * C_ + c0 + 1) * N_ + p);
  size_t o = (size_t)z * CN_ + (size_t)c0 * N_ + p;
  *(float2*)(outbase + o)      = make_float2(a00 + r0.x * s0 + sh0,
                                             a01 + r0.y * s0 + sh0);
  *(float2*)(outbase + o + N_) = make_float2(a10 + r1.x * s1 + sh1,
                                             a11 + r1.y * s1 + sh1);
}

// ===== conv core v7: v5 DPP-edge core extended to 4 couts/wave ============
// 1 wave/block. Lane = g*16+c: image row = tile*4+g, x0 = 4c, active c<12.
// Strip = 6 rows (4 + halo) in LDS, rows padded to 52 (cols 48..51 = 0).
// l/r via DPP from neighbor lanes (row_shr/row_shl, bound_ctrl zeros).
// Per ci: 3x ds_read_b128 + ~1.1 staged writes; zero edge LDS reads.
// Weights wave-uniform (scalar pipe), dbuf'd; input global->reg->LDS dbuf.
template<int CIPB, int WST>    // WST = CIN*9 floats per cout
__device__ __forceinline__ void conv_core7(
    const float* __restrict__ ib, const float* __restrict__ wr,
    int tile, int tid, float (*bufs)[BUFSZ_], float4* A) {
  int g = tid >> 4, c = tid & 15;
  // staging roles: chunk = srow*12+scol; thread t -> chunk t, +chunk 64+t (t<8)
  int sr0 = tid / 12, sc0 = tid - sr0 * 12;
  int gy0 = tile * 4 - 1 + sr0;
  bool v0 = (unsigned)gy0 < (unsigned)H_;
  int go0 = gy0 * W_ + sc0 * 4;
  int lo0 = sr0 * ROWP_ + sc0 * 4;
  int t1 = 64 + tid;
  int sr1 = t1 / 12, sc1 = t1 - sr1 * 12;
  int gy1 = tile * 4 - 1 + sr1;
  bool v1 = (tid < 8) && ((unsigned)gy1 < (unsigned)H_);
  int go1 = gy1 * W_ + sc1 * 4;
  int lo1 = sr1 * ROWP_ + sc1 * 4;
  const float4 zz = make_float4(0.f, 0.f, 0.f, 0.f);

  // zero the pad columns (once, both buffers)
  if (tid < 12) {
    int bi = tid / 6, sr = tid % 6;
    *(float4*)(&bufs[bi][sr * ROWP_ + 48]) = zz;
  }
  // prologue: stage ci=0 into buf0; preload ci=1 into regs
  {
    *(float4*)(&bufs[0][lo0]) = v0 ? *(const float4*)(ib + go0) : zz;
    if (tid < 8)
      *(float4*)(&bufs[0][lo1]) = v1 ? *(const float4*)(ib + go1) : zz;
  }
  float4 ra, rb;
  if (CIPB > 1) {
    ra = v0 ? *(const float4*)(ib + N_ + go0) : zz;
    if (tid < 8) rb = v1 ? *(const float4*)(ib + N_ + go1) : zz;
  }
  float wc[36], wn[36];
#pragma unroll
  for (int j = 0; j < 4; ++j)
#pragma unroll
    for (int i = 0; i < 9; ++i) wc[j * 9 + i] = wr[(size_t)j * WST + i];

  int rdbase = g * ROWP_ + 4 * c;   // ky adds ROWP_ each step

#pragma unroll 2
  for (int ci = 0; ci < CIPB; ++ci) {
    if (ci + 1 < CIPB) {
      // write staged regs for ci+1 into the other buffer
      *(float4*)(&bufs[(ci + 1) & 1][lo0]) = ra;
      if (tid < 8) *(float4*)(&bufs[(ci + 1) & 1][lo1]) = rb;
#pragma unroll
      for (int j = 0; j < 4; ++j)
#pragma unroll
        for (int i = 0; i < 9; ++i)
          wn[j * 9 + i] = wr[(size_t)j * WST + (ci + 1) * 9 + i];
    }
    if (ci + 2 < CIPB) {
      const float* s = ib + (size_t)(ci + 2) * N_;
      ra = v0 ? *(const float4*)(s + go0) : zz;
      if (tid < 8) rb = v1 ? *(const float4*)(s + go1) : zz;
    }
    const float* bc = bufs[ci & 1];
#pragma unroll
    for (int ky = 0; ky < 3; ++ky) {
      float4 mid = *(const float4*)(bc + rdbase + ky * ROWP_);
      float l = dpp_shr1(mid.w);
      float r = dpp_shl1(mid.x);
#pragma unroll
      for (int j = 0; j < 4; ++j) {
        float u0 = wc[j * 9 + ky * 3];
        float u1 = wc[j * 9 + ky * 3 + 1];
        float u2 = wc[j * 9 + ky * 3 + 2];
        A[j].x += l     * u0 + mid.x * u1 + mid.y * u2;
        A[j].y += mid.x * u0 + mid.y * u1 + mid.z * u2;
        A[j].z += mid.y * u0 + mid.z * u1 + mid.w * u2;
        A[j].w += mid.z * u0 + mid.w * u1 + r     * u2;
      }
    }
    if (ci + 1 < CIPB) {
#pragma unroll
      for (int i = 0; i < 36; ++i) wc[i] = wn[i];
    }
  }
}

// ------ 64-cin conv RAW partial: 1 wave, 4-row tile, 4 couts --------------
// grid (12, C_/4, 8). z: img = z&3 (layout img*CN), half = z>>2.
__global__ __launch_bounds__(64) void k_convs(
    const float* __restrict__ inA, const float* __restrict__ inB,
    const float* __restrict__ w,
    float* __restrict__ pA, float* __restrict__ pB) {
  __shared__ float bufs[2][BUFSZ_];
  int tid = threadIdx.x;
  int tile = blockIdx.x;
  int c0 = blockIdx.y * 4;
  int z = blockIdx.z;
  int img = z & 3, half = z >> 2;
  int ci0 = half * (C_ / 2);
  const float* ib = ((img < 2) ? inA + (size_t)img * CN_
                               : inB + (size_t)(img - 2) * CN_)
                    + (size_t)ci0 * N_;
  const float* wr = w + ((size_t)c0 * C_ + ci0) * 9;
  float4 A[4];
#pragma unroll
  for (int j = 0; j < 4; ++j) A[j] = make_float4(0.f, 0.f, 0.f, 0.f);
  conv_core7<C_/2, C_*9>(ib, wr, tile, tid, bufs, A);
  int g = tid >> 4, c = tid & 15;
  if (c < 12) {
    int p = (tile * 4 + g) * W_ + 4 * c;
    float* ob = (half ? pB : pA) + (size_t)img * CN_ + (size_t)c0 * N_ + p;
#pragma unroll
    for (int j = 0; j < 4; ++j) *(float4*)(ob + (size_t)j * N_) = A[j];
  }
}

// ------ combine halves + bias + bn + relu (conv1 epilogue) ----------------
__global__ void k_combp(const float* __restrict__ pA, const float* __restrict__ pB,
                        const float* __restrict__ cb,
                        const float* __restrict__ g, const float* __restrict__ b2,
                        const float* __restrict__ m, const float* __restrict__ v,
                        float* __restrict__ tA, float* __restrict__ tB) {
  int t = blockIdx.x * 256 + threadIdx.x;
  int p4 = t * 4;
  int n = p4 % N_;
  int c = (p4 / N_) % C_;
  int img = p4 / (int)CN_;
  size_t off = (size_t)img * CN_ + (size_t)c * N_ + n;
  float4 a = *(const float4*)(pA + off);
  float4 d = *(const float4*)(pB + off);
  float s  = g[c] * rsqrtf(v[c] + EPS_);
  float sh = b2[c] - m[c] * s;
  float bias = cb[c];
  float4 r;
  r.x = fmaxf((a.x + d.x + bias) * s + sh, 0.f);
  r.y = fmaxf((a.y + d.y + bias) * s + sh, 0.f);
  r.z = fmaxf((a.z + d.z + bias) * s + sh, 0.f);
  r.w = fmaxf((a.w + d.w + bias) * s + sh, 0.f);
  float* ob = (img < 2) ? tA + off : tB + off - 2 * CN_;
  *(float4*)ob = r;
}

// ------ combine halves + bias + bn + relu + resid (conv2 epilogue) --------
__global__ void k_comb2(float* __restrict__ pA, const float* __restrict__ pB,
                        const float* __restrict__ cb,
                        const float* __restrict__ g, const float* __restrict__ b2,
                        const float* __restrict__ m, const float* __restrict__ v,
                        const float* __restrict__ resid) {
  int t = blockIdx.x * 256 + threadIdx.x;
  int p4 = t * 4;
  int n = p4 % N_;
  int c = (p4 / N_) % C_;
  int img = p4 / (int)CN_;
  size_t off = (size_t)img * CN_ + (size_t)c * N_ + n;
  float4 a = *(const float4*)(pA + off);
  float4 d = *(const float4*)(pB + off);
  float4 rr = *(const float4*)(resid + off);
  float s  = g[c] * rsqrtf(v[c] + EPS_);
  float sh = b2[c] - m[c] * s;
  float bias = cb[c];
  float4 r;
  r.x = fmaxf((a.x + d.x + bias) * s + sh, 0.f) + rr.x;
  r.y = fmaxf((a.y + d.y + bias) * s + sh, 0.f) + rr.y;
  r.z = fmaxf((a.z + d.z + bias) * s + sh, 0.f) + rr.z;
  r.w = fmaxf((a.w + d.w + bias) * s + sh, 0.f) + rr.w;
  *(float4*)(pA + off) = r;
}

// ------ cat = [xo+yo ; xo*yo] + bn2 -> fin, float4 ------------------------
__global__ void k_catbn(const float* __restrict__ o2,
                        const float* __restrict__ g, const float* __restrict__ b2,
                        const float* __restrict__ m, const float* __restrict__ v,
                        float* __restrict__ cat, float* __restrict__ fin,
                        size_t finStride) {
  int t = blockIdx.x * 256 + threadIdx.x;
  int p4 = t * 4;
  int n  = p4 % N_;
  int c2 = (p4 / N_) % (2 * C_);
  int b  = p4 / (2 * C_ * N_);
  int c  = c2 & 63;
  float4 X = *(const float4*)(o2 + (size_t)b * CN_ + (size_t)c * N_ + n);
  float4 Y = *(const float4*)(o2 + (size_t)(2 + b) * CN_ + (size_t)c * N_ + n);
  float4 val;
  if (c2 < C_) val = make_float4(X.x + Y.x, X.y + Y.y, X.z + Y.z, X.w + Y.w);
  else         val = make_float4(X.x * Y.x, X.y * Y.y, X.z * Y.z, X.w * Y.w);
  size_t co = ((size_t)b * 2 * C_ + c2) * N_ + n;
  *(float4*)(cat + co) = val;
  float s  = g[c2] * rsqrtf(v[c2] + EPS_);
  float sh = b2[c2] - m[c2] * s;
  *(float4*)(fin + (size_t)b * finStride + (size_t)c2 * N_ + n) =
      make_float4(val.x * s + sh, val.y * s + sh, val.z * s + sh, val.w * s + sh);
}

// ------ f-branch 3x3 conv partial: 1 wave, 4-row tile, 4 couts ------------
// grid (12, 2C/4, 4). z: b = z&1, half = z>>1.
__global__ __launch_bounds__(64) void k_fconvs(
    const float* __restrict__ in, size_t inStride,
    const float* __restrict__ w,
    float* __restrict__ outA, size_t outStrideA,
    float* __restrict__ outB, size_t outStrideB) {
  __shared__ float bufs[2][BUFSZ_];
  int tid = threadIdx.x;
  int tile = blockIdx.x;
  int c0 = blockIdx.y * 4;
  int z = blockIdx.z;
  int b = z & 1, half = z >> 1;
  int ci0 = half * C_;
  const float* ib = in + (size_t)b * inStride + (size_t)ci0 * N_;
  const float* wr = w + ((size_t)c0 * (2 * C_) + ci0) * 9;
  float4 A[4];
#pragma unroll
  for (int j = 0; j < 4; ++j) A[j] = make_float4(0.f, 0.f, 0.f, 0.f);
  conv_core7<C_, 2*C_*9>(ib, wr, tile, tid, bufs, A);
  int g = tid >> 4, c = tid & 15;
  if (c < 12) {
    int p = (tile * 4 + g) * W_ + 4 * c;
    float* ob = (half ? outB + (size_t)b * outStrideB
                      : outA + (size_t)b * outStrideA)
                + (size_t)c0 * N_ + p;
#pragma unroll
    for (int j = 0; j < 4; ++j) *(float4*)(ob + (size_t)j * N_) = A[j];
  }
}

// ------ combine halves + bn + relu, float4 (in-place into A ok) -----------
__global__ void k_comb(const float* __restrict__ pA, size_t strideA,
                       const float* __restrict__ pB, size_t strideB,
                       const float* __restrict__ g, const float* __restrict__ b2,
                       const float* __restrict__ m, const float* __restrict__ v,
                       float* __restrict__ out, size_t outStride) {
  int t = blockIdx.x * 256 + threadIdx.x;
  int p4 = t * 4;
  int n = p4 % N_;
  int c = (p4 / N_) % (2 * C_);
  int b = p4 / (2 * C_ * N_);
  size_t off = (size_t)c * N_ + n;
  float4 a = *(const float4*)(pA + (size_t)b * strideA + off);
  float4 d = *(const float4*)(pB + (size_t)b * strideB + off);
  float s  = g[c] * rsqrtf(v[c] + EPS_);
  float sh = b2[c] - m[c] * s;
  float4 r;
  r.x = fmaxf((a.x + d.x) * s + sh, 0.f);
  r.y = fmaxf((a.y + d.y) * s + sh, 0.f);
  r.z = fmaxf((a.z + d.z) * s + sh, 0.f);
  r.w = fmaxf((a.w + d.w) * s + sh, 0.f);
  *(float4*)(out + (size_t)b * outStride + off) = r;
}

// -------- final v2: 2 couts/block, fused comb(fbn2)+relu + cat add --------
__global__ __launch_bounds__(64) void k_final3(
    const float* __restrict__ pA, size_t strideA,
    const float* __restrict__ pB, size_t strideB,
    const float* __restrict__ g2, const float* __restrict__ b2,
    const float* __restrict__ m2, const float* __restrict__ v2,
    const float* __restrict__ cat,
    const float* __restrict__ w, const float* __restrict__ fb,
    float* __restrict__ out) {
  __shared__ float fsc[2 * C_], fsh[2 * C_];
  for (int j = threadIdx.x; j < 2 * C_; j += 64) {
    float s = g2[j] * rsqrtf(v2[j] + EPS_);
    fsc[j] = s;
    fsh[j] = b2[j] - m2[j] * s;
  }
  __syncthreads();
  int p = blockIdx.x * 128 + threadIdx.x * 2;
  int c0 = blockIdx.y * 2;
  int b = blockIdx.z;
  const float* frA = pA + (size_t)b * strideA;
  const float* frB = pB + (size_t)b * strideB;
  const float* wr0 = w + (size_t)c0 * 2 * C_;
  const float* wr1 = wr0 + 2 * C_;
  float a00 = fb[c0], a01 = a00;
  float a10 = fb[c0 + 1], a11 = a10;
#pragma unroll 4
  for (int j = 0; j < 2 * C_; ++j) {
    float2 fa = *(const float2*)(frA + (size_t)j * N_ + p);
    float2 fd = *(const float2*)(frB + (size_t)j * N_ + p);
    float s = fsc[j], sh = fsh[j];
    float f0 = fmaxf((fa.x + fd.x) * s + sh, 0.f);
    float f1 = fmaxf((fa.y + fd.y) * s + sh, 0.f);
    float wv0 = wr0[j], wv1 = wr1[j];
    a00 += wv0 * f0; a01 += wv0 * f1;
    a10 += wv1 * f0; a11 += wv1 * f1;
  }
  size_t o = ((size_t)b * 2 * C_ + c0) * N_ + p;
  float2 cv0 = *(const float2*)(cat + o);
  float2 cv1 = *(const float2*)(cat + o + N_);
  *(float2*)(out + o)      = make_float2(a00 + cv0.x, a01 + cv0.y);
  *(float2*)(out + o + N_) = make_float2(a10 + cv1.x, a11 + cv1.y);
}

extern "C" void kernel_launch(void* const* d_in, const int* in_sizes, int n_in,
                              void* d_out, int out_size, void* d_ws, size_t ws_size,
                              hipStream_t stream) {
  const float* x       = (const float*)d_in[0];
  const float* y       = (const float*)d_in[1];
  const float* pconv_w = (const float*)d_in[2];
  const float* pconv_b = (const float*)d_in[3];
  const float* bnd_g = (const float*)d_in[4];
  const float* bnd_b = (const float*)d_in[5];
  const float* bnd_m = (const float*)d_in[6];
  const float* bnd_v = (const float*)d_in[7];
  const float* lnx_g = (const float*)d_in[8];
  const float* lnx_b = (const float*)d_in[9];
  const float* lny_g = (const float*)d_in[10];
  const float* lny_b = (const float*)d_in[11];
  const float* lnz_g = (const float*)d_in[12];
  const float* lnz_b = (const float*)d_in[13];
  const float* k_w   = (const float*)d_in[14];
  const float* k_b   = (const float*)d_in[15];
  const float* qv_w  = (const float*)d_in[16];
  const float* qv_b  = (const float*)d_in[17];
  const float* proj_w = (const float*)d_in[18];
  const float* proj_b = (const float*)d_in[19];
  const float* c2w1  = (const float*)d_in[20];
  const float* c2b1  = (const float*)d_in[21];
  const float* c2bn1_g = (const float*)d_in[22];
  const float* c2bn1_b = (const float*)d_in[23];
  const float* c2bn1_m = (const float*)d_in[24];
  const float* c2bn1_v = (const float*)d_in[25];
  const float* c2w2  = (const float*)d_in[26];
  const float* c2b2  = (const float*)d_in[27];
  const float* c2bn2_g = (const float*)d_in[28];
  const float* c2bn2_b = (const float*)d_in[29];
  const float* c2bn2_m = (const float*)d_in[30];
  const float* c2bn2_v = (const float*)d_in[31];
  const float* bn2_g = (const float*)d_in[32];
  const float* bn2_b = (const float*)d_in[33];
  const float* bn2_m = (const float*)d_in[34];
  const float* bn2_v = (const float*)d_in[35];
  const float* f1w   = (const float*)d_in[36];
  const float* fbn1_g = (const float*)d_in[37];
  const float* fbn1_b = (const float*)d_in[38];
  const float* fbn1_m = (const float*)d_in[39];
  const float* fbn1_v = (const float*)d_in[40];
  const float* f2w   = (const float*)d_in[41];
  const float* fbn2_g = (const float*)d_in[42];
  const float* fbn2_b = (const float*)d_in[43];
  const float* fbn2_m = (const float*)d_in[44];
  const float* fbn2_v = (const float*)d_in[45];
  const float* f3w   = (const float*)d_in[46];
  const float* f3b   = (const float*)d_in[47];

  float* ws = (float*)d_ws;
  float* sl0 = ws + 0 * S_;
  float* sl1 = ws + 1 * S_;
  float* sl2 = ws + 2 * S_;
  float* sl3 = ws + 3 * S_;
  float* sl4 = ws + 4 * S_;
  float* sl5 = ws + 5 * S_;
  float* sl7 = ws + 7 * S_;

  // A. fused pconv + bn + ln (v2: 16 rows/block)
  k_pre<<<B_ * N_ / 16, 1024, 0, stream>>>(x, y, pconv_w, pconv_b,
                                    bnd_g, bnd_b, bnd_m, bnd_v,
                                    lnx_g, lnx_b, lny_g, lny_b, lnz_g, lnz_b,
                                    sl1, sl2, sl3);
  // B. qv/k projection v2 -> bf16 attention operands
  u16* qxb = (u16*)sl4;
  u16* qyb = qxb + (size_t)B_ * NH_ * N_ * 8;
  u16* kbf = (u16*)sl5;
  u16* vtb = (u16*)(ws + 6 * S_);
  {
    dim3 g(B_ * N_ / 64, 20);
    k_qvk<<<g, 64, 0, stream>>>(sl1, sl2, sl3, qv_w, qv_b, k_w, k_b,
                                qxb, qyb, kbf, vtb);
  }
  // C. attention v8 (MFMA) -> att_xo(1), att_yo(2)
  {
    dim3 g(N_ / 16, B_ * NH_);
    k_attn8<<<g, 128, 0, stream>>>(qxb, qyb, kbf, vtb, sl1, sl2);
  }
  // D. proj v2 (2 couts) -> xo4(3,4)
  {
    dim3 g(18, C_ / 2, 2 * B_);
    k_proj2<<<g, 64, 0, stream>>>(sl1, x, y, bnd_g, bnd_b, bnd_m, bnd_v,
                                  proj_w, proj_b, sl3);
  }
  // E. conv1 (v7: DPP core, 4 couts) + combine epilogue -> tmp(0 / 7)
  {
    dim3 g(12, C_ / 4, 8);
    k_convs<<<g, 64, 0, stream>>>(sl3, sl3 + 2 * CN_, c2w1, sl1, sl5);
    k_combp<<<576, 256, 0, stream>>>(sl1, sl5, c2b1,
        c2bn1_g, c2bn1_b, c2bn1_m, c2bn1_v, sl0, sl7);
  }
  // F. conv2 (v7) + combine(+resid) -> o2(1,2)
  {
    dim3 g(12, C_ / 4, 8);
    k_convs<<<g, 64, 0, stream>>>(sl0, sl7, c2w2, sl1, sl5);
    k_comb2<<<576, 256, 0, stream>>>(sl1, sl5, c2b2,
        c2bn2_g, c2bn2_b, c2bn2_m, c2bn2_v, sl3);
  }
  // G. cat + bn2 -> cat(3,4), fin(0 / 7)
  k_catbn<<<576, 256, 0, stream>>>(sl1, bn2_g, bn2_b, bn2_m, bn2_v,
                                   sl3, sl0, 7 * S_);
  // H. f-branch convs (v7), ci-split
  {
    dim3 g(12, 2 * C_ / 4, 4);
    k_fconvs<<<g, 64, 0, stream>>>(sl0, 7 * S_, f1w, sl1, S_, sl5, S_);
    k_comb<<<576, 256, 0, stream>>>(sl1, S_, sl5, S_,
                                    fbn1_g, fbn1_b, fbn1_m, fbn1_v, sl1, S_);
    k_fconvs<<<g, 64, 0, stream>>>(sl1, S_, f2w, sl5, S_, sl0, 7 * S_);
  }
  // I. final v2 (2 couts) -> fp32 out
  {
    dim3 g(18, C_, B_);
    k_final3<<<g, 64, 0, stream>>>(sl5, S_, sl0, 7 * S_,
                                   fbn2_g, fbn2_b, fbn2_m, fbn2_v,
                                   sl3, f3w, f3b, (float*)d_out);
  }
}

// Round 10
// 410.353 us; speedup vs baseline: 1.3773x; 1.3773x over previous
//
#include <hip/hip_runtime.h>
#include <hip/hip_bf16.h>

#define B_   2
#define C_   64
#define H_   48
#define W_   48
#define N_   (H_*W_)     // 2304
#define NH_  8
#define HD_  8
#define EPS_ 1e-5f
#define S2_  0.125f      // scale^2 = 1/hd
#define LOG2E_ 1.44269504f
#define FS_  (S2_ * LOG2E_)
#define S_   ((size_t)B_ * C_ * N_)   // 294912 floats per workspace slot
#define CN_  ((size_t)C_ * N_)        // 147456 floats per image

typedef unsigned short u16;
typedef __attribute__((ext_vector_type(8))) short short8v;
typedef __attribute__((ext_vector_type(4))) float f32x4;
union F8 { uint4 u4; short8v s; unsigned int w[4]; };

__device__ __forceinline__ float wsum64(float v) {
#pragma unroll
  for (int o = 32; o > 0; o >>= 1) v += __shfl_xor(v, o, 64);
  return v;
}

__device__ __forceinline__ float ln_val(float t, float g, float b) {
  float mu  = wsum64(t) * (1.0f / 64.0f);
  float d   = t - mu;
  float var = wsum64(d * d) * (1.0f / 64.0f);
  return d * rsqrtf(var + EPS_) * g + b;
}

// round-to-nearest-even f32 -> bf16 (finite inputs only)
__device__ __forceinline__ u16 f2bf(float x) {
  union { float f; unsigned int u; } a; a.f = x;
  unsigned int r = a.u + 0x7fffu + ((a.u >> 16) & 1u);
  return (u16)(r >> 16);
}

// ---- fused 1x1 pconv + BN + 3x LayerNorm; v2: 16 rows/block, LDS pw^T ----
__global__ __launch_bounds__(1024) void k_pre(
    const float* __restrict__ x, const float* __restrict__ y,
    const float* __restrict__ pw, const float* __restrict__ pb,
    const float* g, const float* bb, const float* m, const float* v,
    const float* lnxg, const float* lnxb,
    const float* lnyg, const float* lnyb,
    const float* lnzg, const float* lnzb,
    float* __restrict__ xl, float* __restrict__ yl, float* __restrict__ zl) {
  __shared__ float4 pwT[32][64];           // pwT[i4][c] = pw[c][4*i4..+3]
  __shared__ float xs[16][64], ys[16][64];
  int w = threadIdx.x >> 6, c = threadIdx.x & 63;
  for (int idx = threadIdx.x; idx < 2048; idx += 1024) {
    int cc = idx & 63, i4 = idx >> 6;
    pwT[i4][cc] = *(const float4*)(pw + (size_t)cc * 2 * C_ + i4 * 4);
  }
  int row = blockIdx.x * 16 + w;           // b*N + n
  int b = row / N_, n = row % N_;
  float xv = x[(size_t)(b * C_ + c) * N_ + n];
  float yv = y[(size_t)(b * C_ + c) * N_ + n];
  xs[w][c] = xv; ys[w][c] = yv;
  __syncthreads();
  const float4* xw = (const float4*)xs[w];
  const float4* yw = (const float4*)ys[w];
  float acc = pb[c];
#pragma unroll
  for (int t = 0; t < 16; ++t) {
    float4 a = xw[t], wv = pwT[t][c];
    acc += a.x * wv.x + a.y * wv.y + a.z * wv.z + a.w * wv.w;
  }
#pragma unroll
  for (int t = 0; t < 16; ++t) {
    float4 a = yw[t], wv = pwT[16 + t][c];
    acc += a.x * wv.x + a.y * wv.y + a.z * wv.z + a.w * wv.w;
  }
  float s  = g[c] * rsqrtf(v[c] + EPS_);
  float sh = bb[c] - m[c] * s;
  float tx = xv * s + sh;
  xl[(size_t)row * C_ + c] = ln_val(tx, lnxg[c], lnxb[c]);
  float ty = yv * s + sh;
  yl[(size_t)row * C_ + c] = ln_val(ty, lnyg[c], lnyb[c]);
  float tz = acc * s + sh;
  zl[(size_t)row * C_ + c] = ln_val(tz, lnzg[c], lnzb[c]);
}

// ------------- qv/k projection v2: lane = row, uniform weights ------------
__global__ __launch_bounds__(64) void k_qvk(
    const float* __restrict__ xl, const float* __restrict__ yl,
    const float* __restrict__ zl,
    const float* __restrict__ qvw, const float* __restrict__ qvb,
    const float* __restrict__ kw, const float* __restrict__ kb,
    u16* __restrict__ qxb, u16* __restrict__ qyb,
    u16* __restrict__ kbf, u16* __restrict__ vt) {
  int l = threadIdx.x;
  int part = blockIdx.y >> 2;
  int j0 = (blockIdx.y & 3) * 16;
  int row = blockIdx.x * 64 + l;
  int b = row / N_, n = row % N_;
  const float* inp = (part < 2) ? xl : (part < 4) ? yl : zl;
  float4 in[16];
  const float4* ir = (const float4*)(inp + (size_t)row * C_);
#pragma unroll
  for (int t = 0; t < 16; ++t) in[t] = ir[t];

  const float* wb   = (part == 4) ? kw : qvw;
  const float* bias = (part == 4) ? kb : qvb;
  int joff = (part == 1 || part == 3) ? 64 : 0;

  if (part == 1 || part == 3) {
    int vbase = (part == 1) ? 0 : 8;
#pragma unroll
    for (int jj = 0; jj < 16; ++jj) {
      int j = j0 + jj;
      const float4* wr = (const float4*)(wb + (size_t)(joff + j) * C_);
      float acc = bias[joff + j];
#pragma unroll
      for (int t = 0; t < 16; ++t) {
        float4 a = in[t], wv = wr[t];
        acc += a.x * wv.x + a.y * wv.y + a.z * wv.z + a.w * wv.w;
      }
      int h = j >> 3, d = j & 7;
      vt[((size_t)((b * NH_ + h) * 16 + vbase + d)) * N_ + n] = f2bf(acc);
    }
  } else {
    u16* dst = (part == 0) ? qxb : (part == 2) ? qyb : kbf;
#pragma unroll
    for (int gg = 0; gg < 2; ++gg) {
      int h = (j0 >> 3) + gg;
      union { uint4 u4; u16 s[8]; } pk;
#pragma unroll
      for (int d = 0; d < 8; ++d) {
        int j = h * 8 + d;
        const float4* wr = (const float4*)(wb + (size_t)(joff + j) * C_);
        float acc = bias[joff + j];
#pragma unroll
        for (int t = 0; t < 16; ++t) {
          float4 a = in[t], wv = wr[t];
          acc += a.x * wv.x + a.y * wv.y + a.z * wv.z + a.w * wv.w;
        }
        if (part == 0) acc *= FS_;
        pk.s[d] = f2bf(acc);
      }
      *(uint4*)(dst + ((size_t)(b * NH_ + h) * N_ + n) * 8) = pk.u4;
    }
  }
}

// ---------------- attention v8: MFMA flash, 16-q tile, dual-branch --------
__global__ __launch_bounds__(128, 5) void k_attn8(
    const u16* __restrict__ qx, const u16* __restrict__ qy,
    const u16* __restrict__ kk, const u16* __restrict__ vt,
    float* __restrict__ outx, float* __restrict__ outy) {
  __shared__ float sAcc[2][4][64];
  __shared__ float sL[2][16];
  int qt = blockIdx.x, bh = blockIdx.y;
  int tid = threadIdx.x;
  int lane = tid & 63;
  int wave = tid >> 6;
  int l15 = lane & 15;
  int q0 = qt * 16;

  F8 qxf, qyf;
  size_t qoff = ((size_t)bh * N_ + q0 + l15) * 8;
  qxf.u4 = *(const uint4*)(qx + qoff);
  qyf.u4 = *(const uint4*)(qy + qoff);
  if (lane >= 16) {
    qxf.u4 = make_uint4(0u, 0u, 0u, 0u);
    qyf.u4 = make_uint4(0u, 0u, 0u, 0u);
  }

  int key0 = wave * (N_ / 2);
  const uint4* kp = (const uint4*)(kk + (size_t)bh * N_ * 8) + key0 + l15;
  const uint4* vp = (const uint4*)(vt + ((size_t)bh * 16 + l15) * N_ + key0)
                    + (lane >> 4);
  int addr0 = (((lane >> 4) & 1) * 32 + l15) * 4;
  int addr1 = addr0 + 64;
  int thi = lane >> 5;

  f32x4 acc = {0.f, 0.f, 0.f, 0.f};
  const f32x4 z4 = {0.f, 0.f, 0.f, 0.f};
  float lsum = 0.f;

  F8 ka, kb2, vf;
  ka.u4 = kp[0]; kb2.u4 = kp[16]; vf.u4 = *vp;
  for (int c = 0; c < 36; ++c) {
    F8 kaC = ka, kbC = kb2, vfC = vf;
    kp += 32; vp += 4;
    ka.u4 = kp[0]; kb2.u4 = kp[16]; vf.u4 = *vp;   // prefetch next chunk

    f32x4 s1a = __builtin_amdgcn_mfma_f32_16x16x32_bf16(kaC.s, qxf.s, z4, 0, 0, 0);
    f32x4 s2a = __builtin_amdgcn_mfma_f32_16x16x32_bf16(kaC.s, qyf.s, z4, 0, 0, 0);
    f32x4 s1b = __builtin_amdgcn_mfma_f32_16x16x32_bf16(kbC.s, qxf.s, z4, 0, 0, 0);
    f32x4 s2b = __builtin_amdgcn_mfma_f32_16x16x32_bf16(kbC.s, qyf.s, z4, 0, 0, 0);

    float p00 = exp2f(s1a[0] * s2a[0]), p01 = exp2f(s1a[1] * s2a[1]);
    float p02 = exp2f(s1a[2] * s2a[2]), p03 = exp2f(s1a[3] * s2a[3]);
    float p10 = exp2f(s1b[0] * s2b[0]), p11 = exp2f(s1b[1] * s2b[1]);
    float p12 = exp2f(s1b[2] * s2b[2]), p13 = exp2f(s1b[3] * s2b[3]);
    lsum += ((p00 + p01) + (p02 + p03)) + ((p10 + p11) + (p12 + p13));

    unsigned int pk00, pk10, pk01, pk11;
    asm("v_cvt_pk_bf16_f32 %0, %1, %2" : "=v"(pk00) : "v"(p00), "v"(p01));
    asm("v_cvt_pk_bf16_f32 %0, %1, %2" : "=v"(pk10) : "v"(p02), "v"(p03));
    asm("v_cvt_pk_bf16_f32 %0, %1, %2" : "=v"(pk01) : "v"(p10), "v"(p11));
    asm("v_cvt_pk_bf16_f32 %0, %1, %2" : "=v"(pk11) : "v"(p12), "v"(p13));

    int b00 = __builtin_amdgcn_ds_bpermute(addr0, (int)pk00);
    int b01 = __builtin_amdgcn_ds_bpermute(addr0, (int)pk01);
    int b10 = __builtin_amdgcn_ds_bpermute(addr0, (int)pk10);
    int b11 = __builtin_amdgcn_ds_bpermute(addr0, (int)pk11);
    int c00 = __builtin_amdgcn_ds_bpermute(addr1, (int)pk00);
    int c01 = __builtin_amdgcn_ds_bpermute(addr1, (int)pk01);
    int c10 = __builtin_amdgcn_ds_bpermute(addr1, (int)pk10);
    int c11 = __builtin_amdgcn_ds_bpermute(addr1, (int)pk11);

    F8 pf;
    pf.w[0] = (unsigned int)(thi ? b01 : b00);
    pf.w[1] = (unsigned int)(thi ? b11 : b10);
    pf.w[2] = (unsigned int)(thi ? c01 : c00);
    pf.w[3] = (unsigned int)(thi ? c11 : c10);
    acc = __builtin_amdgcn_mfma_f32_16x16x32_bf16(pf.s, vfC.s, acc, 0, 0, 0);
  }

  lsum += __shfl_xor(lsum, 16, 64);
  lsum += __shfl_xor(lsum, 32, 64);
  if (lane < 16) sL[wave][lane] = lsum;
#pragma unroll
  for (int r = 0; r < 4; ++r) sAcc[wave][r][lane] = acc[r];
  __syncthreads();
  if (wave == 0) {
    float Linv = 1.f / (sL[0][l15] + sL[1][l15]);
    int b = bh >> 3, h = bh & 7;
    int d = l15 & 7;
    float* ob = (l15 < 8) ? outx : outy;
    size_t cbase = (size_t)b * N_ * C_ + (size_t)h * 8 + d;
#pragma unroll
    for (int r = 0; r < 4; ++r) {
      int qrow = 4 * (lane >> 4) + r;
      float li = __shfl(Linv, qrow, 64);
      float a = sAcc[0][r][lane] + sAcc[1][r][lane];
      ob[cbase + (size_t)(q0 + qrow) * C_] = a * li;
    }
  }
}

// -------- proj v2: 2 couts + 2 px per thread (att rows shared) ------------
__global__ __launch_bounds__(64) void k_proj2(
    const float* __restrict__ attbase,
    const float* __restrict__ x, const float* __restrict__ y,
    const float* bg, const float* bb2, const float* bm, const float* bv,
    const float* __restrict__ pw, const float* __restrict__ pbias,
    float* __restrict__ outbase) {
  int p = blockIdx.x * 128 + threadIdx.x * 2;
  int c0 = blockIdx.y * 2;
  int z = blockIdx.z;
  int branch = z >> 1, b = z & 1;
  const float* att = attbase + branch * S_ + (size_t)b * N_ * C_;
  const float4* w0 = (const float4*)(pw + (size_t)c0 * C_);
  const float4* w1 = (const float4*)(pw + (size_t)(c0 + 1) * C_);
  const float4* ar0 = (const float4*)(att + (size_t)p * C_);
  const float4* ar1 = (const float4*)(att + (size_t)(p + 1) * C_);
  float bias0 = pbias[c0], bias1 = pbias[c0 + 1];
  float a00 = bias0, a01 = bias0, a10 = bias1, a11 = bias1;
#pragma unroll
  for (int t = 0; t < 16; ++t) {
    float4 v0 = ar0[t], v1 = ar1[t];
    float4 u = w0[t], w = w1[t];
    a00 += v0.x*u.x + v0.y*u.y + v0.z*u.z + v0.w*u.w;
    a01 += v1.x*u.x + v1.y*u.y + v1.z*u.z + v1.w*u.w;
    a10 += v0.x*w.x + v0.y*w.y + v0.z*w.z + v0.w*w.w;
    a11 += v1.x*w.x + v1.y*w.y + v1.z*w.z + v1.w*w.w;
  }
  float s0  = bg[c0] * rsqrtf(bv[c0] + EPS_);
  float sh0 = bb2[c0] - bm[c0] * s0;
  float s1  = bg[c0+1] * rsqrtf(bv[c0+1] + EPS_);
  float sh1 = bb2[c0+1] - bm[c0+1] * s1;
  const float* xin = branch ? y : x;
  float2 r0 = *(const float2*)(xin + ((size_t)b * C_ + c0) * N_ + p);
  float2 r1 = *(const float2*)(xin + ((size_t)b * C_ + c0 + 1) * N_ + p);
  size_t o = (size_t)z * CN_ + (size_t)c0 * N_ + p;
  *(float2*)(outbase + o)      = make_float2(a00 + r0.x * s0 + sh0,
                                             a01 + r0.y * s0 + sh0);
  *(float2*)(outbase + o + N_) = make_float2(a10 + r1.x * s1 + sh1,
                                             a11 + r1.y * s1 + sh1);
}

// ===== conv core v3 (proven): async LDS input staging (dbuf) + s-weights ==
template<int CIN, int CIPB>
__device__ __forceinline__ void conv_core3(
    const float* __restrict__ ib, const float* __restrict__ w,
    int c0, int ci0, int p0, int tid, float (*bufs)[384],
    float4& A0, float4& A1) {
  const float* w0r = w + ((size_t)c0 * CIN + ci0) * 9;
  const float* w1r = w0r + (size_t)CIN * 9;
  int p  = p0 + tid * 4;
  int yy0 = p0 / W_;
  int yy = p / W_, x0 = p - yy * W_;
  int lr = yy - yy0;                     // 0..5 ; +ky in 0..7
  bool okL = x0 > 0, okR = x0 + 4 < W_;

  int rf0 = tid / 12, cf0 = tid - rf0 * 12;
  int gy0 = yy0 - 1 + rf0;
  int rf1 = (64 + tid) / 12, cf1 = (64 + tid) - rf1 * 12;
  int gy1 = yy0 - 1 + rf1;
  bool v0 = (unsigned)gy0 < (unsigned)H_;
  bool v1 = (tid < 32) && ((unsigned)gy1 < (unsigned)H_);
  int o0 = gy0 * W_ + cf0 * 4;
  int o1 = gy1 * W_ + cf1 * 4;
  const float4 zz = make_float4(0.f, 0.f, 0.f, 0.f);

  {
    const float* s = ib + (size_t)ci0 * N_;
    float4 ga = v0 ? *(const float4*)(s + o0) : zz;
    ((float4*)bufs[0])[tid] = ga;
    if (tid < 32) {
      float4 gb = v1 ? *(const float4*)(s + o1) : zz;
      ((float4*)bufs[0])[64 + tid] = gb;
    }
  }
  float wc[18];
#pragma unroll
  for (int i = 0; i < 9; ++i) { wc[i] = w0r[i]; wc[9 + i] = w1r[i]; }

#pragma unroll 2
  for (int ci = 0; ci < CIPB; ++ci) {
    float4 ga = zz, gb = zz;
    float wn[18];
    if (ci + 1 < CIPB) {
      const float* s = ib + (size_t)(ci0 + ci + 1) * N_;
      ga = v0 ? *(const float4*)(s + o0) : zz;
      gb = v1 ? *(const float4*)(s + o1) : zz;
      const float* nw0 = w0r + (ci + 1) * 9;
      const float* nw1 = w1r + (ci + 1) * 9;
#pragma unroll
      for (int i = 0; i < 9; ++i) { wn[i] = nw0[i]; wn[9 + i] = nw1[i]; }
    }
    const float* bc = bufs[ci & 1];
#pragma unroll
    for (int ky = 0; ky < 3; ++ky) {
      int base = (lr + ky) * W_ + x0;
      float4 mid = *(const float4*)(bc + base);
      float l = okL ? bc[base - 1] : 0.f;
      float r = okR ? bc[base + 4] : 0.f;
      float u0 = wc[ky*3], u1 = wc[ky*3+1], u2 = wc[ky*3+2];
      float t0 = wc[9+ky*3], t1 = wc[9+ky*3+1], t2 = wc[9+ky*3+2];
      A0.x += l     * u0 + mid.x * u1 + mid.y * u2;
      A0.y += mid.x * u0 + mid.y * u1 + mid.z * u2;
      A0.z += mid.y * u0 + mid.z * u1 + mid.w * u2;
      A0.w += mid.z * u0 + mid.w * u1 + r     * u2;
      A1.x += l     * t0 + mid.x * t1 + mid.y * t2;
      A1.y += mid.x * t0 + mid.y * t1 + mid.z * t2;
      A1.z += mid.y * t0 + mid.z * t1 + mid.w * t2;
      A1.w += mid.z * t0 + mid.w * t1 + r     * t2;
    }
    if (ci + 1 < CIPB) {
      float4* d = (float4*)bufs[(ci + 1) & 1];
      d[tid] = ga;
      if (tid < 32) d[64 + tid] = gb;
#pragma unroll
      for (int i = 0; i < 18; ++i) wc[i] = wn[i];
    }
  }
}

// ===== 2-wave conv (CIN=64): waves split cin halves, in-block combine =====
// grid (9, C_/2, 4 imgs), block 128. MODE 0: conv1 (bias+bn+relu -> split
// tmp oA/oB). MODE 1: conv2 (bias+bn+relu + resid -> oA at img*CN).
template<int MODE>
__global__ __launch_bounds__(128) void k_convf(
    const float* __restrict__ inA, const float* __restrict__ inB,
    const float* __restrict__ w, const float* __restrict__ cb,
    const float* g, const float* b2, const float* m, const float* v,
    const float* __restrict__ resid,
    float* __restrict__ oA, float* __restrict__ oB) {
  __shared__ float lds[2 * 768 + 512];
  int tid = threadIdx.x, wave = tid >> 6, lane = tid & 63;
  int tile = blockIdx.x, c0 = blockIdx.y * 2, img = blockIdx.z;
  const float* ib = (img < 2) ? inA + (size_t)img * CN_
                              : inB + (size_t)(img - 2) * CN_;
  float (*mybufs)[384] = (float(*)[384])(lds + wave * 768);
  float* comb = lds + 1536;
  float4 A0 = make_float4(0.f,0.f,0.f,0.f);
  float4 A1 = make_float4(0.f,0.f,0.f,0.f);
  conv_core3<C_, C_/2>(ib, w, c0, wave * (C_/2), tile * 256, lane, mybufs,
                       A0, A1);
  if (wave == 1) {
    float* cw = comb + lane * 8;
    *(float4*)cw = A0; *(float4*)(cw + 4) = A1;
  }
  __syncthreads();
  if (wave == 0) {
    const float* cr = comb + lane * 8;
    float4 d0 = *(const float4*)cr, d1 = *(const float4*)(cr + 4);
    int p = tile * 256 + lane * 4;
#pragma unroll
    for (int j = 0; j < 2; ++j) {
      int c = c0 + j;
      float4 a = j ? A1 : A0;
      float4 d = j ? d1 : d0;
      float s  = g[c] * rsqrtf(v[c] + EPS_);
      float sh = b2[c] - m[c] * s;
      float bias = cb[c];
      float4 r;
      r.x = fmaxf((a.x + d.x + bias) * s + sh, 0.f);
      r.y = fmaxf((a.y + d.y + bias) * s + sh, 0.f);
      r.z = fmaxf((a.z + d.z + bias) * s + sh, 0.f);
      r.w = fmaxf((a.w + d.w + bias) * s + sh, 0.f);
      size_t off = (size_t)img * CN_ + (size_t)c * N_ + p;
      if (MODE == 0) {
        float* ob = (img < 2) ? oA + off : oB + off - 2 * CN_;
        *(float4*)ob = r;
      } else {
        float4 rr = *(const float4*)(resid + off);
        r.x += rr.x; r.y += rr.y; r.z += rr.z; r.w += rr.w;
        *(float4*)(oA + off) = r;
      }
    }
  }
}

// ===== 2-wave f-conv (CIN=128): waves split cin halves, in-block combine ==
// grid (9, C_, B_), block 128. MODE 0: f1 (bn+relu). MODE 1: f2 (raw sum).
template<int MODE>
__global__ __launch_bounds__(128) void k_fconvf(
    const float* __restrict__ in, size_t inStride,
    const float* __restrict__ w,
    const float* g, const float* b2, const float* m, const float* v,
    float* __restrict__ out) {     // out + b*S_, layout c*N+p
  __shared__ float lds[2 * 768 + 512];
  int tid = threadIdx.x, wave = tid >> 6, lane = tid & 63;
  int tile = blockIdx.x, c0 = blockIdx.y * 2, b = blockIdx.z;
  const float* ib = in + (size_t)b * inStride;
  float (*mybufs)[384] = (float(*)[384])(lds + wave * 768);
  float* comb = lds + 1536;
  float4 A0 = make_float4(0.f,0.f,0.f,0.f);
  float4 A1 = make_float4(0.f,0.f,0.f,0.f);
  conv_core3<2*C_, C_>(ib, w, c0, wave * C_, tile * 256, lane, mybufs,
                       A0, A1);
  if (wave == 1) {
    float* cw = comb + lane * 8;
    *(float4*)cw = A0; *(float4*)(cw + 4) = A1;
  }
  __syncthreads();
  if (wave == 0) {
    const float* cr = comb + lane * 8;
    float4 d0 = *(const float4*)cr, d1 = *(const float4*)(cr + 4);
    int p = tile * 256 + lane * 4;
#pragma unroll
    for (int j = 0; j < 2; ++j) {
      int c = c0 + j;
      float4 a = j ? A1 : A0;
      float4 d = j ? d1 : d0;
      float4 r;
      if (MODE == 0) {
        float s  = g[c] * rsqrtf(v[c] + EPS_);
        float sh = b2[c] - m[c] * s;
        r.x = fmaxf((a.x + d.x) * s + sh, 0.f);
        r.y = fmaxf((a.y + d.y) * s + sh, 0.f);
        r.z = fmaxf((a.z + d.z) * s + sh, 0.f);
        r.w = fmaxf((a.w + d.w) * s + sh, 0.f);
      } else {
        r.x = a.x + d.x; r.y = a.y + d.y;
        r.z = a.z + d.z; r.w = a.w + d.w;
      }
      *(float4*)(out + (size_t)b * S_ + (size_t)c * N_ + p) = r;
    }
  }
}

// ------ cat = [xo+yo ; xo*yo] + bn2 -> fin, float4 ------------------------
__global__ void k_catbn(const float* __restrict__ o2,
                        const float* __restrict__ g, const float* __restrict__ b2,
                        const float* __restrict__ m, const float* __restrict__ v,
                        float* __restrict__ cat, float* __restrict__ fin,
                        size_t finStride) {
  int t = blockIdx.x * 256 + threadIdx.x;
  int p4 = t * 4;
  int n  = p4 % N_;
  int c2 = (p4 / N_) % (2 * C_);
  int b  = p4 / (2 * C_ * N_);
  int c  = c2 & 63;
  float4 X = *(const float4*)(o2 + (size_t)b * CN_ + (size_t)c * N_ + n);
  float4 Y = *(const float4*)(o2 + (size_t)(2 + b) * CN_ + (size_t)c * N_ + n);
  float4 val;
  if (c2 < C_) val = make_float4(X.x + Y.x, X.y + Y.y, X.z + Y.z, X.w + Y.w);
  else         val = make_float4(X.x * Y.x, X.y * Y.y, X.z * Y.z, X.w * Y.w);
  size_t co = ((size_t)b * 2 * C_ + c2) * N_ + n;
  *(float4*)(cat + co) = val;
  float s  = g[c2] * rsqrtf(v[c2] + EPS_);
  float sh = b2[c2] - m[c2] * s;
  *(float4*)(fin + (size_t)b * finStride + (size_t)c2 * N_ + n) =
      make_float4(val.x * s + sh, val.y * s + sh, val.z * s + sh, val.w * s + sh);
}

// -------- final v3: single pre-combined f2 input + fbn2+relu + cat add ----
__global__ __launch_bounds__(64) void k_final3(
    const float* __restrict__ ff, size_t strideF,
    const float* __restrict__ g2, const float* __restrict__ b2,
    const float* __restrict__ m2, const float* __restrict__ v2,
    const float* __restrict__ cat,
    const float* __restrict__ w, const float* __restrict__ fb,
    float* __restrict__ out) {
  __shared__ float fsc[2 * C_], fsh[2 * C_];
  for (int j = threadIdx.x; j < 2 * C_; j += 64) {
    float s = g2[j] * rsqrtf(v2[j] + EPS_);
    fsc[j] = s;
    fsh[j] = b2[j] - m2[j] * s;
  }
  __syncthreads();
  int p = blockIdx.x * 128 + threadIdx.x * 2;
  int c0 = blockIdx.y * 2;
  int b = blockIdx.z;
  const float* fr = ff + (size_t)b * strideF;
  const float* wr0 = w + (size_t)c0 * 2 * C_;
  const float* wr1 = wr0 + 2 * C_;
  float a00 = fb[c0], a01 = a00;
  float a10 = fb[c0 + 1], a11 = a10;
#pragma unroll 4
  for (int j = 0; j < 2 * C_; ++j) {
    float2 fa = *(const float2*)(fr + (size_t)j * N_ + p);
    float s = fsc[j], sh = fsh[j];
    float f0 = fmaxf(fa.x * s + sh, 0.f);
    float f1 = fmaxf(fa.y * s + sh, 0.f);
    float wv0 = wr0[j], wv1 = wr1[j];
    a00 += wv0 * f0; a01 += wv0 * f1;
    a10 += wv1 * f0; a11 += wv1 * f1;
  }
  size_t o = ((size_t)b * 2 * C_ + c0) * N_ + p;
  float2 cv0 = *(const float2*)(cat + o);
  float2 cv1 = *(const float2*)(cat + o + N_);
  *(float2*)(out + o)      = make_float2(a00 + cv0.x, a01 + cv0.y);
  *(float2*)(out + o + N_) = make_float2(a10 + cv1.x, a11 + cv1.y);
}

extern "C" void kernel_launch(void* const* d_in, const int* in_sizes, int n_in,
                              void* d_out, int out_size, void* d_ws, size_t ws_size,
                              hipStream_t stream) {
  const float* x       = (const float*)d_in[0];
  const float* y       = (const float*)d_in[1];
  const float* pconv_w = (const float*)d_in[2];
  const float* pconv_b = (const float*)d_in[3];
  const float* bnd_g = (const float*)d_in[4];
  const float* bnd_b = (const float*)d_in[5];
  const float* bnd_m = (const float*)d_in[6];
  const float* bnd_v = (const float*)d_in[7];
  const float* lnx_g = (const float*)d_in[8];
  const float* lnx_b = (const float*)d_in[9];
  const float* lny_g = (const float*)d_in[10];
  const float* lny_b = (const float*)d_in[11];
  const float* lnz_g = (const float*)d_in[12];
  const float* lnz_b = (const float*)d_in[13];
  const float* k_w   = (const float*)d_in[14];
  const float* k_b   = (const float*)d_in[15];
  const float* qv_w  = (const float*)d_in[16];
  const float* qv_b  = (const float*)d_in[17];
  const float* proj_w = (const float*)d_in[18];
  const float* proj_b = (const float*)d_in[19];
  const float* c2w1  = (const float*)d_in[20];
  const float* c2b1  = (const float*)d_in[21];
  const float* c2bn1_g = (const float*)d_in[22];
  const float* c2bn1_b = (const float*)d_in[23];
  const float* c2bn1_m = (const float*)d_in[24];
  const float* c2bn1_v = (const float*)d_in[25];
  const float* c2w2  = (const float*)d_in[26];
  const float* c2b2  = (const float*)d_in[27];
  const float* c2bn2_g = (const float*)d_in[28];
  const float* c2bn2_b = (const float*)d_in[29];
  const float* c2bn2_m = (const float*)d_in[30];
  const float* c2bn2_v = (const float*)d_in[31];
  const float* bn2_g = (const float*)d_in[32];
  const float* bn2_b = (const float*)d_in[33];
  const float* bn2_m = (const float*)d_in[34];
  const float* bn2_v = (const float*)d_in[35];
  const float* f1w   = (const float*)d_in[36];
  const float* fbn1_g = (const float*)d_in[37];
  const float* fbn1_b = (const float*)d_in[38];
  const float* fbn1_m = (const float*)d_in[39];
  const float* fbn1_v = (const float*)d_in[40];
  const float* f2w   = (const float*)d_in[41];
  const float* fbn2_g = (const float*)d_in[42];
  const float* fbn2_b = (const float*)d_in[43];
  const float* fbn2_m = (const float*)d_in[44];
  const float* fbn2_v = (const float*)d_in[45];
  const float* f3w   = (const float*)d_in[46];
  const float* f3b   = (const float*)d_in[47];

  // Workspace plan:
  //   A: k_pre -> xl(1) yl(2) zl(3)
  //   B: qvk -> qx|qy(4), k(5), VT(6)
  //   C: attn8 -> att_xo(1) att_yo(2)
  //   D: proj -> xo4(3,4) [img*CN, imgs 0..3]
  //   E: convf<0> (2-wave, fused) reads xo4(3,4) -> tmp imgs01(0), imgs23(7)
  //   F: convf<1> (2-wave, fused+resid(3,4)) reads tmp -> o2(1,2) [img*CN]
  //   G: catbn reads o2(1,2) -> cat(3,4), fin b0->(0), b1->(7) [stride 7S]
  //   H1: fconvf<0> f1: fin(0/7) -> (1,2) [b*S_]
  //   H2: fconvf<1> f2: (1,2) -> (5,6) [b*S_] raw
  //   I: final3 reads (5,6) + cat(3,4) -> out
  float* ws = (float*)d_ws;
  float* sl0 = ws + 0 * S_;
  float* sl1 = ws + 1 * S_;
  float* sl2 = ws + 2 * S_;
  float* sl3 = ws + 3 * S_;
  float* sl4 = ws + 4 * S_;
  float* sl5 = ws + 5 * S_;
  float* sl7 = ws + 7 * S_;

  // A. fused pconv + bn + ln (v2: 16 rows/block)
  k_pre<<<B_ * N_ / 16, 1024, 0, stream>>>(x, y, pconv_w, pconv_b,
                                    bnd_g, bnd_b, bnd_m, bnd_v,
                                    lnx_g, lnx_b, lny_g, lny_b, lnz_g, lnz_b,
                                    sl1, sl2, sl3);
  // B. qv/k projection v2 -> bf16 attention operands
  u16* qxb = (u16*)sl4;
  u16* qyb = qxb + (size_t)B_ * NH_ * N_ * 8;
  u16* kbf = (u16*)sl5;
  u16* vtb = (u16*)(ws + 6 * S_);
  {
    dim3 g(B_ * N_ / 64, 20);
    k_qvk<<<g, 64, 0, stream>>>(sl1, sl2, sl3, qv_w, qv_b, k_w, k_b,
                                qxb, qyb, kbf, vtb);
  }
  // C. attention v8 (MFMA) -> att_xo(1), att_yo(2)
  {
    dim3 g(N_ / 16, B_ * NH_);
    k_attn8<<<g, 128, 0, stream>>>(qxb, qyb, kbf, vtb, sl1, sl2);
  }
  // D. proj v2 (2 couts) -> xo4(3,4)
  {
    dim3 g(18, C_ / 2, 2 * B_);
    k_proj2<<<g, 64, 0, stream>>>(sl1, x, y, bnd_g, bnd_b, bnd_m, bnd_v,
                                  proj_w, proj_b, sl3);
  }
  // E. conv1 (2-wave fused) -> tmp(0 / 7)
  {
    dim3 g(9, C_ / 2, 4);
    k_convf<0><<<g, 128, 0, stream>>>(sl3, sl3 + 2 * CN_, c2w1, c2b1,
        c2bn1_g, c2bn1_b, c2bn1_m, c2bn1_v, sl3, sl0, sl7);
  }
  // F. conv2 (2-wave fused + resid) -> o2(1,2)
  {
    dim3 g(9, C_ / 2, 4);
    k_convf<1><<<g, 128, 0, stream>>>(sl0, sl7, c2w2, c2b2,
        c2bn2_g, c2bn2_b, c2bn2_m, c2bn2_v, sl3, sl1, sl1);
  }
  // G. cat + bn2 -> cat(3,4), fin(0 / 7)
  k_catbn<<<576, 256, 0, stream>>>(sl1, bn2_g, bn2_b, bn2_m, bn2_v,
                                   sl3, sl0, 7 * S_);
  // H. f-branch convs (2-wave fused)
  {
    dim3 g(9, C_, B_);
    k_fconvf<0><<<g, 128, 0, stream>>>(sl0, 7 * S_, f1w,
        fbn1_g, fbn1_b, fbn1_m, fbn1_v, sl1);
    k_fconvf<1><<<g, 128, 0, stream>>>(sl1, S_, f2w,
        fbn1_g, fbn1_b, fbn1_m, fbn1_v, sl5);
  }
  // I. final v3 (single f2 input) -> fp32 out
  {
    dim3 g(18, C_, B_);
    k_final3<<<g, 64, 0, stream>>>(sl5, S_,
                                   fbn2_g, fbn2_b, fbn2_m, fbn2_v,
                                   sl3, f3w, f3b, (float*)d_out);
  }
}

// Round 11
// 402.963 us; speedup vs baseline: 1.4025x; 1.0183x over previous
//
#include <hip/hip_runtime.h>
#include <hip/hip_bf16.h>

#define B_   2
#define C_   64
#define H_   48
#define W_   48
#define N_   (H_*W_)     // 2304
#define NH_  8
#define HD_  8
#define EPS_ 1e-5f
#define S2_  0.125f      // scale^2 = 1/hd
#define LOG2E_ 1.44269504f
#define FS_  (S2_ * LOG2E_)
#define S_   ((size_t)B_ * C_ * N_)   // 294912 floats per workspace slot
#define CN_  ((size_t)C_ * N_)        // 147456 floats per image

typedef unsigned short u16;
typedef __attribute__((ext_vector_type(8))) short short8v;
typedef __attribute__((ext_vector_type(4))) float f32x4;
union F8 { uint4 u4; short8v s; unsigned int w[4]; };

__device__ __forceinline__ float wsum64(float v) {
#pragma unroll
  for (int o = 32; o > 0; o >>= 1) v += __shfl_xor(v, o, 64);
  return v;
}

__device__ __forceinline__ float ln_val(float t, float g, float b) {
  float mu  = wsum64(t) * (1.0f / 64.0f);
  float d   = t - mu;
  float var = wsum64(d * d) * (1.0f / 64.0f);
  return d * rsqrtf(var + EPS_) * g + b;
}

// round-to-nearest-even f32 -> bf16 (finite inputs only)
__device__ __forceinline__ u16 f2bf(float x) {
  union { float f; unsigned int u; } a; a.f = x;
  unsigned int r = a.u + 0x7fffu + ((a.u >> 16) & 1u);
  return (u16)(r >> 16);
}

// ---- fused 1x1 pconv + BN + 3x LayerNorm; v2: 16 rows/block, LDS pw^T ----
__global__ __launch_bounds__(1024) void k_pre(
    const float* __restrict__ x, const float* __restrict__ y,
    const float* __restrict__ pw, const float* __restrict__ pb,
    const float* g, const float* bb, const float* m, const float* v,
    const float* lnxg, const float* lnxb,
    const float* lnyg, const float* lnyb,
    const float* lnzg, const float* lnzb,
    float* __restrict__ xl, float* __restrict__ yl, float* __restrict__ zl) {
  __shared__ float4 pwT[32][64];           // pwT[i4][c] = pw[c][4*i4..+3]
  __shared__ float xs[16][64], ys[16][64];
  int w = threadIdx.x >> 6, c = threadIdx.x & 63;
  for (int idx = threadIdx.x; idx < 2048; idx += 1024) {
    int cc = idx & 63, i4 = idx >> 6;
    pwT[i4][cc] = *(const float4*)(pw + (size_t)cc * 2 * C_ + i4 * 4);
  }
  int row = blockIdx.x * 16 + w;           // b*N + n
  int b = row / N_, n = row % N_;
  float xv = x[(size_t)(b * C_ + c) * N_ + n];
  float yv = y[(size_t)(b * C_ + c) * N_ + n];
  xs[w][c] = xv; ys[w][c] = yv;
  __syncthreads();
  const float4* xw = (const float4*)xs[w];
  const float4* yw = (const float4*)ys[w];
  float acc = pb[c];
#pragma unroll
  for (int t = 0; t < 16; ++t) {
    float4 a = xw[t], wv = pwT[t][c];
    acc += a.x * wv.x + a.y * wv.y + a.z * wv.z + a.w * wv.w;
  }
#pragma unroll
  for (int t = 0; t < 16; ++t) {
    float4 a = yw[t], wv = pwT[16 + t][c];
    acc += a.x * wv.x + a.y * wv.y + a.z * wv.z + a.w * wv.w;
  }
  float s  = g[c] * rsqrtf(v[c] + EPS_);
  float sh = bb[c] - m[c] * s;
  float tx = xv * s + sh;
  xl[(size_t)row * C_ + c] = ln_val(tx, lnxg[c], lnxb[c]);
  float ty = yv * s + sh;
  yl[(size_t)row * C_ + c] = ln_val(ty, lnyg[c], lnyb[c]);
  float tz = acc * s + sh;
  zl[(size_t)row * C_ + c] = ln_val(tz, lnzg[c], lnzb[c]);
}

// ------------- qv/k projection v2: lane = row, uniform weights ------------
__global__ __launch_bounds__(64) void k_qvk(
    const float* __restrict__ xl, const float* __restrict__ yl,
    const float* __restrict__ zl,
    const float* __restrict__ qvw, const float* __restrict__ qvb,
    const float* __restrict__ kw, const float* __restrict__ kb,
    u16* __restrict__ qxb, u16* __restrict__ qyb,
    u16* __restrict__ kbf, u16* __restrict__ vt) {
  int l = threadIdx.x;
  int part = blockIdx.y >> 2;
  int j0 = (blockIdx.y & 3) * 16;
  int row = blockIdx.x * 64 + l;
  int b = row / N_, n = row % N_;
  const float* inp = (part < 2) ? xl : (part < 4) ? yl : zl;
  float4 in[16];
  const float4* ir = (const float4*)(inp + (size_t)row * C_);
#pragma unroll
  for (int t = 0; t < 16; ++t) in[t] = ir[t];

  const float* wb   = (part == 4) ? kw : qvw;
  const float* bias = (part == 4) ? kb : qvb;
  int joff = (part == 1 || part == 3) ? 64 : 0;

  if (part == 1 || part == 3) {
    int vbase = (part == 1) ? 0 : 8;
#pragma unroll
    for (int jj = 0; jj < 16; ++jj) {
      int j = j0 + jj;
      const float4* wr = (const float4*)(wb + (size_t)(joff + j) * C_);
      float acc = bias[joff + j];
#pragma unroll
      for (int t = 0; t < 16; ++t) {
        float4 a = in[t], wv = wr[t];
        acc += a.x * wv.x + a.y * wv.y + a.z * wv.z + a.w * wv.w;
      }
      int h = j >> 3, d = j & 7;
      vt[((size_t)((b * NH_ + h) * 16 + vbase + d)) * N_ + n] = f2bf(acc);
    }
  } else {
    u16* dst = (part == 0) ? qxb : (part == 2) ? qyb : kbf;
#pragma unroll
    for (int gg = 0; gg < 2; ++gg) {
      int h = (j0 >> 3) + gg;
      union { uint4 u4; u16 s[8]; } pk;
#pragma unroll
      for (int d = 0; d < 8; ++d) {
        int j = h * 8 + d;
        const float4* wr = (const float4*)(wb + (size_t)(joff + j) * C_);
        float acc = bias[joff + j];
#pragma unroll
        for (int t = 0; t < 16; ++t) {
          float4 a = in[t], wv = wr[t];
          acc += a.x * wv.x + a.y * wv.y + a.z * wv.z + a.w * wv.w;
        }
        if (part == 0) acc *= FS_;
        pk.s[d] = f2bf(acc);
      }
      *(uint4*)(dst + ((size_t)(b * NH_ + h) * N_ + n) * 8) = pk.u4;
    }
  }
}

// ---------------- attention v8: MFMA flash, 16-q tile, dual-branch --------
__global__ __launch_bounds__(128, 5) void k_attn8(
    const u16* __restrict__ qx, const u16* __restrict__ qy,
    const u16* __restrict__ kk, const u16* __restrict__ vt,
    float* __restrict__ outx, float* __restrict__ outy) {
  __shared__ float sAcc[2][4][64];
  __shared__ float sL[2][16];
  int qt = blockIdx.x, bh = blockIdx.y;
  int tid = threadIdx.x;
  int lane = tid & 63;
  int wave = tid >> 6;
  int l15 = lane & 15;
  int q0 = qt * 16;

  F8 qxf, qyf;
  size_t qoff = ((size_t)bh * N_ + q0 + l15) * 8;
  qxf.u4 = *(const uint4*)(qx + qoff);
  qyf.u4 = *(const uint4*)(qy + qoff);
  if (lane >= 16) {
    qxf.u4 = make_uint4(0u, 0u, 0u, 0u);
    qyf.u4 = make_uint4(0u, 0u, 0u, 0u);
  }

  int key0 = wave * (N_ / 2);
  const uint4* kp = (const uint4*)(kk + (size_t)bh * N_ * 8) + key0 + l15;
  const uint4* vp = (const uint4*)(vt + ((size_t)bh * 16 + l15) * N_ + key0)
                    + (lane >> 4);
  int addr0 = (((lane >> 4) & 1) * 32 + l15) * 4;
  int addr1 = addr0 + 64;
  int thi = lane >> 5;

  f32x4 acc = {0.f, 0.f, 0.f, 0.f};
  const f32x4 z4 = {0.f, 0.f, 0.f, 0.f};
  float lsum = 0.f;

  F8 ka, kb2, vf;
  ka.u4 = kp[0]; kb2.u4 = kp[16]; vf.u4 = *vp;
  for (int c = 0; c < 36; ++c) {
    F8 kaC = ka, kbC = kb2, vfC = vf;
    kp += 32; vp += 4;
    ka.u4 = kp[0]; kb2.u4 = kp[16]; vf.u4 = *vp;   // prefetch next chunk

    f32x4 s1a = __builtin_amdgcn_mfma_f32_16x16x32_bf16(kaC.s, qxf.s, z4, 0, 0, 0);
    f32x4 s2a = __builtin_amdgcn_mfma_f32_16x16x32_bf16(kaC.s, qyf.s, z4, 0, 0, 0);
    f32x4 s1b = __builtin_amdgcn_mfma_f32_16x16x32_bf16(kbC.s, qxf.s, z4, 0, 0, 0);
    f32x4 s2b = __builtin_amdgcn_mfma_f32_16x16x32_bf16(kbC.s, qyf.s, z4, 0, 0, 0);

    float p00 = exp2f(s1a[0] * s2a[0]), p01 = exp2f(s1a[1] * s2a[1]);
    float p02 = exp2f(s1a[2] * s2a[2]), p03 = exp2f(s1a[3] * s2a[3]);
    float p10 = exp2f(s1b[0] * s2b[0]), p11 = exp2f(s1b[1] * s2b[1]);
    float p12 = exp2f(s1b[2] * s2b[2]), p13 = exp2f(s1b[3] * s2b[3]);
    lsum += ((p00 + p01) + (p02 + p03)) + ((p10 + p11) + (p12 + p13));

    unsigned int pk00, pk10, pk01, pk11;
    asm("v_cvt_pk_bf16_f32 %0, %1, %2" : "=v"(pk00) : "v"(p00), "v"(p01));
    asm("v_cvt_pk_bf16_f32 %0, %1, %2" : "=v"(pk10) : "v"(p02), "v"(p03));
    asm("v_cvt_pk_bf16_f32 %0, %1, %2" : "=v"(pk01) : "v"(p10), "v"(p11));
    asm("v_cvt_pk_bf16_f32 %0, %1, %2" : "=v"(pk11) : "v"(p12), "v"(p13));

    int b00 = __builtin_amdgcn_ds_bpermute(addr0, (int)pk00);
    int b01 = __builtin_amdgcn_ds_bpermute(addr0, (int)pk01);
    int b10 = __builtin_amdgcn_ds_bpermute(addr0, (int)pk10);
    int b11 = __builtin_amdgcn_ds_bpermute(addr0, (int)pk11);
    int c00 = __builtin_amdgcn_ds_bpermute(addr1, (int)pk00);
    int c01 = __builtin_amdgcn_ds_bpermute(addr1, (int)pk01);
    int c10 = __builtin_amdgcn_ds_bpermute(addr1, (int)pk10);
    int c11 = __builtin_amdgcn_ds_bpermute(addr1, (int)pk11);

    F8 pf;
    pf.w[0] = (unsigned int)(thi ? b01 : b00);
    pf.w[1] = (unsigned int)(thi ? b11 : b10);
    pf.w[2] = (unsigned int)(thi ? c01 : c00);
    pf.w[3] = (unsigned int)(thi ? c11 : c10);
    acc = __builtin_amdgcn_mfma_f32_16x16x32_bf16(pf.s, vfC.s, acc, 0, 0, 0);
  }

  lsum += __shfl_xor(lsum, 16, 64);
  lsum += __shfl_xor(lsum, 32, 64);
  if (lane < 16) sL[wave][lane] = lsum;
#pragma unroll
  for (int r = 0; r < 4; ++r) sAcc[wave][r][lane] = acc[r];
  __syncthreads();
  if (wave == 0) {
    float Linv = 1.f / (sL[0][l15] + sL[1][l15]);
    int b = bh >> 3, h = bh & 7;
    int d = l15 & 7;
    float* ob = (l15 < 8) ? outx : outy;
    size_t cbase = (size_t)b * N_ * C_ + (size_t)h * 8 + d;
#pragma unroll
    for (int r = 0; r < 4; ++r) {
      int qrow = 4 * (lane >> 4) + r;
      float li = __shfl(Linv, qrow, 64);
      float a = sAcc[0][r][lane] + sAcc[1][r][lane];
      ob[cbase + (size_t)(q0 + qrow) * C_] = a * li;
    }
  }
}

// -------- proj v3: LDS-transposed att tile, conflict-free reads -----------
// grid (36, C_/2, 2*B_), block 64. Block = 64 px, 2 couts.
__global__ __launch_bounds__(64) void k_proj3(
    const float* __restrict__ attbase,
    const float* __restrict__ x, const float* __restrict__ y,
    const float* bg, const float* bb2, const float* bm, const float* bv,
    const float* __restrict__ pw, const float* __restrict__ pbias,
    float* __restrict__ outbase) {
  __shared__ float attT[64][66];   // attT[c][r] = att[p0+r][c]
  int tid = threadIdx.x;
  int p0 = blockIdx.x * 64;
  int c0 = blockIdx.y * 2;
  int z = blockIdx.z;
  int branch = z >> 1, b = z & 1;
  const float* att = attbase + branch * S_ + (size_t)b * N_ * C_;
  // stage: lane = channel, loop rows (coalesced global; 2-way LDS = free)
  for (int r = 0; r < 64; ++r)
    attT[tid][r] = att[(size_t)(p0 + r) * C_ + tid];
  __syncthreads();
  int p = p0 + tid;
  const float* w0 = pw + (size_t)c0 * C_;
  const float* w1 = w0 + C_;
  float a0 = pbias[c0], a1 = pbias[c0 + 1];
#pragma unroll 8
  for (int c = 0; c < C_; ++c) {
    float av = attT[c][tid];
    a0 += av * w0[c];
    a1 += av * w1[c];
  }
  float s0  = bg[c0] * rsqrtf(bv[c0] + EPS_);
  float sh0 = bb2[c0] - bm[c0] * s0;
  float s1  = bg[c0+1] * rsqrtf(bv[c0+1] + EPS_);
  float sh1 = bb2[c0+1] - bm[c0+1] * s1;
  const float* xin = branch ? y : x;
  float r0 = xin[((size_t)b * C_ + c0) * N_ + p];
  float r1 = xin[((size_t)b * C_ + c0 + 1) * N_ + p];
  size_t o = (size_t)z * CN_ + (size_t)c0 * N_ + p;
  outbase[o]      = a0 + r0 * s0 + sh0;
  outbase[o + N_] = a1 + r1 * s1 + sh1;
}

// ===== conv core v3 (proven): async LDS input staging (dbuf) + s-weights ==
template<int CIN, int CIPB>
__device__ __forceinline__ void conv_core3(
    const float* __restrict__ ib, const float* __restrict__ w,
    int c0, int ci0, int p0, int tid, float (*bufs)[384],
    float4& A0, float4& A1) {
  const float* w0r = w + ((size_t)c0 * CIN + ci0) * 9;
  const float* w1r = w0r + (size_t)CIN * 9;
  int p  = p0 + tid * 4;
  int yy0 = p0 / W_;
  int yy = p / W_, x0 = p - yy * W_;
  int lr = yy - yy0;                     // 0..5 ; +ky in 0..7
  bool okL = x0 > 0, okR = x0 + 4 < W_;

  int rf0 = tid / 12, cf0 = tid - rf0 * 12;
  int gy0 = yy0 - 1 + rf0;
  int rf1 = (64 + tid) / 12, cf1 = (64 + tid) - rf1 * 12;
  int gy1 = yy0 - 1 + rf1;
  bool v0 = (unsigned)gy0 < (unsigned)H_;
  bool v1 = (tid < 32) && ((unsigned)gy1 < (unsigned)H_);
  int o0 = gy0 * W_ + cf0 * 4;
  int o1 = gy1 * W_ + cf1 * 4;
  const float4 zz = make_float4(0.f, 0.f, 0.f, 0.f);

  {
    const float* s = ib + (size_t)ci0 * N_;
    float4 ga = v0 ? *(const float4*)(s + o0) : zz;
    ((float4*)bufs[0])[tid] = ga;
    if (tid < 32) {
      float4 gb = v1 ? *(const float4*)(s + o1) : zz;
      ((float4*)bufs[0])[64 + tid] = gb;
    }
  }
  float wc[18];
#pragma unroll
  for (int i = 0; i < 9; ++i) { wc[i] = w0r[i]; wc[9 + i] = w1r[i]; }

#pragma unroll 2
  for (int ci = 0; ci < CIPB; ++ci) {
    float4 ga = zz, gb = zz;
    float wn[18];
    if (ci + 1 < CIPB) {
      const float* s = ib + (size_t)(ci0 + ci + 1) * N_;
      ga = v0 ? *(const float4*)(s + o0) : zz;
      gb = v1 ? *(const float4*)(s + o1) : zz;
      const float* nw0 = w0r + (ci + 1) * 9;
      const float* nw1 = w1r + (ci + 1) * 9;
#pragma unroll
      for (int i = 0; i < 9; ++i) { wn[i] = nw0[i]; wn[9 + i] = nw1[i]; }
    }
    const float* bc = bufs[ci & 1];
#pragma unroll
    for (int ky = 0; ky < 3; ++ky) {
      int base = (lr + ky) * W_ + x0;
      float4 mid = *(const float4*)(bc + base);
      float l = okL ? bc[base - 1] : 0.f;
      float r = okR ? bc[base + 4] : 0.f;
      float u0 = wc[ky*3], u1 = wc[ky*3+1], u2 = wc[ky*3+2];
      float t0 = wc[9+ky*3], t1 = wc[9+ky*3+1], t2 = wc[9+ky*3+2];
      A0.x += l     * u0 + mid.x * u1 + mid.y * u2;
      A0.y += mid.x * u0 + mid.y * u1 + mid.z * u2;
      A0.z += mid.y * u0 + mid.z * u1 + mid.w * u2;
      A0.w += mid.z * u0 + mid.w * u1 + r     * u2;
      A1.x += l     * t0 + mid.x * t1 + mid.y * t2;
      A1.y += mid.x * t0 + mid.y * t1 + mid.z * t2;
      A1.z += mid.y * t0 + mid.z * t1 + mid.w * t2;
      A1.w += mid.z * t0 + mid.w * t1 + r     * t2;
    }
    if (ci + 1 < CIPB) {
      float4* d = (float4*)bufs[(ci + 1) & 1];
      d[tid] = ga;
      if (tid < 32) d[64 + tid] = gb;
#pragma unroll
      for (int i = 0; i < 18; ++i) wc[i] = wn[i];
    }
  }
}

// ===== 2-wave conv (CIN=64): waves split cin halves; epilogue split too ===
// grid (9, C_/2, 4 imgs), block 128. Each wave exchanges only the half the
// other needs, then stores ONE cout row (wave w -> cout c0+w).
// MODE 0: conv1 (bias+bn+relu -> split tmp oA/oB). MODE 1: + resid -> oA.
template<int MODE>
__global__ __launch_bounds__(128) void k_convf(
    const float* __restrict__ inA, const float* __restrict__ inB,
    const float* __restrict__ w, const float* __restrict__ cb,
    const float* g, const float* b2, const float* m, const float* v,
    const float* __restrict__ resid,
    float* __restrict__ oA, float* __restrict__ oB) {
  __shared__ float lds[2 * 768 + 512];
  int tid = threadIdx.x, wave = tid >> 6, lane = tid & 63;
  int tile = blockIdx.x, c0 = blockIdx.y * 2, img = blockIdx.z;
  const float* ib = (img < 2) ? inA + (size_t)img * CN_
                              : inB + (size_t)(img - 2) * CN_;
  float (*mybufs)[384] = (float(*)[384])(lds + wave * 768);
  float* comb = lds + 1536;
  float4 A0 = make_float4(0.f,0.f,0.f,0.f);
  float4 A1 = make_float4(0.f,0.f,0.f,0.f);
  conv_core3<C_, C_/2>(ib, w, c0, wave * (C_/2), tile * 256, lane, mybufs,
                       A0, A1);
  // wave0 posts its A1 (needed by wave1); wave1 posts its A0 (for wave0)
  float* cw = comb + wave * 256 + lane * 4;
  *(float4*)cw = wave ? A0 : A1;
  __syncthreads();
  {
    int c = c0 + wave;
    const float4 other = *(const float4*)(comb + (1 - wave) * 256 + lane * 4);
    float4 a = wave ? other : A0;    // cin 0..31 half
    float4 d = wave ? A1 : other;    // cin 32..63 half
    int p = tile * 256 + lane * 4;
    float s  = g[c] * rsqrtf(v[c] + EPS_);
    float sh = b2[c] - m[c] * s;
    float bias = cb[c];
    float4 r;
    r.x = fmaxf((a.x + d.x + bias) * s + sh, 0.f);
    r.y = fmaxf((a.y + d.y + bias) * s + sh, 0.f);
    r.z = fmaxf((a.z + d.z + bias) * s + sh, 0.f);
    r.w = fmaxf((a.w + d.w + bias) * s + sh, 0.f);
    size_t off = (size_t)img * CN_ + (size_t)c * N_ + p;
    if (MODE == 0) {
      float* ob = (img < 2) ? oA + off : oB + off - 2 * CN_;
      *(float4*)ob = r;
    } else {
      float4 rr = *(const float4*)(resid + off);
      r.x += rr.x; r.y += rr.y; r.z += rr.z; r.w += rr.w;
      *(float4*)(oA + off) = r;
    }
  }
}

// ------ cat = [xo+yo ; xo*yo] + bn2 -> fin, float4 ------------------------
__global__ void k_catbn(const float* __restrict__ o2,
                        const float* __restrict__ g, const float* __restrict__ b2,
                        const float* __restrict__ m, const float* __restrict__ v,
                        float* __restrict__ cat, float* __restrict__ fin,
                        size_t finStride) {
  int t = blockIdx.x * 256 + threadIdx.x;
  int p4 = t * 4;
  int n  = p4 % N_;
  int c2 = (p4 / N_) % (2 * C_);
  int b  = p4 / (2 * C_ * N_);
  int c  = c2 & 63;
  float4 X = *(const float4*)(o2 + (size_t)b * CN_ + (size_t)c * N_ + n);
  float4 Y = *(const float4*)(o2 + (size_t)(2 + b) * CN_ + (size_t)c * N_ + n);
  float4 val;
  if (c2 < C_) val = make_float4(X.x + Y.x, X.y + Y.y, X.z + Y.z, X.w + Y.w);
  else         val = make_float4(X.x * Y.x, X.y * Y.y, X.z * Y.z, X.w * Y.w);
  size_t co = ((size_t)b * 2 * C_ + c2) * N_ + n;
  *(float4*)(cat + co) = val;
  float s  = g[c2] * rsqrtf(v[c2] + EPS_);
  float sh = b2[c2] - m[c2] * s;
  *(float4*)(fin + (size_t)b * finStride + (size_t)c2 * N_ + n) =
      make_float4(val.x * s + sh, val.y * s + sh, val.z * s + sh, val.w * s + sh);
}

// ------ f-branch 3x3 conv partial (64-cin half), 2 couts + 4 px (R4) ------
// grid (9, C_, 2*B_), block 64. z: b = z&1, half = z>>1.
__global__ __launch_bounds__(64) void k_fconvs(
    const float* __restrict__ in, size_t inStride,
    const float* __restrict__ w,
    float* __restrict__ outA, size_t outStrideA,
    float* __restrict__ outB, size_t outStrideB) {
  __shared__ float bufs[2][384];
  int p0 = blockIdx.x * 256;
  int p = p0 + threadIdx.x * 4;
  int c0 = blockIdx.y * 2;
  int z = blockIdx.z;
  int b = z & 1, half = z >> 1;
  const float* ib = in + (size_t)b * inStride;
  float4 A0 = make_float4(0.f,0.f,0.f,0.f);
  float4 A1 = make_float4(0.f,0.f,0.f,0.f);
  conv_core3<2*C_, C_>(ib, w, c0, half * C_, p0, threadIdx.x, bufs, A0, A1);
  float* ob = (half ? outB + (size_t)b * outStrideB
                    : outA + (size_t)b * outStrideA)
              + (size_t)c0 * N_ + p;
  *(float4*)(ob)      = A0;
  *(float4*)(ob + N_) = A1;
}

// ------ combine halves + bn + relu, float4 (in-place into A ok) -----------
__global__ void k_comb(const float* __restrict__ pA, size_t strideA,
                       const float* __restrict__ pB, size_t strideB,
                       const float* __restrict__ g, const float* __restrict__ b2,
                       const float* __restrict__ m, const float* __restrict__ v,
                       float* __restrict__ out, size_t outStride) {
  int t = blockIdx.x * 256 + threadIdx.x;
  int p4 = t * 4;
  int n = p4 % N_;
  int c = (p4 / N_) % (2 * C_);
  int b = p4 / (2 * C_ * N_);
  size_t off = (size_t)c * N_ + n;
  float4 a = *(const float4*)(pA + (size_t)b * strideA + off);
  float4 d = *(const float4*)(pB + (size_t)b * strideB + off);
  float s  = g[c] * rsqrtf(v[c] + EPS_);
  float sh = b2[c] - m[c] * s;
  float4 r;
  r.x = fmaxf((a.x + d.x) * s + sh, 0.f);
  r.y = fmaxf((a.y + d.y) * s + sh, 0.f);
  r.z = fmaxf((a.z + d.z) * s + sh, 0.f);
  r.w = fmaxf((a.w + d.w) * s + sh, 0.f);
  *(float4*)(out + (size_t)b * outStride + off) = r;
}

// -------- final v2 (R4): 2 couts/block, fused comb(fbn2)+relu + cat add ---
__global__ __launch_bounds__(64) void k_final3(
    const float* __restrict__ pA, size_t strideA,
    const float* __restrict__ pB, size_t strideB,
    const float* __restrict__ g2, const float* __restrict__ b2,
    const float* __restrict__ m2, const float* __restrict__ v2,
    const float* __restrict__ cat,
    const float* __restrict__ w, const float* __restrict__ fb,
    float* __restrict__ out) {
  __shared__ float fsc[2 * C_], fsh[2 * C_];
  for (int j = threadIdx.x; j < 2 * C_; j += 64) {
    float s = g2[j] * rsqrtf(v2[j] + EPS_);
    fsc[j] = s;
    fsh[j] = b2[j] - m2[j] * s;
  }
  __syncthreads();
  int p = blockIdx.x * 128 + threadIdx.x * 2;
  int c0 = blockIdx.y * 2;
  int b = blockIdx.z;
  const float* frA = pA + (size_t)b * strideA;
  const float* frB = pB + (size_t)b * strideB;
  const float* wr0 = w + (size_t)c0 * 2 * C_;
  const float* wr1 = wr0 + 2 * C_;
  float a00 = fb[c0], a01 = a00;
  float a10 = fb[c0 + 1], a11 = a10;
#pragma unroll 4
  for (int j = 0; j < 2 * C_; ++j) {
    float2 fa = *(const float2*)(frA + (size_t)j * N_ + p);
    float2 fd = *(const float2*)(frB + (size_t)j * N_ + p);
    float s = fsc[j], sh = fsh[j];
    float f0 = fmaxf((fa.x + fd.x) * s + sh, 0.f);
    float f1 = fmaxf((fa.y + fd.y) * s + sh, 0.f);
    float wv0 = wr0[j], wv1 = wr1[j];
    a00 += wv0 * f0; a01 += wv0 * f1;
    a10 += wv1 * f0; a11 += wv1 * f1;
  }
  size_t o = ((size_t)b * 2 * C_ + c0) * N_ + p;
  float2 cv0 = *(const float2*)(cat + o);
  float2 cv1 = *(const float2*)(cat + o + N_);
  *(float2*)(out + o)      = make_float2(a00 + cv0.x, a01 + cv0.y);
  *(float2*)(out + o + N_) = make_float2(a10 + cv1.x, a11 + cv1.y);
}

extern "C" void kernel_launch(void* const* d_in, const int* in_sizes, int n_in,
                              void* d_out, int out_size, void* d_ws, size_t ws_size,
                              hipStream_t stream) {
  const float* x       = (const float*)d_in[0];
  const float* y       = (const float*)d_in[1];
  const float* pconv_w = (const float*)d_in[2];
  const float* pconv_b = (const float*)d_in[3];
  const float* bnd_g = (const float*)d_in[4];
  const float* bnd_b = (const float*)d_in[5];
  const float* bnd_m = (const float*)d_in[6];
  const float* bnd_v = (const float*)d_in[7];
  const float* lnx_g = (const float*)d_in[8];
  const float* lnx_b = (const float*)d_in[9];
  const float* lny_g = (const float*)d_in[10];
  const float* lny_b = (const float*)d_in[11];
  const float* lnz_g = (const float*)d_in[12];
  const float* lnz_b = (const float*)d_in[13];
  const float* k_w   = (const float*)d_in[14];
  const float* k_b   = (const float*)d_in[15];
  const float* qv_w  = (const float*)d_in[16];
  const float* qv_b  = (const float*)d_in[17];
  const float* proj_w = (const float*)d_in[18];
  const float* proj_b = (const float*)d_in[19];
  const float* c2w1  = (const float*)d_in[20];
  const float* c2b1  = (const float*)d_in[21];
  const float* c2bn1_g = (const float*)d_in[22];
  const float* c2bn1_b = (const float*)d_in[23];
  const float* c2bn1_m = (const float*)d_in[24];
  const float* c2bn1_v = (const float*)d_in[25];
  const float* c2w2  = (const float*)d_in[26];
  const float* c2b2  = (const float*)d_in[27];
  const float* c2bn2_g = (const float*)d_in[28];
  const float* c2bn2_b = (const float*)d_in[29];
  const float* c2bn2_m = (const float*)d_in[30];
  const float* c2bn2_v = (const float*)d_in[31];
  const float* bn2_g = (const float*)d_in[32];
  const float* bn2_b = (const float*)d_in[33];
  const float* bn2_m = (const float*)d_in[34];
  const float* bn2_v = (const float*)d_in[35];
  const float* f1w   = (const float*)d_in[36];
  const float* fbn1_g = (const float*)d_in[37];
  const float* fbn1_b = (const float*)d_in[38];
  const float* fbn1_m = (const float*)d_in[39];
  const float* fbn1_v = (const float*)d_in[40];
  const float* f2w   = (const float*)d_in[41];
  const float* fbn2_g = (const float*)d_in[42];
  const float* fbn2_b = (const float*)d_in[43];
  const float* fbn2_m = (const float*)d_in[44];
  const float* fbn2_v = (const float*)d_in[45];
  const float* f3w   = (const float*)d_in[46];
  const float* f3b   = (const float*)d_in[47];

  // Workspace plan:
  //   A: k_pre -> xl(1) yl(2) zl(3)
  //   B: qvk -> qx|qy(4), k(5), VT(6)
  //   C: attn8 -> att_xo(1) att_yo(2)
  //   D: proj3 -> xo4(3,4) [img*CN, imgs 0..3]
  //   E: convf<0> reads xo4(3,4) -> tmp imgs01(0), imgs23(7)
  //   F: convf<1> reads tmp + resid(3,4) -> o2(1,2) [img*CN]
  //   G: catbn reads o2(1,2) -> cat(3,4), fin b0->(0), b1->(7) [stride 7S]
  //   H1: fconvs f1: fin(0/7) -> half0 (1,2 stride S), half1 (5,6 stride S)
  //   H2: comb -> (1,2) in-place
  //   H3: fconvs f2: (1,2) -> half0 (5,6), half1 (0/7)
  //   I: final3 reads (5,6)+(0/7), cat(3,4) -> out
  float* ws = (float*)d_ws;
  float* sl0 = ws + 0 * S_;
  float* sl1 = ws + 1 * S_;
  float* sl2 = ws + 2 * S_;
  float* sl3 = ws + 3 * S_;
  float* sl4 = ws + 4 * S_;
  float* sl5 = ws + 5 * S_;
  float* sl7 = ws + 7 * S_;

  // A. fused pconv + bn + ln (v2: 16 rows/block)
  k_pre<<<B_ * N_ / 16, 1024, 0, stream>>>(x, y, pconv_w, pconv_b,
                                    bnd_g, bnd_b, bnd_m, bnd_v,
                                    lnx_g, lnx_b, lny_g, lny_b, lnz_g, lnz_b,
                                    sl1, sl2, sl3);
  // B. qv/k projection v2 -> bf16 attention operands
  u16* qxb = (u16*)sl4;
  u16* qyb = qxb + (size_t)B_ * NH_ * N_ * 8;
  u16* kbf = (u16*)sl5;
  u16* vtb = (u16*)(ws + 6 * S_);
  {
    dim3 g(B_ * N_ / 64, 20);
    k_qvk<<<g, 64, 0, stream>>>(sl1, sl2, sl3, qv_w, qv_b, k_w, k_b,
                                qxb, qyb, kbf, vtb);
  }
  // C. attention v8 (MFMA) -> att_xo(1), att_yo(2)
  {
    dim3 g(N_ / 16, B_ * NH_);
    k_attn8<<<g, 128, 0, stream>>>(qxb, qyb, kbf, vtb, sl1, sl2);
  }
  // D. proj v3 (LDS-staged) -> xo4(3,4)
  {
    dim3 g(36, C_ / 2, 2 * B_);
    k_proj3<<<g, 64, 0, stream>>>(sl1, x, y, bnd_g, bnd_b, bnd_m, bnd_v,
                                  proj_w, proj_b, sl3);
  }
  // E. conv1 (2-wave fused, split epilogue) -> tmp(0 / 7)
  {
    dim3 g(9, C_ / 2, 4);
    k_convf<0><<<g, 128, 0, stream>>>(sl3, sl3 + 2 * CN_, c2w1, c2b1,
        c2bn1_g, c2bn1_b, c2bn1_m, c2bn1_v, sl3, sl0, sl7);
  }
  // F. conv2 (2-wave fused + resid) -> o2(1,2)
  {
    dim3 g(9, C_ / 2, 4);
    k_convf<1><<<g, 128, 0, stream>>>(sl0, sl7, c2w2, c2b2,
        c2bn2_g, c2bn2_b, c2bn2_m, c2bn2_v, sl3, sl1, sl1);
  }
  // G. cat + bn2 -> cat(3,4), fin(0 / 7)
  k_catbn<<<576, 256, 0, stream>>>(sl1, bn2_g, bn2_b, bn2_m, bn2_v,
                                   sl3, sl0, 7 * S_);
  // H. f-branch convs (R4 separate kernels, measured-fastest)
  {
    dim3 g(9, C_, 2 * B_);
    k_fconvs<<<g, 64, 0, stream>>>(sl0, 7 * S_, f1w, sl1, S_, sl5, S_);
    k_comb<<<576, 256, 0, stream>>>(sl1, S_, sl5, S_,
                                    fbn1_g, fbn1_b, fbn1_m, fbn1_v, sl1, S_);
    k_fconvs<<<g, 64, 0, stream>>>(sl1, S_, f2w, sl5, S_, sl0, 7 * S_);
  }
  // I. final v2 (two-input, R4) -> fp32 out
  {
    dim3 g(18, C_, B_);
    k_final3<<<g, 64, 0, stream>>>(sl5, S_, sl0, 7 * S_,
                                   fbn2_g, fbn2_b, fbn2_m, fbn2_v,
                                   sl3, f3w, f3b, (float*)d_out);
  }
}

// Round 12
// 399.006 us; speedup vs baseline: 1.4164x; 1.0099x over previous
//
#include <hip/hip_runtime.h>
#include <hip/hip_bf16.h>

#define B_   2
#define C_   64
#define H_   48
#define W_   48
#define N_   (H_*W_)     // 2304
#define NH_  8
#define HD_  8
#define EPS_ 1e-5f
#define S2_  0.125f      // scale^2 = 1/hd
#define LOG2E_ 1.44269504f
#define FS_  (S2_ * LOG2E_)
#define S_   ((size_t)B_ * C_ * N_)   // 294912 floats per workspace slot
#define CN_  ((size_t)C_ * N_)        // 147456 floats per image
#define ROWP_ 52                      // padded LDS row stride (bank spread)
#define CBUF_ (8 * ROWP_)             // 416 floats per staging buffer

typedef unsigned short u16;
typedef __attribute__((ext_vector_type(8))) short short8v;
typedef __attribute__((ext_vector_type(4))) float f32x4;
union F8 { uint4 u4; short8v s; unsigned int w[4]; };

__device__ __forceinline__ float wsum64(float v) {
#pragma unroll
  for (int o = 32; o > 0; o >>= 1) v += __shfl_xor(v, o, 64);
  return v;
}

__device__ __forceinline__ float ln_val(float t, float g, float b) {
  float mu  = wsum64(t) * (1.0f / 64.0f);
  float d   = t - mu;
  float var = wsum64(d * d) * (1.0f / 64.0f);
  return d * rsqrtf(var + EPS_) * g + b;
}

// round-to-nearest-even f32 -> bf16 (finite inputs only)
__device__ __forceinline__ u16 f2bf(float x) {
  union { float f; unsigned int u; } a; a.f = x;
  unsigned int r = a.u + 0x7fffu + ((a.u >> 16) & 1u);
  return (u16)(r >> 16);
}

// ---- fused 1x1 pconv + BN + 3x LayerNorm; v2: 16 rows/block, LDS pw^T ----
__global__ __launch_bounds__(1024) void k_pre(
    const float* __restrict__ x, const float* __restrict__ y,
    const float* __restrict__ pw, const float* __restrict__ pb,
    const float* g, const float* bb, const float* m, const float* v,
    const float* lnxg, const float* lnxb,
    const float* lnyg, const float* lnyb,
    const float* lnzg, const float* lnzb,
    float* __restrict__ xl, float* __restrict__ yl, float* __restrict__ zl) {
  __shared__ float4 pwT[32][64];           // pwT[i4][c] = pw[c][4*i4..+3]
  __shared__ float xs[16][64], ys[16][64];
  int w = threadIdx.x >> 6, c = threadIdx.x & 63;
  for (int idx = threadIdx.x; idx < 2048; idx += 1024) {
    int cc = idx & 63, i4 = idx >> 6;
    pwT[i4][cc] = *(const float4*)(pw + (size_t)cc * 2 * C_ + i4 * 4);
  }
  int row = blockIdx.x * 16 + w;           // b*N + n
  int b = row / N_, n = row % N_;
  float xv = x[(size_t)(b * C_ + c) * N_ + n];
  float yv = y[(size_t)(b * C_ + c) * N_ + n];
  xs[w][c] = xv; ys[w][c] = yv;
  __syncthreads();
  const float4* xw = (const float4*)xs[w];
  const float4* yw = (const float4*)ys[w];
  float acc = pb[c];
#pragma unroll
  for (int t = 0; t < 16; ++t) {
    float4 a = xw[t], wv = pwT[t][c];
    acc += a.x * wv.x + a.y * wv.y + a.z * wv.z + a.w * wv.w;
  }
#pragma unroll
  for (int t = 0; t < 16; ++t) {
    float4 a = yw[t], wv = pwT[16 + t][c];
    acc += a.x * wv.x + a.y * wv.y + a.z * wv.z + a.w * wv.w;
  }
  float s  = g[c] * rsqrtf(v[c] + EPS_);
  float sh = bb[c] - m[c] * s;
  float tx = xv * s + sh;
  xl[(size_t)row * C_ + c] = ln_val(tx, lnxg[c], lnxb[c]);
  float ty = yv * s + sh;
  yl[(size_t)row * C_ + c] = ln_val(ty, lnyg[c], lnyb[c]);
  float tz = acc * s + sh;
  zl[(size_t)row * C_ + c] = ln_val(tz, lnzg[c], lnzb[c]);
}

// ------------- qv/k projection v2: lane = row, uniform weights ------------
__global__ __launch_bounds__(64) void k_qvk(
    const float* __restrict__ xl, const float* __restrict__ yl,
    const float* __restrict__ zl,
    const float* __restrict__ qvw, const float* __restrict__ qvb,
    const float* __restrict__ kw, const float* __restrict__ kb,
    u16* __restrict__ qxb, u16* __restrict__ qyb,
    u16* __restrict__ kbf, u16* __restrict__ vt) {
  int l = threadIdx.x;
  int part = blockIdx.y >> 2;
  int j0 = (blockIdx.y & 3) * 16;
  int row = blockIdx.x * 64 + l;
  int b = row / N_, n = row % N_;
  const float* inp = (part < 2) ? xl : (part < 4) ? yl : zl;
  float4 in[16];
  const float4* ir = (const float4*)(inp + (size_t)row * C_);
#pragma unroll
  for (int t = 0; t < 16; ++t) in[t] = ir[t];

  const float* wb   = (part == 4) ? kw : qvw;
  const float* bias = (part == 4) ? kb : qvb;
  int joff = (part == 1 || part == 3) ? 64 : 0;

  if (part == 1 || part == 3) {
    int vbase = (part == 1) ? 0 : 8;
#pragma unroll
    for (int jj = 0; jj < 16; ++jj) {
      int j = j0 + jj;
      const float4* wr = (const float4*)(wb + (size_t)(joff + j) * C_);
      float acc = bias[joff + j];
#pragma unroll
      for (int t = 0; t < 16; ++t) {
        float4 a = in[t], wv = wr[t];
        acc += a.x * wv.x + a.y * wv.y + a.z * wv.z + a.w * wv.w;
      }
      int h = j >> 3, d = j & 7;
      vt[((size_t)((b * NH_ + h) * 16 + vbase + d)) * N_ + n] = f2bf(acc);
    }
  } else {
    u16* dst = (part == 0) ? qxb : (part == 2) ? qyb : kbf;
#pragma unroll
    for (int gg = 0; gg < 2; ++gg) {
      int h = (j0 >> 3) + gg;
      union { uint4 u4; u16 s[8]; } pk;
#pragma unroll
      for (int d = 0; d < 8; ++d) {
        int j = h * 8 + d;
        const float4* wr = (const float4*)(wb + (size_t)(joff + j) * C_);
        float acc = bias[joff + j];
#pragma unroll
        for (int t = 0; t < 16; ++t) {
          float4 a = in[t], wv = wr[t];
          acc += a.x * wv.x + a.y * wv.y + a.z * wv.z + a.w * wv.w;
        }
        if (part == 0) acc *= FS_;
        pk.s[d] = f2bf(acc);
      }
      *(uint4*)(dst + ((size_t)(b * NH_ + h) * N_ + n) * 8) = pk.u4;
    }
  }
}

// ---------------- attention v8: MFMA flash, 16-q tile, dual-branch --------
__global__ __launch_bounds__(128, 5) void k_attn8(
    const u16* __restrict__ qx, const u16* __restrict__ qy,
    const u16* __restrict__ kk, const u16* __restrict__ vt,
    float* __restrict__ outx, float* __restrict__ outy) {
  __shared__ float sAcc[2][4][64];
  __shared__ float sL[2][16];
  int qt = blockIdx.x, bh = blockIdx.y;
  int tid = threadIdx.x;
  int lane = tid & 63;
  int wave = tid >> 6;
  int l15 = lane & 15;
  int q0 = qt * 16;

  F8 qxf, qyf;
  size_t qoff = ((size_t)bh * N_ + q0 + l15) * 8;
  qxf.u4 = *(const uint4*)(qx + qoff);
  qyf.u4 = *(const uint4*)(qy + qoff);
  if (lane >= 16) {
    qxf.u4 = make_uint4(0u, 0u, 0u, 0u);
    qyf.u4 = make_uint4(0u, 0u, 0u, 0u);
  }

  int key0 = wave * (N_ / 2);
  const uint4* kp = (const uint4*)(kk + (size_t)bh * N_ * 8) + key0 + l15;
  const uint4* vp = (const uint4*)(vt + ((size_t)bh * 16 + l15) * N_ + key0)
                    + (lane >> 4);
  int addr0 = (((lane >> 4) & 1) * 32 + l15) * 4;
  int addr1 = addr0 + 64;
  int thi = lane >> 5;

  f32x4 acc = {0.f, 0.f, 0.f, 0.f};
  const f32x4 z4 = {0.f, 0.f, 0.f, 0.f};
  float lsum = 0.f;

  F8 ka, kb2, vf;
  ka.u4 = kp[0]; kb2.u4 = kp[16]; vf.u4 = *vp;
  for (int c = 0; c < 36; ++c) {
    F8 kaC = ka, kbC = kb2, vfC = vf;
    kp += 32; vp += 4;
    ka.u4 = kp[0]; kb2.u4 = kp[16]; vf.u4 = *vp;   // prefetch next chunk

    f32x4 s1a = __builtin_amdgcn_mfma_f32_16x16x32_bf16(kaC.s, qxf.s, z4, 0, 0, 0);
    f32x4 s2a = __builtin_amdgcn_mfma_f32_16x16x32_bf16(kaC.s, qyf.s, z4, 0, 0, 0);
    f32x4 s1b = __builtin_amdgcn_mfma_f32_16x16x32_bf16(kbC.s, qxf.s, z4, 0, 0, 0);
    f32x4 s2b = __builtin_amdgcn_mfma_f32_16x16x32_bf16(kbC.s, qyf.s, z4, 0, 0, 0);

    float p00 = exp2f(s1a[0] * s2a[0]), p01 = exp2f(s1a[1] * s2a[1]);
    float p02 = exp2f(s1a[2] * s2a[2]), p03 = exp2f(s1a[3] * s2a[3]);
    float p10 = exp2f(s1b[0] * s2b[0]), p11 = exp2f(s1b[1] * s2b[1]);
    float p12 = exp2f(s1b[2] * s2b[2]), p13 = exp2f(s1b[3] * s2b[3]);
    lsum += ((p00 + p01) + (p02 + p03)) + ((p10 + p11) + (p12 + p13));

    unsigned int pk00, pk10, pk01, pk11;
    asm("v_cvt_pk_bf16_f32 %0, %1, %2" : "=v"(pk00) : "v"(p00), "v"(p01));
    asm("v_cvt_pk_bf16_f32 %0, %1, %2" : "=v"(pk10) : "v"(p02), "v"(p03));
    asm("v_cvt_pk_bf16_f32 %0, %1, %2" : "=v"(pk01) : "v"(p10), "v"(p11));
    asm("v_cvt_pk_bf16_f32 %0, %1, %2" : "=v"(pk11) : "v"(p12), "v"(p13));

    int b00 = __builtin_amdgcn_ds_bpermute(addr0, (int)pk00);
    int b01 = __builtin_amdgcn_ds_bpermute(addr0, (int)pk01);
    int b10 = __builtin_amdgcn_ds_bpermute(addr0, (int)pk10);
    int b11 = __builtin_amdgcn_ds_bpermute(addr0, (int)pk11);
    int c00 = __builtin_amdgcn_ds_bpermute(addr1, (int)pk00);
    int c01 = __builtin_amdgcn_ds_bpermute(addr1, (int)pk01);
    int c10 = __builtin_amdgcn_ds_bpermute(addr1, (int)pk10);
    int c11 = __builtin_amdgcn_ds_bpermute(addr1, (int)pk11);

    F8 pf;
    pf.w[0] = (unsigned int)(thi ? b01 : b00);
    pf.w[1] = (unsigned int)(thi ? b11 : b10);
    pf.w[2] = (unsigned int)(thi ? c01 : c00);
    pf.w[3] = (unsigned int)(thi ? c11 : c10);
    acc = __builtin_amdgcn_mfma_f32_16x16x32_bf16(pf.s, vfC.s, acc, 0, 0, 0);
  }

  lsum += __shfl_xor(lsum, 16, 64);
  lsum += __shfl_xor(lsum, 32, 64);
  if (lane < 16) sL[wave][lane] = lsum;
#pragma unroll
  for (int r = 0; r < 4; ++r) sAcc[wave][r][lane] = acc[r];
  __syncthreads();
  if (wave == 0) {
    float Linv = 1.f / (sL[0][l15] + sL[1][l15]);
    int b = bh >> 3, h = bh & 7;
    int d = l15 & 7;
    float* ob = (l15 < 8) ? outx : outy;
    size_t cbase = (size_t)b * N_ * C_ + (size_t)h * 8 + d;
#pragma unroll
    for (int r = 0; r < 4; ++r) {
      int qrow = 4 * (lane >> 4) + r;
      float li = __shfl(Linv, qrow, 64);
      float a = sAcc[0][r][lane] + sAcc[1][r][lane];
      ob[cbase + (size_t)(q0 + qrow) * C_] = a * li;
    }
  }
}

// -------- proj v3: LDS-transposed att tile, conflict-free reads -----------
// grid (36, C_/2, 2*B_), block 64. Block = 64 px, 2 couts.
__global__ __launch_bounds__(64) void k_proj3(
    const float* __restrict__ attbase,
    const float* __restrict__ x, const float* __restrict__ y,
    const float* bg, const float* bb2, const float* bm, const float* bv,
    const float* __restrict__ pw, const float* __restrict__ pbias,
    float* __restrict__ outbase) {
  __shared__ float attT[64][66];   // attT[c][r] = att[p0+r][c]
  int tid = threadIdx.x;
  int p0 = blockIdx.x * 64;
  int c0 = blockIdx.y * 2;
  int z = blockIdx.z;
  int branch = z >> 1, b = z & 1;
  const float* att = attbase + branch * S_ + (size_t)b * N_ * C_;
  for (int r = 0; r < 64; ++r)
    attT[tid][r] = att[(size_t)(p0 + r) * C_ + tid];
  __syncthreads();
  int p = p0 + tid;
  const float* w0 = pw + (size_t)c0 * C_;
  const float* w1 = w0 + C_;
  float a0 = pbias[c0], a1 = pbias[c0 + 1];
#pragma unroll 8
  for (int c = 0; c < C_; ++c) {
    float av = attT[c][tid];
    a0 += av * w0[c];
    a1 += av * w1[c];
  }
  float s0  = bg[c0] * rsqrtf(bv[c0] + EPS_);
  float sh0 = bb2[c0] - bm[c0] * s0;
  float s1  = bg[c0+1] * rsqrtf(bv[c0+1] + EPS_);
  float sh1 = bb2[c0+1] - bm[c0+1] * s1;
  const float* xin = branch ? y : x;
  float r0 = xin[((size_t)b * C_ + c0) * N_ + p];
  float r1 = xin[((size_t)b * C_ + c0 + 1) * N_ + p];
  size_t o = (size_t)z * CN_ + (size_t)c0 * N_ + p;
  outbase[o]      = a0 + r0 * s0 + sh0;
  outbase[o + N_] = a1 + r1 * s1 + sh1;
}

// ===== conv core v3p: proven v3 skeleton, LDS rows padded to 52 ===========
// Identical math/order to v3; only LDS addressing uses ROWP_ stride so the
// 8 row bases land on 8 distinct banks (kills edge-read conflicts).
// Guards okL/okR keep all reads inside the 48 valid columns.
template<int CIN, int CIPB>
__device__ __forceinline__ void conv_core3(
    const float* __restrict__ ib, const float* __restrict__ w,
    int c0, int ci0, int p0, int tid, float (*bufs)[CBUF_],
    float4& A0, float4& A1) {
  const float* w0r = w + ((size_t)c0 * CIN + ci0) * 9;
  const float* w1r = w0r + (size_t)CIN * 9;
  int p  = p0 + tid * 4;
  int yy0 = p0 / W_;
  int yy = p / W_, x0 = p - yy * W_;
  int lr = yy - yy0;                     // 0..5 ; +ky in 0..7
  bool okL = x0 > 0, okR = x0 + 4 < W_;

  int rf0 = tid / 12, cf0 = tid - rf0 * 12;
  int gy0 = yy0 - 1 + rf0;
  int rf1 = (64 + tid) / 12, cf1 = (64 + tid) - rf1 * 12;
  int gy1 = yy0 - 1 + rf1;
  bool v0 = (unsigned)gy0 < (unsigned)H_;
  bool v1 = (tid < 32) && ((unsigned)gy1 < (unsigned)H_);
  int o0 = gy0 * W_ + cf0 * 4;
  int o1 = gy1 * W_ + cf1 * 4;
  int lo0 = rf0 * ROWP_ + cf0 * 4;
  int lo1 = rf1 * ROWP_ + cf1 * 4;
  const float4 zz = make_float4(0.f, 0.f, 0.f, 0.f);

  {
    const float* s = ib + (size_t)ci0 * N_;
    float4 ga = v0 ? *(const float4*)(s + o0) : zz;
    *(float4*)(&bufs[0][lo0]) = ga;
    if (tid < 32) {
      float4 gb = v1 ? *(const float4*)(s + o1) : zz;
      *(float4*)(&bufs[0][lo1]) = gb;
    }
  }
  float wc[18];
#pragma unroll
  for (int i = 0; i < 9; ++i) { wc[i] = w0r[i]; wc[9 + i] = w1r[i]; }

#pragma unroll 2
  for (int ci = 0; ci < CIPB; ++ci) {
    float4 ga = zz, gb = zz;
    float wn[18];
    if (ci + 1 < CIPB) {
      const float* s = ib + (size_t)(ci0 + ci + 1) * N_;
      ga = v0 ? *(const float4*)(s + o0) : zz;
      gb = v1 ? *(const float4*)(s + o1) : zz;
      const float* nw0 = w0r + (ci + 1) * 9;
      const float* nw1 = w1r + (ci + 1) * 9;
#pragma unroll
      for (int i = 0; i < 9; ++i) { wn[i] = nw0[i]; wn[9 + i] = nw1[i]; }
    }
    const float* bc = bufs[ci & 1];
#pragma unroll
    for (int ky = 0; ky < 3; ++ky) {
      int base = (lr + ky) * ROWP_ + x0;
      float4 mid = *(const float4*)(bc + base);
      float l = okL ? bc[base - 1] : 0.f;
      float r = okR ? bc[base + 4] : 0.f;
      float u0 = wc[ky*3], u1 = wc[ky*3+1], u2 = wc[ky*3+2];
      float t0 = wc[9+ky*3], t1 = wc[9+ky*3+1], t2 = wc[9+ky*3+2];
      A0.x += l     * u0 + mid.x * u1 + mid.y * u2;
      A0.y += mid.x * u0 + mid.y * u1 + mid.z * u2;
      A0.z += mid.y * u0 + mid.z * u1 + mid.w * u2;
      A0.w += mid.z * u0 + mid.w * u1 + r     * u2;
      A1.x += l     * t0 + mid.x * t1 + mid.y * t2;
      A1.y += mid.x * t0 + mid.y * t1 + mid.z * t2;
      A1.z += mid.y * t0 + mid.z * t1 + mid.w * t2;
      A1.w += mid.z * t0 + mid.w * t1 + r     * t2;
    }
    if (ci + 1 < CIPB) {
      float* d = bufs[(ci + 1) & 1];
      *(float4*)(&d[lo0]) = ga;
      if (tid < 32) *(float4*)(&d[lo1]) = gb;
#pragma unroll
      for (int i = 0; i < 18; ++i) wc[i] = wn[i];
    }
  }
}

// ===== 2-wave conv (CIN=64): waves split cin halves; epilogue split too ===
// grid (9, C_/2, 4 imgs), block 128.
template<int MODE>
__global__ __launch_bounds__(128) void k_convf(
    const float* __restrict__ inA, const float* __restrict__ inB,
    const float* __restrict__ w, const float* __restrict__ cb,
    const float* g, const float* b2, const float* m, const float* v,
    const float* __restrict__ resid,
    float* __restrict__ oA, float* __restrict__ oB) {
  __shared__ float lds[2 * 2 * CBUF_ + 512];
  int tid = threadIdx.x, wave = tid >> 6, lane = tid & 63;
  int tile = blockIdx.x, c0 = blockIdx.y * 2, img = blockIdx.z;
  const float* ib = (img < 2) ? inA + (size_t)img * CN_
                              : inB + (size_t)(img - 2) * CN_;
  float (*mybufs)[CBUF_] = (float(*)[CBUF_])(lds + wave * 2 * CBUF_);
  float* comb = lds + 4 * CBUF_;
  float4 A0 = make_float4(0.f,0.f,0.f,0.f);
  float4 A1 = make_float4(0.f,0.f,0.f,0.f);
  conv_core3<C_, C_/2>(ib, w, c0, wave * (C_/2), tile * 256, lane, mybufs,
                       A0, A1);
  float* cw = comb + wave * 256 + lane * 4;
  *(float4*)cw = wave ? A0 : A1;
  __syncthreads();
  {
    int c = c0 + wave;
    const float4 other = *(const float4*)(comb + (1 - wave) * 256 + lane * 4);
    float4 a = wave ? other : A0;    // cin 0..31 half
    float4 d = wave ? A1 : other;    // cin 32..63 half
    int p = tile * 256 + lane * 4;
    float s  = g[c] * rsqrtf(v[c] + EPS_);
    float sh = b2[c] - m[c] * s;
    float bias = cb[c];
    float4 r;
    r.x = fmaxf((a.x + d.x + bias) * s + sh, 0.f);
    r.y = fmaxf((a.y + d.y + bias) * s + sh, 0.f);
    r.z = fmaxf((a.z + d.z + bias) * s + sh, 0.f);
    r.w = fmaxf((a.w + d.w + bias) * s + sh, 0.f);
    size_t off = (size_t)img * CN_ + (size_t)c * N_ + p;
    if (MODE == 0) {
      float* ob = (img < 2) ? oA + off : oB + off - 2 * CN_;
      *(float4*)ob = r;
    } else {
      float4 rr = *(const float4*)(resid + off);
      r.x += rr.x; r.y += rr.y; r.z += rr.z; r.w += rr.w;
      *(float4*)(oA + off) = r;
    }
  }
}

// ------ cat = [xo+yo ; xo*yo] + bn2 -> fin, float4 ------------------------
__global__ void k_catbn(const float* __restrict__ o2,
                        const float* __restrict__ g, const float* __restrict__ b2,
                        const float* __restrict__ m, const float* __restrict__ v,
                        float* __restrict__ cat, float* __restrict__ fin,
                        size_t finStride) {
  int t = blockIdx.x * 256 + threadIdx.x;
  int p4 = t * 4;
  int n  = p4 % N_;
  int c2 = (p4 / N_) % (2 * C_);
  int b  = p4 / (2 * C_ * N_);
  int c  = c2 & 63;
  float4 X = *(const float4*)(o2 + (size_t)b * CN_ + (size_t)c * N_ + n);
  float4 Y = *(const float4*)(o2 + (size_t)(2 + b) * CN_ + (size_t)c * N_ + n);
  float4 val;
  if (c2 < C_) val = make_float4(X.x + Y.x, X.y + Y.y, X.z + Y.z, X.w + Y.w);
  else         val = make_float4(X.x * Y.x, X.y * Y.y, X.z * Y.z, X.w * Y.w);
  size_t co = ((size_t)b * 2 * C_ + c2) * N_ + n;
  *(float4*)(cat + co) = val;
  float s  = g[c2] * rsqrtf(v[c2] + EPS_);
  float sh = b2[c2] - m[c2] * s;
  *(float4*)(fin + (size_t)b * finStride + (size_t)c2 * N_ + n) =
      make_float4(val.x * s + sh, val.y * s + sh, val.z * s + sh, val.w * s + sh);
}

// ------ f-branch 3x3 conv partial (64-cin half), 2 couts + 4 px (R4) ------
// grid (9, C_, 2*B_), block 64. z: b = z&1, half = z>>1.
__global__ __launch_bounds__(64) void k_fconvs(
    const float* __restrict__ in, size_t inStride,
    const float* __restrict__ w,
    float* __restrict__ outA, size_t outStrideA,
    float* __restrict__ outB, size_t outStrideB) {
  __shared__ float bufs[2][CBUF_];
  int p0 = blockIdx.x * 256;
  int p = p0 + threadIdx.x * 4;
  int c0 = blockIdx.y * 2;
  int z = blockIdx.z;
  int b = z & 1, half = z >> 1;
  const float* ib = in + (size_t)b * inStride;
  float4 A0 = make_float4(0.f,0.f,0.f,0.f);
  float4 A1 = make_float4(0.f,0.f,0.f,0.f);
  conv_core3<2*C_, C_>(ib, w, c0, half * C_, p0, threadIdx.x, bufs, A0, A1);
  float* ob = (half ? outB + (size_t)b * outStrideB
                    : outA + (size_t)b * outStrideA)
              + (size_t)c0 * N_ + p;
  *(float4*)(ob)      = A0;
  *(float4*)(ob + N_) = A1;
}

// ------ combine halves + bn + relu, float4 (in-place into A ok) -----------
__global__ void k_comb(const float* __restrict__ pA, size_t strideA,
                       const float* __restrict__ pB, size_t strideB,
                       const float* __restrict__ g, const float* __restrict__ b2,
                       const float* __restrict__ m, const float* __restrict__ v,
                       float* __restrict__ out, size_t outStride) {
  int t = blockIdx.x * 256 + threadIdx.x;
  int p4 = t * 4;
  int n = p4 % N_;
  int c = (p4 / N_) % (2 * C_);
  int b = p4 / (2 * C_ * N_);
  size_t off = (size_t)c * N_ + n;
  float4 a = *(const float4*)(pA + (size_t)b * strideA + off);
  float4 d = *(const float4*)(pB + (size_t)b * strideB + off);
  float s  = g[c] * rsqrtf(v[c] + EPS_);
  float sh = b2[c] - m[c] * s;
  float4 r;
  r.x = fmaxf((a.x + d.x) * s + sh, 0.f);
  r.y = fmaxf((a.y + d.y) * s + sh, 0.f);
  r.z = fmaxf((a.z + d.z) * s + sh, 0.f);
  r.w = fmaxf((a.w + d.w) * s + sh, 0.f);
  *(float4*)(out + (size_t)b * outStride + off) = r;
}

// -------- final v2 (R4): 2 couts/block, fused comb(fbn2)+relu + cat add ---
__global__ __launch_bounds__(64) void k_final3(
    const float* __restrict__ pA, size_t strideA,
    const float* __restrict__ pB, size_t strideB,
    const float* __restrict__ g2, const float* __restrict__ b2,
    const float* __restrict__ m2, const float* __restrict__ v2,
    const float* __restrict__ cat,
    const float* __restrict__ w, const float* __restrict__ fb,
    float* __restrict__ out) {
  __shared__ float fsc[2 * C_], fsh[2 * C_];
  for (int j = threadIdx.x; j < 2 * C_; j += 64) {
    float s = g2[j] * rsqrtf(v2[j] + EPS_);
    fsc[j] = s;
    fsh[j] = b2[j] - m2[j] * s;
  }
  __syncthreads();
  int p = blockIdx.x * 128 + threadIdx.x * 2;
  int c0 = blockIdx.y * 2;
  int b = blockIdx.z;
  const float* frA = pA + (size_t)b * strideA;
  const float* frB = pB + (size_t)b * strideB;
  const float* wr0 = w + (size_t)c0 * 2 * C_;
  const float* wr1 = wr0 + 2 * C_;
  float a00 = fb[c0], a01 = a00;
  float a10 = fb[c0 + 1], a11 = a10;
#pragma unroll 4
  for (int j = 0; j < 2 * C_; ++j) {
    float2 fa = *(const float2*)(frA + (size_t)j * N_ + p);
    float2 fd = *(const float2*)(frB + (size_t)j * N_ + p);
    float s = fsc[j], sh = fsh[j];
    float f0 = fmaxf((fa.x + fd.x) * s + sh, 0.f);
    float f1 = fmaxf((fa.y + fd.y) * s + sh, 0.f);
    float wv0 = wr0[j], wv1 = wr1[j];
    a00 += wv0 * f0; a01 += wv0 * f1;
    a10 += wv1 * f0; a11 += wv1 * f1;
  }
  size_t o = ((size_t)b * 2 * C_ + c0) * N_ + p;
  float2 cv0 = *(const float2*)(cat + o);
  float2 cv1 = *(const float2*)(cat + o + N_);
  *(float2*)(out + o)      = make_float2(a00 + cv0.x, a01 + cv0.y);
  *(float2*)(out + o + N_) = make_float2(a10 + cv1.x, a11 + cv1.y);
}

extern "C" void kernel_launch(void* const* d_in, const int* in_sizes, int n_in,
                              void* d_out, int out_size, void* d_ws, size_t ws_size,
                              hipStream_t stream) {
  const float* x       = (const float*)d_in[0];
  const float* y       = (const float*)d_in[1];
  const float* pconv_w = (const float*)d_in[2];
  const float* pconv_b = (const float*)d_in[3];
  const float* bnd_g = (const float*)d_in[4];
  const float* bnd_b = (const float*)d_in[5];
  const float* bnd_m = (const float*)d_in[6];
  const float* bnd_v = (const float*)d_in[7];
  const float* lnx_g = (const float*)d_in[8];
  const float* lnx_b = (const float*)d_in[9];
  const float* lny_g = (const float*)d_in[10];
  const float* lny_b = (const float*)d_in[11];
  const float* lnz_g = (const float*)d_in[12];
  const float* lnz_b = (const float*)d_in[13];
  const float* k_w   = (const float*)d_in[14];
  const float* k_b   = (const float*)d_in[15];
  const float* qv_w  = (const float*)d_in[16];
  const float* qv_b  = (const float*)d_in[17];
  const float* proj_w = (const float*)d_in[18];
  const float* proj_b = (const float*)d_in[19];
  const float* c2w1  = (const float*)d_in[20];
  const float* c2b1  = (const float*)d_in[21];
  const float* c2bn1_g = (const float*)d_in[22];
  const float* c2bn1_b = (const float*)d_in[23];
  const float* c2bn1_m = (const float*)d_in[24];
  const float* c2bn1_v = (const float*)d_in[25];
  const float* c2w2  = (const float*)d_in[26];
  const float* c2b2  = (const float*)d_in[27];
  const float* c2bn2_g = (const float*)d_in[28];
  const float* c2bn2_b = (const float*)d_in[29];
  const float* c2bn2_m = (const float*)d_in[30];
  const float* c2bn2_v = (const float*)d_in[31];
  const float* bn2_g = (const float*)d_in[32];
  const float* bn2_b = (const float*)d_in[33];
  const float* bn2_m = (const float*)d_in[34];
  const float* bn2_v = (const float*)d_in[35];
  const float* f1w   = (const float*)d_in[36];
  const float* fbn1_g = (const float*)d_in[37];
  const float* fbn1_b = (const float*)d_in[38];
  const float* fbn1_m = (const float*)d_in[39];
  const float* fbn1_v = (const float*)d_in[40];
  const float* f2w   = (const float*)d_in[41];
  const float* fbn2_g = (const float*)d_in[42];
  const float* fbn2_b = (const float*)d_in[43];
  const float* fbn2_m = (const float*)d_in[44];
  const float* fbn2_v = (const float*)d_in[45];
  const float* f3w   = (const float*)d_in[46];
  const float* f3b   = (const float*)d_in[47];

  // Workspace plan (unchanged from R10):
  //   A: k_pre -> xl(1) yl(2) zl(3)
  //   B: qvk -> qx|qy(4), k(5), VT(6)
  //   C: attn8 -> att_xo(1) att_yo(2)
  //   D: proj3 -> xo4(3,4) [img*CN, imgs 0..3]
  //   E: convf<0> reads xo4(3,4) -> tmp imgs01(0), imgs23(7)
  //   F: convf<1> reads tmp + resid(3,4) -> o2(1,2) [img*CN]
  //   G: catbn reads o2(1,2) -> cat(3,4), fin b0->(0), b1->(7) [stride 7S]
  //   H1: fconvs f1: fin(0/7) -> half0 (1,2 stride S), half1 (5,6 stride S)
  //   H2: comb -> (1,2) in-place
  //   H3: fconvs f2: (1,2) -> half0 (5,6), half1 (0/7)
  //   I: final3 reads (5,6)+(0/7), cat(3,4) -> out
  float* ws = (float*)d_ws;
  float* sl0 = ws + 0 * S_;
  float* sl1 = ws + 1 * S_;
  float* sl2 = ws + 2 * S_;
  float* sl3 = ws + 3 * S_;
  float* sl4 = ws + 4 * S_;
  float* sl5 = ws + 5 * S_;
  float* sl7 = ws + 7 * S_;

  // A. fused pconv + bn + ln (v2: 16 rows/block)
  k_pre<<<B_ * N_ / 16, 1024, 0, stream>>>(x, y, pconv_w, pconv_b,
                                    bnd_g, bnd_b, bnd_m, bnd_v,
                                    lnx_g, lnx_b, lny_g, lny_b, lnz_g, lnz_b,
                                    sl1, sl2, sl3);
  // B. qv/k projection v2 -> bf16 attention operands
  u16* qxb = (u16*)sl4;
  u16* qyb = qxb + (size_t)B_ * NH_ * N_ * 8;
  u16* kbf = (u16*)sl5;
  u16* vtb = (u16*)(ws + 6 * S_);
  {
    dim3 g(B_ * N_ / 64, 20);
    k_qvk<<<g, 64, 0, stream>>>(sl1, sl2, sl3, qv_w, qv_b, k_w, k_b,
                                qxb, qyb, kbf, vtb);
  }
  // C. attention v8 (MFMA) -> att_xo(1), att_yo(2)
  {
    dim3 g(N_ / 16, B_ * NH_);
    k_attn8<<<g, 128, 0, stream>>>(qxb, qyb, kbf, vtb, sl1, sl2);
  }
  // D. proj v3 (LDS-staged) -> xo4(3,4)
  {
    dim3 g(36, C_ / 2, 2 * B_);
    k_proj3<<<g, 64, 0, stream>>>(sl1, x, y, bnd_g, bnd_b, bnd_m, bnd_v,
                                  proj_w, proj_b, sl3);
  }
  // E. conv1 (2-wave fused, split epilogue) -> tmp(0 / 7)
  {
    dim3 g(9, C_ / 2, 4);
    k_convf<0><<<g, 128, 0, stream>>>(sl3, sl3 + 2 * CN_, c2w1, c2b1,
        c2bn1_g, c2bn1_b, c2bn1_m, c2bn1_v, sl3, sl0, sl7);
  }
  // F. conv2 (2-wave fused + resid) -> o2(1,2)
  {
    dim3 g(9, C_ / 2, 4);
    k_convf<1><<<g, 128, 0, stream>>>(sl0, sl7, c2w2, c2b2,
        c2bn2_g, c2bn2_b, c2bn2_m, c2bn2_v, sl3, sl1, sl1);
  }
  // G. cat + bn2 -> cat(3,4), fin(0 / 7)
  k_catbn<<<576, 256, 0, stream>>>(sl1, bn2_g, bn2_b, bn2_m, bn2_v,
                                   sl3, sl0, 7 * S_);
  // H. f-branch convs (R4 separate kernels, padded core)
  {
    dim3 g(9, C_, 2 * B_);
    k_fconvs<<<g, 64, 0, stream>>>(sl0, 7 * S_, f1w, sl1, S_, sl5, S_);
    k_comb<<<576, 256, 0, stream>>>(sl1, S_, sl5, S_,
                                    fbn1_g, fbn1_b, fbn1_m, fbn1_v, sl1, S_);
    k_fconvs<<<g, 64, 0, stream>>>(sl1, S_, f2w, sl5, S_, sl0, 7 * S_);
  }
  // I. final v2 (two-input, R4) -> fp32 out
  {
    dim3 g(18, C_, B_);
    k_final3<<<g, 64, 0, stream>>>(sl5, S_, sl0, 7 * S_,
                                   fbn2_g, fbn2_b, fbn2_m, fbn2_v,
                                   sl3, f3w, f3b, (float*)d_out);
  }
}

// Round 13
// 357.051 us; speedup vs baseline: 1.5829x; 1.1175x over previous
//
#include <hip/hip_runtime.h>
#include <hip/hip_bf16.h>

#define B_   2
#define C_   64
#define H_   48
#define W_   48
#define N_   (H_*W_)     // 2304
#define NH_  8
#define HD_  8
#define EPS_ 1e-5f
#define S2_  0.125f      // scale^2 = 1/hd
#define LOG2E_ 1.44269504f
#define FS_  (S2_ * LOG2E_)
#define S_   ((size_t)B_ * C_ * N_)   // 294912 floats per workspace slot
#define CN_  ((size_t)C_ * N_)        // 147456 floats per image
#define ROWP_ 52                      // padded LDS row stride
#define CBUF_ (8 * ROWP_)             // 416 floats per staging buffer
#define XTSZ_ ((N_ + 2 * W_) * 128)   // 307200 bf16 per image (w/ guards)

typedef unsigned short u16;
typedef __attribute__((ext_vector_type(8))) short short8v;
typedef __attribute__((ext_vector_type(4))) float f32x4;
union F8 { uint4 u4; short8v s; unsigned int w[4]; };

__device__ __forceinline__ float wsum64(float v) {
#pragma unroll
  for (int o = 32; o > 0; o >>= 1) v += __shfl_xor(v, o, 64);
  return v;
}

__device__ __forceinline__ float ln_val(float t, float g, float b) {
  float mu  = wsum64(t) * (1.0f / 64.0f);
  float d   = t - mu;
  float var = wsum64(d * d) * (1.0f / 64.0f);
  return d * rsqrtf(var + EPS_) * g + b;
}

// round-to-nearest-even f32 -> bf16 (finite inputs only)
__device__ __forceinline__ u16 f2bf(float x) {
  union { float f; unsigned int u; } a; a.f = x;
  unsigned int r = a.u + 0x7fffu + ((a.u >> 16) & 1u);
  return (u16)(r >> 16);
}

// ---- fused 1x1 pconv + BN + 3x LayerNorm; v2: 16 rows/block, LDS pw^T ----
__global__ __launch_bounds__(1024) void k_pre(
    const float* __restrict__ x, const float* __restrict__ y,
    const float* __restrict__ pw, const float* __restrict__ pb,
    const float* g, const float* bb, const float* m, const float* v,
    const float* lnxg, const float* lnxb,
    const float* lnyg, const float* lnyb,
    const float* lnzg, const float* lnzb,
    float* __restrict__ xl, float* __restrict__ yl, float* __restrict__ zl) {
  __shared__ float4 pwT[32][64];           // pwT[i4][c] = pw[c][4*i4..+3]
  __shared__ float xs[16][64], ys[16][64];
  int w = threadIdx.x >> 6, c = threadIdx.x & 63;
  for (int idx = threadIdx.x; idx < 2048; idx += 1024) {
    int cc = idx & 63, i4 = idx >> 6;
    pwT[i4][cc] = *(const float4*)(pw + (size_t)cc * 2 * C_ + i4 * 4);
  }
  int row = blockIdx.x * 16 + w;           // b*N + n
  int b = row / N_, n = row % N_;
  float xv = x[(size_t)(b * C_ + c) * N_ + n];
  float yv = y[(size_t)(b * C_ + c) * N_ + n];
  xs[w][c] = xv; ys[w][c] = yv;
  __syncthreads();
  const float4* xw = (const float4*)xs[w];
  const float4* yw = (const float4*)ys[w];
  float acc = pb[c];
#pragma unroll
  for (int t = 0; t < 16; ++t) {
    float4 a = xw[t], wv = pwT[t][c];
    acc += a.x * wv.x + a.y * wv.y + a.z * wv.z + a.w * wv.w;
  }
#pragma unroll
  for (int t = 0; t < 16; ++t) {
    float4 a = yw[t], wv = pwT[16 + t][c];
    acc += a.x * wv.x + a.y * wv.y + a.z * wv.z + a.w * wv.w;
  }
  float s  = g[c] * rsqrtf(v[c] + EPS_);
  float sh = bb[c] - m[c] * s;
  float tx = xv * s + sh;
  xl[(size_t)row * C_ + c] = ln_val(tx, lnxg[c], lnxb[c]);
  float ty = yv * s + sh;
  yl[(size_t)row * C_ + c] = ln_val(ty, lnyg[c], lnyb[c]);
  float tz = acc * s + sh;
  zl[(size_t)row * C_ + c] = ln_val(tz, lnzg[c], lnzb[c]);
}

// ------------- qv/k projection v2: lane = row, uniform weights ------------
__global__ __launch_bounds__(64) void k_qvk(
    const float* __restrict__ xl, const float* __restrict__ yl,
    const float* __restrict__ zl,
    const float* __restrict__ qvw, const float* __restrict__ qvb,
    const float* __restrict__ kw, const float* __restrict__ kb,
    u16* __restrict__ qxb, u16* __restrict__ qyb,
    u16* __restrict__ kbf, u16* __restrict__ vt) {
  int l = threadIdx.x;
  int part = blockIdx.y >> 2;
  int j0 = (blockIdx.y & 3) * 16;
  int row = blockIdx.x * 64 + l;
  int b = row / N_, n = row % N_;
  const float* inp = (part < 2) ? xl : (part < 4) ? yl : zl;
  float4 in[16];
  const float4* ir = (const float4*)(inp + (size_t)row * C_);
#pragma unroll
  for (int t = 0; t < 16; ++t) in[t] = ir[t];

  const float* wb   = (part == 4) ? kw : qvw;
  const float* bias = (part == 4) ? kb : qvb;
  int joff = (part == 1 || part == 3) ? 64 : 0;

  if (part == 1 || part == 3) {
    int vbase = (part == 1) ? 0 : 8;
#pragma unroll
    for (int jj = 0; jj < 16; ++jj) {
      int j = j0 + jj;
      const float4* wr = (const float4*)(wb + (size_t)(joff + j) * C_);
      float acc = bias[joff + j];
#pragma unroll
      for (int t = 0; t < 16; ++t) {
        float4 a = in[t], wv = wr[t];
        acc += a.x * wv.x + a.y * wv.y + a.z * wv.z + a.w * wv.w;
      }
      int h = j >> 3, d = j & 7;
      vt[((size_t)((b * NH_ + h) * 16 + vbase + d)) * N_ + n] = f2bf(acc);
    }
  } else {
    u16* dst = (part == 0) ? qxb : (part == 2) ? qyb : kbf;
#pragma unroll
    for (int gg = 0; gg < 2; ++gg) {
      int h = (j0 >> 3) + gg;
      union { uint4 u4; u16 s[8]; } pk;
#pragma unroll
      for (int d = 0; d < 8; ++d) {
        int j = h * 8 + d;
        const float4* wr = (const float4*)(wb + (size_t)(joff + j) * C_);
        float acc = bias[joff + j];
#pragma unroll
        for (int t = 0; t < 16; ++t) {
          float4 a = in[t], wv = wr[t];
          acc += a.x * wv.x + a.y * wv.y + a.z * wv.z + a.w * wv.w;
        }
        if (part == 0) acc *= FS_;
        pk.s[d] = f2bf(acc);
      }
      *(uint4*)(dst + ((size_t)(b * NH_ + h) * N_ + n) * 8) = pk.u4;
    }
  }
}

// ---------------- attention v8: MFMA flash, 16-q tile, dual-branch --------
__global__ __launch_bounds__(128, 5) void k_attn8(
    const u16* __restrict__ qx, const u16* __restrict__ qy,
    const u16* __restrict__ kk, const u16* __restrict__ vt,
    float* __restrict__ outx, float* __restrict__ outy) {
  __shared__ float sAcc[2][4][64];
  __shared__ float sL[2][16];
  int qt = blockIdx.x, bh = blockIdx.y;
  int tid = threadIdx.x;
  int lane = tid & 63;
  int wave = tid >> 6;
  int l15 = lane & 15;
  int q0 = qt * 16;

  F8 qxf, qyf;
  size_t qoff = ((size_t)bh * N_ + q0 + l15) * 8;
  qxf.u4 = *(const uint4*)(qx + qoff);
  qyf.u4 = *(const uint4*)(qy + qoff);
  if (lane >= 16) {
    qxf.u4 = make_uint4(0u, 0u, 0u, 0u);
    qyf.u4 = make_uint4(0u, 0u, 0u, 0u);
  }

  int key0 = wave * (N_ / 2);
  const uint4* kp = (const uint4*)(kk + (size_t)bh * N_ * 8) + key0 + l15;
  const uint4* vp = (const uint4*)(vt + ((size_t)bh * 16 + l15) * N_ + key0)
                    + (lane >> 4);
  int addr0 = (((lane >> 4) & 1) * 32 + l15) * 4;
  int addr1 = addr0 + 64;
  int thi = lane >> 5;

  f32x4 acc = {0.f, 0.f, 0.f, 0.f};
  const f32x4 z4 = {0.f, 0.f, 0.f, 0.f};
  float lsum = 0.f;

  F8 ka, kb2, vf;
  ka.u4 = kp[0]; kb2.u4 = kp[16]; vf.u4 = *vp;
  for (int c = 0; c < 36; ++c) {
    F8 kaC = ka, kbC = kb2, vfC = vf;
    kp += 32; vp += 4;
    ka.u4 = kp[0]; kb2.u4 = kp[16]; vf.u4 = *vp;   // prefetch next chunk

    f32x4 s1a = __builtin_amdgcn_mfma_f32_16x16x32_bf16(kaC.s, qxf.s, z4, 0, 0, 0);
    f32x4 s2a = __builtin_amdgcn_mfma_f32_16x16x32_bf16(kaC.s, qyf.s, z4, 0, 0, 0);
    f32x4 s1b = __builtin_amdgcn_mfma_f32_16x16x32_bf16(kbC.s, qxf.s, z4, 0, 0, 0);
    f32x4 s2b = __builtin_amdgcn_mfma_f32_16x16x32_bf16(kbC.s, qyf.s, z4, 0, 0, 0);

    float p00 = exp2f(s1a[0] * s2a[0]), p01 = exp2f(s1a[1] * s2a[1]);
    float p02 = exp2f(s1a[2] * s2a[2]), p03 = exp2f(s1a[3] * s2a[3]);
    float p10 = exp2f(s1b[0] * s2b[0]), p11 = exp2f(s1b[1] * s2b[1]);
    float p12 = exp2f(s1b[2] * s2b[2]), p13 = exp2f(s1b[3] * s2b[3]);
    lsum += ((p00 + p01) + (p02 + p03)) + ((p10 + p11) + (p12 + p13));

    unsigned int pk00, pk10, pk01, pk11;
    asm("v_cvt_pk_bf16_f32 %0, %1, %2" : "=v"(pk00) : "v"(p00), "v"(p01));
    asm("v_cvt_pk_bf16_f32 %0, %1, %2" : "=v"(pk10) : "v"(p02), "v"(p03));
    asm("v_cvt_pk_bf16_f32 %0, %1, %2" : "=v"(pk01) : "v"(p10), "v"(p11));
    asm("v_cvt_pk_bf16_f32 %0, %1, %2" : "=v"(pk11) : "v"(p12), "v"(p13));

    int b00 = __builtin_amdgcn_ds_bpermute(addr0, (int)pk00);
    int b01 = __builtin_amdgcn_ds_bpermute(addr0, (int)pk01);
    int b10 = __builtin_amdgcn_ds_bpermute(addr0, (int)pk10);
    int b11 = __builtin_amdgcn_ds_bpermute(addr0, (int)pk11);
    int c00 = __builtin_amdgcn_ds_bpermute(addr1, (int)pk00);
    int c01 = __builtin_amdgcn_ds_bpermute(addr1, (int)pk01);
    int c10 = __builtin_amdgcn_ds_bpermute(addr1, (int)pk10);
    int c11 = __builtin_amdgcn_ds_bpermute(addr1, (int)pk11);

    F8 pf;
    pf.w[0] = (unsigned int)(thi ? b01 : b00);
    pf.w[1] = (unsigned int)(thi ? b11 : b10);
    pf.w[2] = (unsigned int)(thi ? c01 : c00);
    pf.w[3] = (unsigned int)(thi ? c11 : c10);
    acc = __builtin_amdgcn_mfma_f32_16x16x32_bf16(pf.s, vfC.s, acc, 0, 0, 0);
  }

  lsum += __shfl_xor(lsum, 16, 64);
  lsum += __shfl_xor(lsum, 32, 64);
  if (lane < 16) sL[wave][lane] = lsum;
#pragma unroll
  for (int r = 0; r < 4; ++r) sAcc[wave][r][lane] = acc[r];
  __syncthreads();
  if (wave == 0) {
    float Linv = 1.f / (sL[0][l15] + sL[1][l15]);
    int b = bh >> 3, h = bh & 7;
    int d = l15 & 7;
    float* ob = (l15 < 8) ? outx : outy;
    size_t cbase = (size_t)b * N_ * C_ + (size_t)h * 8 + d;
#pragma unroll
    for (int r = 0; r < 4; ++r) {
      int qrow = 4 * (lane >> 4) + r;
      float li = __shfl(Linv, qrow, 64);
      float a = sAcc[0][r][lane] + sAcc[1][r][lane];
      ob[cbase + (size_t)(q0 + qrow) * C_] = a * li;
    }
  }
}

// -------- proj v3: LDS-transposed att tile, conflict-free reads -----------
__global__ __launch_bounds__(64) void k_proj3(
    const float* __restrict__ attbase,
    const float* __restrict__ x, const float* __restrict__ y,
    const float* bg, const float* bb2, const float* bm, const float* bv,
    const float* __restrict__ pw, const float* __restrict__ pbias,
    float* __restrict__ outbase) {
  __shared__ float attT[64][66];   // attT[c][r] = att[p0+r][c]
  int tid = threadIdx.x;
  int p0 = blockIdx.x * 64;
  int c0 = blockIdx.y * 2;
  int z = blockIdx.z;
  int branch = z >> 1, b = z & 1;
  const float* att = attbase + branch * S_ + (size_t)b * N_ * C_;
  for (int r = 0; r < 64; ++r)
    attT[tid][r] = att[(size_t)(p0 + r) * C_ + tid];
  __syncthreads();
  int p = p0 + tid;
  const float* w0 = pw + (size_t)c0 * C_;
  const float* w1 = w0 + C_;
  float a0 = pbias[c0], a1 = pbias[c0 + 1];
#pragma unroll 8
  for (int c = 0; c < C_; ++c) {
    float av = attT[c][tid];
    a0 += av * w0[c];
    a1 += av * w1[c];
  }
  float s0  = bg[c0] * rsqrtf(bv[c0] + EPS_);
  float sh0 = bb2[c0] - bm[c0] * s0;
  float s1  = bg[c0+1] * rsqrtf(bv[c0+1] + EPS_);
  float sh1 = bb2[c0+1] - bm[c0+1] * s1;
  const float* xin = branch ? y : x;
  float r0 = xin[((size_t)b * C_ + c0) * N_ + p];
  float r1 = xin[((size_t)b * C_ + c0 + 1) * N_ + p];
  size_t o = (size_t)z * CN_ + (size_t)c0 * N_ + p;
  outbase[o]      = a0 + r0 * s0 + sh0;
  outbase[o + N_] = a1 + r1 * s1 + sh1;
}

// ===== conv core v3p (proven best, kept for c2 convs) =====================
template<int CIN, int CIPB>
__device__ __forceinline__ void conv_core3(
    const float* __restrict__ ib, const float* __restrict__ w,
    int c0, int ci0, int p0, int tid, float (*bufs)[CBUF_],
    float4& A0, float4& A1) {
  const float* w0r = w + ((size_t)c0 * CIN + ci0) * 9;
  const float* w1r = w0r + (size_t)CIN * 9;
  int p  = p0 + tid * 4;
  int yy0 = p0 / W_;
  int yy = p / W_, x0 = p - yy * W_;
  int lr = yy - yy0;
  bool okL = x0 > 0, okR = x0 + 4 < W_;

  int rf0 = tid / 12, cf0 = tid - rf0 * 12;
  int gy0 = yy0 - 1 + rf0;
  int rf1 = (64 + tid) / 12, cf1 = (64 + tid) - rf1 * 12;
  int gy1 = yy0 - 1 + rf1;
  bool v0 = (unsigned)gy0 < (unsigned)H_;
  bool v1 = (tid < 32) && ((unsigned)gy1 < (unsigned)H_);
  int o0 = gy0 * W_ + cf0 * 4;
  int o1 = gy1 * W_ + cf1 * 4;
  int lo0 = rf0 * ROWP_ + cf0 * 4;
  int lo1 = rf1 * ROWP_ + cf1 * 4;
  const float4 zz = make_float4(0.f, 0.f, 0.f, 0.f);

  {
    const float* s = ib + (size_t)ci0 * N_;
    float4 ga = v0 ? *(const float4*)(s + o0) : zz;
    *(float4*)(&bufs[0][lo0]) = ga;
    if (tid < 32) {
      float4 gb = v1 ? *(const float4*)(s + o1) : zz;
      *(float4*)(&bufs[0][lo1]) = gb;
    }
  }
  float wc[18];
#pragma unroll
  for (int i = 0; i < 9; ++i) { wc[i] = w0r[i]; wc[9 + i] = w1r[i]; }

#pragma unroll 2
  for (int ci = 0; ci < CIPB; ++ci) {
    float4 ga = zz, gb = zz;
    float wn[18];
    if (ci + 1 < CIPB) {
      const float* s = ib + (size_t)(ci0 + ci + 1) * N_;
      ga = v0 ? *(const float4*)(s + o0) : zz;
      gb = v1 ? *(const float4*)(s + o1) : zz;
      const float* nw0 = w0r + (ci + 1) * 9;
      const float* nw1 = w1r + (ci + 1) * 9;
#pragma unroll
      for (int i = 0; i < 9; ++i) { wn[i] = nw0[i]; wn[9 + i] = nw1[i]; }
    }
    const float* bc = bufs[ci & 1];
#pragma unroll
    for (int ky = 0; ky < 3; ++ky) {
      int base = (lr + ky) * ROWP_ + x0;
      float4 mid = *(const float4*)(bc + base);
      float l = okL ? bc[base - 1] : 0.f;
      float r = okR ? bc[base + 4] : 0.f;
      float u0 = wc[ky*3], u1 = wc[ky*3+1], u2 = wc[ky*3+2];
      float t0 = wc[9+ky*3], t1 = wc[9+ky*3+1], t2 = wc[9+ky*3+2];
      A0.x += l     * u0 + mid.x * u1 + mid.y * u2;
      A0.y += mid.x * u0 + mid.y * u1 + mid.z * u2;
      A0.z += mid.y * u0 + mid.z * u1 + mid.w * u2;
      A0.w += mid.z * u0 + mid.w * u1 + r     * u2;
      A1.x += l     * t0 + mid.x * t1 + mid.y * t2;
      A1.y += mid.x * t0 + mid.y * t1 + mid.z * t2;
      A1.z += mid.y * t0 + mid.z * t1 + mid.w * t2;
      A1.w += mid.z * t0 + mid.w * t1 + r     * t2;
    }
    if (ci + 1 < CIPB) {
      float* d = bufs[(ci + 1) & 1];
      *(float4*)(&d[lo0]) = ga;
      if (tid < 32) *(float4*)(&d[lo1]) = gb;
#pragma unroll
      for (int i = 0; i < 18; ++i) wc[i] = wn[i];
    }
  }
}

// ===== 2-wave conv (CIN=64): waves split cin halves; epilogue split too ===
template<int MODE>
__global__ __launch_bounds__(128) void k_convf(
    const float* __restrict__ inA, const float* __restrict__ inB,
    const float* __restrict__ w, const float* __restrict__ cb,
    const float* g, const float* b2, const float* m, const float* v,
    const float* __restrict__ resid,
    float* __restrict__ oA, float* __restrict__ oB) {
  __shared__ float lds[2 * 2 * CBUF_ + 512];
  int tid = threadIdx.x, wave = tid >> 6, lane = tid & 63;
  int tile = blockIdx.x, c0 = blockIdx.y * 2, img = blockIdx.z;
  const float* ib = (img < 2) ? inA + (size_t)img * CN_
                              : inB + (size_t)(img - 2) * CN_;
  float (*mybufs)[CBUF_] = (float(*)[CBUF_])(lds + wave * 2 * CBUF_);
  float* comb = lds + 4 * CBUF_;
  float4 A0 = make_float4(0.f,0.f,0.f,0.f);
  float4 A1 = make_float4(0.f,0.f,0.f,0.f);
  conv_core3<C_, C_/2>(ib, w, c0, wave * (C_/2), tile * 256, lane, mybufs,
                       A0, A1);
  float* cw = comb + wave * 256 + lane * 4;
  *(float4*)cw = wave ? A0 : A1;
  __syncthreads();
  {
    int c = c0 + wave;
    const float4 other = *(const float4*)(comb + (1 - wave) * 256 + lane * 4);
    float4 a = wave ? other : A0;
    float4 d = wave ? A1 : other;
    int p = tile * 256 + lane * 4;
    float s  = g[c] * rsqrtf(v[c] + EPS_);
    float sh = b2[c] - m[c] * s;
    float bias = cb[c];
    float4 r;
    r.x = fmaxf((a.x + d.x + bias) * s + sh, 0.f);
    r.y = fmaxf((a.y + d.y + bias) * s + sh, 0.f);
    r.z = fmaxf((a.z + d.z + bias) * s + sh, 0.f);
    r.w = fmaxf((a.w + d.w + bias) * s + sh, 0.f);
    size_t off = (size_t)img * CN_ + (size_t)c * N_ + p;
    if (MODE == 0) {
      float* ob = (img < 2) ? oA + off : oB + off - 2 * CN_;
      *(float4*)ob = r;
    } else {
      float4 rr = *(const float4*)(resid + off);
      r.x += rr.x; r.y += rr.y; r.z += rr.z; r.w += rr.w;
      *(float4*)(oA + off) = r;
    }
  }
}

// ------ cat + bn2 -> cat(fp32) and XT1 (bf16 transposed, guarded) ---------
__global__ void k_catbn(const float* __restrict__ o2,
                        const float* __restrict__ g, const float* __restrict__ b2,
                        const float* __restrict__ m, const float* __restrict__ v,
                        float* __restrict__ cat, u16* __restrict__ xt1) {
  int t = blockIdx.x * 256 + threadIdx.x;
  int p4 = t * 4;
  int n  = p4 % N_;
  int c2 = (p4 / N_) % (2 * C_);
  int b  = p4 / (2 * C_ * N_);
  int c  = c2 & 63;
  float4 X = *(const float4*)(o2 + (size_t)b * CN_ + (size_t)c * N_ + n);
  float4 Y = *(const float4*)(o2 + (size_t)(2 + b) * CN_ + (size_t)c * N_ + n);
  float4 val;
  if (c2 < C_) val = make_float4(X.x + Y.x, X.y + Y.y, X.z + Y.z, X.w + Y.w);
  else         val = make_float4(X.x * Y.x, X.y * Y.y, X.z * Y.z, X.w * Y.w);
  size_t co = ((size_t)b * 2 * C_ + c2) * N_ + n;
  *(float4*)(cat + co) = val;
  float s  = g[c2] * rsqrtf(v[c2] + EPS_);
  float sh = b2[c2] - m[c2] * s;
  u16* xb = xt1 + (size_t)b * XTSZ_ + (size_t)(W_ + n) * 128 + c2;
  xb[0]       = f2bf(val.x * s + sh);
  xb[128]     = f2bf(val.y * s + sh);
  xb[256]     = f2bf(val.z * s + sh);
  xb[384]     = f2bf(val.w * s + sh);
}

// ------ zero guard rows of XT1 and XT2 ------------------------------------
__global__ void k_zg(u16* __restrict__ xt1, u16* __restrict__ xt2) {
  int idx = blockIdx.x * 256 + threadIdx.x;   // 24576 u32 total
  if (idx >= 24576) return;
  int r = idx / 3072, o = idx - r * 3072;     // 3072 u32 = W*128 u16
  u16* base = (r & 4) ? xt2 : xt1;
  int b = (r >> 1) & 1, hi = r & 1;
  unsigned int* p = (unsigned int*)(base + (size_t)b * XTSZ_
                                    + (hi ? (size_t)(W_ + N_) * 128 : 0));
  p[o] = 0u;
}

// ------ convert f1w/f2w (OIHW) -> wbf[t][cout][ci] bf16 -------------------
__global__ void k_wcvt(const float* __restrict__ w1,
                       const float* __restrict__ w2,
                       u16* __restrict__ wb1, u16* __restrict__ wb2) {
  int idx = blockIdx.x * 256 + threadIdx.x;   // 2 * 147456
  if (idx >= 2 * 147456) return;
  int layer = idx / 147456, rem = idx - layer * 147456;
  int t = rem / 16384, r2 = rem - t * 16384;
  int co = r2 >> 7, ci = r2 & 127;
  const float* w = layer ? w2 : w1;
  u16* ob = layer ? wb2 : wb1;
  ob[rem] = f2bf(w[(size_t)co * 1152 + ci * 9 + t]);
}

// ===== f-conv as 9 tap-GEMMs on MFMA ======================================
// grid (N_/16, 8, B_), block 64 (1 wave): tile = 16 couts x 16 px.
// XT layout: [b][W guard | N px | W guard][128 ci] bf16.
// wb layout: [t][cout][ci] bf16.
// MODE 0 (f1): epilogue fbn1+relu -> XT2 bf16 transposed.
// MODE 1 (f2): raw fp32 conv out [b][cout][px].
template<int MODE>
__global__ __launch_bounds__(64) void k_fmma(
    const u16* __restrict__ xt, const u16* __restrict__ wb,
    const float* g, const float* b2, const float* m, const float* v,
    u16* __restrict__ xto, float* __restrict__ fo) {
  int l = threadIdx.x;
  int c = l & 15, gg = l >> 4;
  int px0 = blockIdx.x * 16;
  int ct0 = blockIdx.y * 16;
  int b = blockIdx.z;
  int x0 = px0 % W_;                       // 0, 16, or 32
  bool mL = (x0 == 0) && (c == 0);
  bool mR = (x0 == 32) && (c == 15);
  const u16* xb = xt + (size_t)b * XTSZ_ + (size_t)W_ * 128;
  const u16* aw = wb + (size_t)(ct0 + c) * 128 + gg * 8;

  f32x4 acc = {0.f, 0.f, 0.f, 0.f};
#pragma unroll
  for (int cb = 0; cb < 4; ++cb) {
#pragma unroll
    for (int t = 0; t < 9; ++t) {
      const int dx = t % 3 - 1, dy = t / 3 - 1;
      F8 af, bf;
      af.u4 = *(const uint4*)(aw + t * 16384 + cb * 32);
      int px = px0 + c + dx + dy * W_;
      px = max(px, -W_);                   // clamp into guard (no OOB)
      bf.u4 = *(const uint4*)(xb + (ptrdiff_t)px * 128 + cb * 32 + gg * 8);
      bool msk = (dx < 0 && mL) || (dx > 0 && mR);
      if (msk) bf.u4 = make_uint4(0u, 0u, 0u, 0u);
      acc = __builtin_amdgcn_mfma_f32_16x16x32_bf16(af.s, bf.s, acc, 0, 0, 0);
    }
  }
  int px = px0 + c;
  if (MODE == 0) {
    union { ushort4 u; u16 s[4]; } pk;
#pragma unroll
    for (int r = 0; r < 4; ++r) {
      int cout = ct0 + 4 * gg + r;
      float s = g[cout] * rsqrtf(v[cout] + EPS_);
      float sh = b2[cout] - m[cout] * s;
      pk.s[r] = f2bf(fmaxf(acc[r] * s + sh, 0.f));
    }
    *(ushort4*)(xto + (size_t)b * XTSZ_ + (size_t)(W_ + px) * 128
                + ct0 + 4 * gg) = pk.u;
  } else {
#pragma unroll
    for (int r = 0; r < 4; ++r) {
      int cout = ct0 + 4 * gg + r;
      fo[(size_t)b * S_ + (size_t)cout * N_ + px] = acc[r];
    }
  }
}

// -------- final (R9 single-input): fbn2+relu + f3 + cat add ---------------
__global__ __launch_bounds__(64) void k_final3(
    const float* __restrict__ ff, size_t strideF,
    const float* __restrict__ g2, const float* __restrict__ b2,
    const float* __restrict__ m2, const float* __restrict__ v2,
    const float* __restrict__ cat,
    const float* __restrict__ w, const float* __restrict__ fb,
    float* __restrict__ out) {
  __shared__ float fsc[2 * C_], fsh[2 * C_];
  for (int j = threadIdx.x; j < 2 * C_; j += 64) {
    float s = g2[j] * rsqrtf(v2[j] + EPS_);
    fsc[j] = s;
    fsh[j] = b2[j] - m2[j] * s;
  }
  __syncthreads();
  int p = blockIdx.x * 128 + threadIdx.x * 2;
  int c0 = blockIdx.y * 2;
  int b = blockIdx.z;
  const float* fr = ff + (size_t)b * strideF;
  const float* wr0 = w + (size_t)c0 * 2 * C_;
  const float* wr1 = wr0 + 2 * C_;
  float a00 = fb[c0], a01 = a00;
  float a10 = fb[c0 + 1], a11 = a10;
#pragma unroll 4
  for (int j = 0; j < 2 * C_; ++j) {
    float2 fa = *(const float2*)(fr + (size_t)j * N_ + p);
    float s = fsc[j], sh = fsh[j];
    float f0 = fmaxf(fa.x * s + sh, 0.f);
    float f1 = fmaxf(fa.y * s + sh, 0.f);
    float wv0 = wr0[j], wv1 = wr1[j];
    a00 += wv0 * f0; a01 += wv0 * f1;
    a10 += wv1 * f0; a11 += wv1 * f1;
  }
  size_t o = ((size_t)b * 2 * C_ + c0) * N_ + p;
  float2 cv0 = *(const float2*)(cat + o);
  float2 cv1 = *(const float2*)(cat + o + N_);
  *(float2*)(out + o)      = make_float2(a00 + cv0.x, a01 + cv0.y);
  *(float2*)(out + o + N_) = make_float2(a10 + cv1.x, a11 + cv1.y);
}

extern "C" void kernel_launch(void* const* d_in, const int* in_sizes, int n_in,
                              void* d_out, int out_size, void* d_ws, size_t ws_size,
                              hipStream_t stream) {
  const float* x       = (const float*)d_in[0];
  const float* y       = (const float*)d_in[1];
  const float* pconv_w = (const float*)d_in[2];
  const float* pconv_b = (const float*)d_in[3];
  const float* bnd_g = (const float*)d_in[4];
  const float* bnd_b = (const float*)d_in[5];
  const float* bnd_m = (const float*)d_in[6];
  const float* bnd_v = (const float*)d_in[7];
  const float* lnx_g = (const float*)d_in[8];
  const float* lnx_b = (const float*)d_in[9];
  const float* lny_g = (const float*)d_in[10];
  const float* lny_b = (const float*)d_in[11];
  const float* lnz_g = (const float*)d_in[12];
  const float* lnz_b = (const float*)d_in[13];
  const float* k_w   = (const float*)d_in[14];
  const float* k_b   = (const float*)d_in[15];
  const float* qv_w  = (const float*)d_in[16];
  const float* qv_b  = (const float*)d_in[17];
  const float* proj_w = (const float*)d_in[18];
  const float* proj_b = (const float*)d_in[19];
  const float* c2w1  = (const float*)d_in[20];
  const float* c2b1  = (const float*)d_in[21];
  const float* c2bn1_g = (const float*)d_in[22];
  const float* c2bn1_b = (const float*)d_in[23];
  const float* c2bn1_m = (const float*)d_in[24];
  const float* c2bn1_v = (const float*)d_in[25];
  const float* c2w2  = (const float*)d_in[26];
  const float* c2b2  = (const float*)d_in[27];
  const float* c2bn2_g = (const float*)d_in[28];
  const float* c2bn2_b = (const float*)d_in[29];
  const float* c2bn2_m = (const float*)d_in[30];
  const float* c2bn2_v = (const float*)d_in[31];
  const float* bn2_g = (const float*)d_in[32];
  const float* bn2_b = (const float*)d_in[33];
  const float* bn2_m = (const float*)d_in[34];
  const float* bn2_v = (const float*)d_in[35];
  const float* f1w   = (const float*)d_in[36];
  const float* fbn1_g = (const float*)d_in[37];
  const float* fbn1_b = (const float*)d_in[38];
  const float* fbn1_m = (const float*)d_in[39];
  const float* fbn1_v = (const float*)d_in[40];
  const float* f2w   = (const float*)d_in[41];
  const float* fbn2_g = (const float*)d_in[42];
  const float* fbn2_b = (const float*)d_in[43];
  const float* fbn2_m = (const float*)d_in[44];
  const float* fbn2_v = (const float*)d_in[45];
  const float* f3w   = (const float*)d_in[46];
  const float* f3b   = (const float*)d_in[47];

  // Workspace plan:
  //   A: k_pre -> xl(1) yl(2) zl(3)
  //   B: qvk -> qx|qy(4), k(5), VT(6)
  //   C: attn8 -> att_xo(1) att_yo(2)
  //   D: proj3 -> xo4(3,4)
  //   E: convf<0> -> tmp imgs01(0), imgs23(7)
  //   F: convf<1> + resid(3,4) -> o2(1,2)
  //   [k_wcvt -> wbf1|wbf2 at sl7 (free after F)]
  //   G: catbn reads o2(1,2) -> cat(3,4) + XT1 bf16 @ sl5 (spans sl5..6)
  //   [k_zg zero guards of XT1@sl5, XT2@sl0]
  //   H1: k_fmma<0>: XT1 -> XT2 bf16 @ sl0 (spans sl0..1)
  //   H2: k_fmma<1>: XT2 -> f2out fp32 @ sl5 (2 slots, overwrites dead XT1)
  //   I: final3 reads f2out(sl5) + cat(3,4) -> out
  float* ws = (float*)d_ws;
  float* sl0 = ws + 0 * S_;
  float* sl1 = ws + 1 * S_;
  float* sl2 = ws + 2 * S_;
  float* sl3 = ws + 3 * S_;
  float* sl4 = ws + 4 * S_;
  float* sl5 = ws + 5 * S_;
  float* sl7 = ws + 7 * S_;
  u16* xt1  = (u16*)sl5;
  u16* xt2  = (u16*)sl0;
  u16* wbf1 = (u16*)sl7;
  u16* wbf2 = wbf1 + 9 * 16384;
  float* f2o = sl5;

  // A. fused pconv + bn + ln
  k_pre<<<B_ * N_ / 16, 1024, 0, stream>>>(x, y, pconv_w, pconv_b,
                                    bnd_g, bnd_b, bnd_m, bnd_v,
                                    lnx_g, lnx_b, lny_g, lny_b, lnz_g, lnz_b,
                                    sl1, sl2, sl3);
  // B. qv/k projection
  u16* qxb = (u16*)(ws + 4 * S_);
  u16* qyb = qxb + (size_t)B_ * NH_ * N_ * 8;
  u16* kbf = (u16*)sl5;
  u16* vtb = (u16*)(ws + 6 * S_);
  {
    dim3 g(B_ * N_ / 64, 20);
    k_qvk<<<g, 64, 0, stream>>>(sl1, sl2, sl3, qv_w, qv_b, k_w, k_b,
                                qxb, qyb, kbf, vtb);
  }
  // C. attention v8 (MFMA)
  {
    dim3 g(N_ / 16, B_ * NH_);
    k_attn8<<<g, 128, 0, stream>>>(qxb, qyb, kbf, vtb, sl1, sl2);
  }
  // D. proj v3 -> xo4(3,4)
  {
    dim3 g(36, C_ / 2, 2 * B_);
    k_proj3<<<g, 64, 0, stream>>>(sl1, x, y, bnd_g, bnd_b, bnd_m, bnd_v,
                                  proj_w, proj_b, sl3);
  }
  // E. conv1 (2-wave fused) -> tmp(0 / 7)
  {
    dim3 g(9, C_ / 2, 4);
    k_convf<0><<<g, 128, 0, stream>>>(sl3, sl3 + 2 * CN_, c2w1, c2b1,
        c2bn1_g, c2bn1_b, c2bn1_m, c2bn1_v, sl3, sl0, sl7);
  }
  // F. conv2 (2-wave fused + resid) -> o2(1,2)
  {
    dim3 g(9, C_ / 2, 4);
    k_convf<1><<<g, 128, 0, stream>>>(sl0, sl7, c2w2, c2b2,
        c2bn2_g, c2bn2_b, c2bn2_m, c2bn2_v, sl3, sl1, sl1);
  }
  // Weights -> bf16 tap-major (sl7 free after F)
  k_wcvt<<<1152, 256, 0, stream>>>(f1w, f2w, wbf1, wbf2);
  // G. cat + bn2 -> cat(3,4) + XT1 bf16 (sl5..)
  k_catbn<<<576, 256, 0, stream>>>(sl1, bn2_g, bn2_b, bn2_m, bn2_v,
                                   sl3, xt1);
  // zero guard rows of XT1, XT2
  k_zg<<<96, 256, 0, stream>>>(xt1, xt2);
  // H. f-branch via MFMA tap-GEMMs
  {
    dim3 g(N_ / 16, 8, B_);
    k_fmma<0><<<g, 64, 0, stream>>>(xt1, wbf1,
        fbn1_g, fbn1_b, fbn1_m, fbn1_v, xt2, nullptr);
    k_fmma<1><<<g, 64, 0, stream>>>(xt2, wbf2,
        nullptr, nullptr, nullptr, nullptr, nullptr, f2o);
  }
  // I. final (single-input) -> fp32 out
  {
    dim3 g(18, C_, B_);
    k_final3<<<g, 64, 0, stream>>>(f2o, S_,
                                   fbn2_g, fbn2_b, fbn2_m, fbn2_v,
                                   sl3, f3w, f3b, (float*)d_out);
  }
}

// Round 14
// 321.761 us; speedup vs baseline: 1.7565x; 1.1097x over previous
//
#include <hip/hip_runtime.h>
#include <hip/hip_bf16.h>

#define B_   2
#define C_   64
#define H_   48
#define W_   48
#define N_   (H_*W_)     // 2304
#define NH_  8
#define HD_  8
#define EPS_ 1e-5f
#define S2_  0.125f      // scale^2 = 1/hd
#define LOG2E_ 1.44269504f
#define FS_  (S2_ * LOG2E_)
#define S_   ((size_t)B_ * C_ * N_)   // 294912 floats per workspace slot
#define CN_  ((size_t)C_ * N_)        // 147456 floats per image
#define XTSZ_ ((size_t)(N_ + 2 * W_) * 128)  // bf16 elems per 128-ch image
#define XTSC_ ((size_t)(N_ + 2 * W_) * 64)   // bf16 elems per 64-ch image

typedef unsigned short u16;
typedef __attribute__((ext_vector_type(8))) short short8v;
typedef __attribute__((ext_vector_type(4))) float f32x4;
union F8 { uint4 u4; short8v s; unsigned int w[4]; };

__device__ __forceinline__ float wsum64(float v) {
#pragma unroll
  for (int o = 32; o > 0; o >>= 1) v += __shfl_xor(v, o, 64);
  return v;
}

__device__ __forceinline__ float ln_val(float t, float g, float b) {
  float mu  = wsum64(t) * (1.0f / 64.0f);
  float d   = t - mu;
  float var = wsum64(d * d) * (1.0f / 64.0f);
  return d * rsqrtf(var + EPS_) * g + b;
}

// round-to-nearest-even f32 -> bf16 (finite inputs only)
__device__ __forceinline__ u16 f2bf(float x) {
  union { float f; unsigned int u; } a; a.f = x;
  unsigned int r = a.u + 0x7fffu + ((a.u >> 16) & 1u);
  return (u16)(r >> 16);
}

// ---- fused 1x1 pconv + BN + 3x LayerNorm; v2: 16 rows/block, LDS pw^T ----
__global__ __launch_bounds__(1024) void k_pre(
    const float* __restrict__ x, const float* __restrict__ y,
    const float* __restrict__ pw, const float* __restrict__ pb,
    const float* g, const float* bb, const float* m, const float* v,
    const float* lnxg, const float* lnxb,
    const float* lnyg, const float* lnyb,
    const float* lnzg, const float* lnzb,
    float* __restrict__ xl, float* __restrict__ yl, float* __restrict__ zl) {
  __shared__ float4 pwT[32][64];           // pwT[i4][c] = pw[c][4*i4..+3]
  __shared__ float xs[16][64], ys[16][64];
  int w = threadIdx.x >> 6, c = threadIdx.x & 63;
  for (int idx = threadIdx.x; idx < 2048; idx += 1024) {
    int cc = idx & 63, i4 = idx >> 6;
    pwT[i4][cc] = *(const float4*)(pw + (size_t)cc * 2 * C_ + i4 * 4);
  }
  int row = blockIdx.x * 16 + w;           // b*N + n
  int b = row / N_, n = row % N_;
  float xv = x[(size_t)(b * C_ + c) * N_ + n];
  float yv = y[(size_t)(b * C_ + c) * N_ + n];
  xs[w][c] = xv; ys[w][c] = yv;
  __syncthreads();
  const float4* xw = (const float4*)xs[w];
  const float4* yw = (const float4*)ys[w];
  float acc = pb[c];
#pragma unroll
  for (int t = 0; t < 16; ++t) {
    float4 a = xw[t], wv = pwT[t][c];
    acc += a.x * wv.x + a.y * wv.y + a.z * wv.z + a.w * wv.w;
  }
#pragma unroll
  for (int t = 0; t < 16; ++t) {
    float4 a = yw[t], wv = pwT[16 + t][c];
    acc += a.x * wv.x + a.y * wv.y + a.z * wv.z + a.w * wv.w;
  }
  float s  = g[c] * rsqrtf(v[c] + EPS_);
  float sh = bb[c] - m[c] * s;
  float tx = xv * s + sh;
  xl[(size_t)row * C_ + c] = ln_val(tx, lnxg[c], lnxb[c]);
  float ty = yv * s + sh;
  yl[(size_t)row * C_ + c] = ln_val(ty, lnyg[c], lnyb[c]);
  float tz = acc * s + sh;
  zl[(size_t)row * C_ + c] = ln_val(tz, lnzg[c], lnzb[c]);
}

// ------------- qv/k projection v2: lane = row, uniform weights ------------
__global__ __launch_bounds__(64) void k_qvk(
    const float* __restrict__ xl, const float* __restrict__ yl,
    const float* __restrict__ zl,
    const float* __restrict__ qvw, const float* __restrict__ qvb,
    const float* __restrict__ kw, const float* __restrict__ kb,
    u16* __restrict__ qxb, u16* __restrict__ qyb,
    u16* __restrict__ kbf, u16* __restrict__ vt) {
  int l = threadIdx.x;
  int part = blockIdx.y >> 2;
  int j0 = (blockIdx.y & 3) * 16;
  int row = blockIdx.x * 64 + l;
  int b = row / N_, n = row % N_;
  const float* inp = (part < 2) ? xl : (part < 4) ? yl : zl;
  float4 in[16];
  const float4* ir = (const float4*)(inp + (size_t)row * C_);
#pragma unroll
  for (int t = 0; t < 16; ++t) in[t] = ir[t];

  const float* wb   = (part == 4) ? kw : qvw;
  const float* bias = (part == 4) ? kb : qvb;
  int joff = (part == 1 || part == 3) ? 64 : 0;

  if (part == 1 || part == 3) {
    int vbase = (part == 1) ? 0 : 8;
#pragma unroll
    for (int jj = 0; jj < 16; ++jj) {
      int j = j0 + jj;
      const float4* wr = (const float4*)(wb + (size_t)(joff + j) * C_);
      float acc = bias[joff + j];
#pragma unroll
      for (int t = 0; t < 16; ++t) {
        float4 a = in[t], wv = wr[t];
        acc += a.x * wv.x + a.y * wv.y + a.z * wv.z + a.w * wv.w;
      }
      int h = j >> 3, d = j & 7;
      vt[((size_t)((b * NH_ + h) * 16 + vbase + d)) * N_ + n] = f2bf(acc);
    }
  } else {
    u16* dst = (part == 0) ? qxb : (part == 2) ? qyb : kbf;
#pragma unroll
    for (int gg = 0; gg < 2; ++gg) {
      int h = (j0 >> 3) + gg;
      union { uint4 u4; u16 s[8]; } pk;
#pragma unroll
      for (int d = 0; d < 8; ++d) {
        int j = h * 8 + d;
        const float4* wr = (const float4*)(wb + (size_t)(joff + j) * C_);
        float acc = bias[joff + j];
#pragma unroll
        for (int t = 0; t < 16; ++t) {
          float4 a = in[t], wv = wr[t];
          acc += a.x * wv.x + a.y * wv.y + a.z * wv.z + a.w * wv.w;
        }
        if (part == 0) acc *= FS_;
        pk.s[d] = f2bf(acc);
      }
      *(uint4*)(dst + ((size_t)(b * NH_ + h) * N_ + n) * 8) = pk.u4;
    }
  }
}

// ---------------- attention v8: MFMA flash, 16-q tile, dual-branch --------
__global__ __launch_bounds__(128, 5) void k_attn8(
    const u16* __restrict__ qx, const u16* __restrict__ qy,
    const u16* __restrict__ kk, const u16* __restrict__ vt,
    float* __restrict__ outx, float* __restrict__ outy) {
  __shared__ float sAcc[2][4][64];
  __shared__ float sL[2][16];
  int qt = blockIdx.x, bh = blockIdx.y;
  int tid = threadIdx.x;
  int lane = tid & 63;
  int wave = tid >> 6;
  int l15 = lane & 15;
  int q0 = qt * 16;

  F8 qxf, qyf;
  size_t qoff = ((size_t)bh * N_ + q0 + l15) * 8;
  qxf.u4 = *(const uint4*)(qx + qoff);
  qyf.u4 = *(const uint4*)(qy + qoff);
  if (lane >= 16) {
    qxf.u4 = make_uint4(0u, 0u, 0u, 0u);
    qyf.u4 = make_uint4(0u, 0u, 0u, 0u);
  }

  int key0 = wave * (N_ / 2);
  const uint4* kp = (const uint4*)(kk + (size_t)bh * N_ * 8) + key0 + l15;
  const uint4* vp = (const uint4*)(vt + ((size_t)bh * 16 + l15) * N_ + key0)
                    + (lane >> 4);
  int addr0 = (((lane >> 4) & 1) * 32 + l15) * 4;
  int addr1 = addr0 + 64;
  int thi = lane >> 5;

  f32x4 acc = {0.f, 0.f, 0.f, 0.f};
  const f32x4 z4 = {0.f, 0.f, 0.f, 0.f};
  float lsum = 0.f;

  F8 ka, kb2, vf;
  ka.u4 = kp[0]; kb2.u4 = kp[16]; vf.u4 = *vp;
  for (int c = 0; c < 36; ++c) {
    F8 kaC = ka, kbC = kb2, vfC = vf;
    kp += 32; vp += 4;
    ka.u4 = kp[0]; kb2.u4 = kp[16]; vf.u4 = *vp;   // prefetch next chunk

    f32x4 s1a = __builtin_amdgcn_mfma_f32_16x16x32_bf16(kaC.s, qxf.s, z4, 0, 0, 0);
    f32x4 s2a = __builtin_amdgcn_mfma_f32_16x16x32_bf16(kaC.s, qyf.s, z4, 0, 0, 0);
    f32x4 s1b = __builtin_amdgcn_mfma_f32_16x16x32_bf16(kbC.s, qxf.s, z4, 0, 0, 0);
    f32x4 s2b = __builtin_amdgcn_mfma_f32_16x16x32_bf16(kbC.s, qyf.s, z4, 0, 0, 0);

    float p00 = exp2f(s1a[0] * s2a[0]), p01 = exp2f(s1a[1] * s2a[1]);
    float p02 = exp2f(s1a[2] * s2a[2]), p03 = exp2f(s1a[3] * s2a[3]);
    float p10 = exp2f(s1b[0] * s2b[0]), p11 = exp2f(s1b[1] * s2b[1]);
    float p12 = exp2f(s1b[2] * s2b[2]), p13 = exp2f(s1b[3] * s2b[3]);
    lsum += ((p00 + p01) + (p02 + p03)) + ((p10 + p11) + (p12 + p13));

    unsigned int pk00, pk10, pk01, pk11;
    asm("v_cvt_pk_bf16_f32 %0, %1, %2" : "=v"(pk00) : "v"(p00), "v"(p01));
    asm("v_cvt_pk_bf16_f32 %0, %1, %2" : "=v"(pk10) : "v"(p02), "v"(p03));
    asm("v_cvt_pk_bf16_f32 %0, %1, %2" : "=v"(pk01) : "v"(p10), "v"(p11));
    asm("v_cvt_pk_bf16_f32 %0, %1, %2" : "=v"(pk11) : "v"(p12), "v"(p13));

    int b00 = __builtin_amdgcn_ds_bpermute(addr0, (int)pk00);
    int b01 = __builtin_amdgcn_ds_bpermute(addr0, (int)pk01);
    int b10 = __builtin_amdgcn_ds_bpermute(addr0, (int)pk10);
    int b11 = __builtin_amdgcn_ds_bpermute(addr0, (int)pk11);
    int c00 = __builtin_amdgcn_ds_bpermute(addr1, (int)pk00);
    int c01 = __builtin_amdgcn_ds_bpermute(addr1, (int)pk01);
    int c10 = __builtin_amdgcn_ds_bpermute(addr1, (int)pk10);
    int c11 = __builtin_amdgcn_ds_bpermute(addr1, (int)pk11);

    F8 pf;
    pf.w[0] = (unsigned int)(thi ? b01 : b00);
    pf.w[1] = (unsigned int)(thi ? b11 : b10);
    pf.w[2] = (unsigned int)(thi ? c01 : c00);
    pf.w[3] = (unsigned int)(thi ? c11 : c10);
    acc = __builtin_amdgcn_mfma_f32_16x16x32_bf16(pf.s, vfC.s, acc, 0, 0, 0);
  }

  lsum += __shfl_xor(lsum, 16, 64);
  lsum += __shfl_xor(lsum, 32, 64);
  if (lane < 16) sL[wave][lane] = lsum;
#pragma unroll
  for (int r = 0; r < 4; ++r) sAcc[wave][r][lane] = acc[r];
  __syncthreads();
  if (wave == 0) {
    float Linv = 1.f / (sL[0][l15] + sL[1][l15]);
    int b = bh >> 3, h = bh & 7;
    int d = l15 & 7;
    float* ob = (l15 < 8) ? outx : outy;
    size_t cbase = (size_t)b * N_ * C_ + (size_t)h * 8 + d;
#pragma unroll
    for (int r = 0; r < 4; ++r) {
      int qrow = 4 * (lane >> 4) + r;
      float li = __shfl(Linv, qrow, 64);
      float a = sAcc[0][r][lane] + sAcc[1][r][lane];
      ob[cbase + (size_t)(q0 + qrow) * C_] = a * li;
    }
  }
}

// -------- proj v4: LDS-transposed att tile + emits conv1 XT bf16 ----------
// grid (36, C_/2, 2*B_), block 64.
__global__ __launch_bounds__(64) void k_proj4(
    const float* __restrict__ attbase,
    const float* __restrict__ x, const float* __restrict__ y,
    const float* bg, const float* bb2, const float* bm, const float* bv,
    const float* __restrict__ pw, const float* __restrict__ pbias,
    float* __restrict__ outbase, u16* __restrict__ xt0) {
  __shared__ float attT[64][66];   // attT[c][r] = att[p0+r][c]
  int tid = threadIdx.x;
  int p0 = blockIdx.x * 64;
  int c0 = blockIdx.y * 2;
  int z = blockIdx.z;
  int branch = z >> 1, b = z & 1;
  const float* att = attbase + branch * S_ + (size_t)b * N_ * C_;
  for (int r = 0; r < 64; ++r)
    attT[tid][r] = att[(size_t)(p0 + r) * C_ + tid];
  __syncthreads();
  int p = p0 + tid;
  const float* w0 = pw + (size_t)c0 * C_;
  const float* w1 = w0 + C_;
  float a0 = pbias[c0], a1 = pbias[c0 + 1];
#pragma unroll 8
  for (int c = 0; c < C_; ++c) {
    float av = attT[c][tid];
    a0 += av * w0[c];
    a1 += av * w1[c];
  }
  float s0  = bg[c0] * rsqrtf(bv[c0] + EPS_);
  float sh0 = bb2[c0] - bm[c0] * s0;
  float s1  = bg[c0+1] * rsqrtf(bv[c0+1] + EPS_);
  float sh1 = bb2[c0+1] - bm[c0+1] * s1;
  const float* xin = branch ? y : x;
  float r0 = xin[((size_t)b * C_ + c0) * N_ + p];
  float r1 = xin[((size_t)b * C_ + c0 + 1) * N_ + p];
  float v0 = a0 + r0 * s0 + sh0;
  float v1 = a1 + r1 * s1 + sh1;
  size_t o = (size_t)z * CN_ + (size_t)c0 * N_ + p;
  outbase[o]      = v0;
  outbase[o + N_] = v1;
  unsigned int pv = ((unsigned int)f2bf(v1) << 16) | (unsigned int)f2bf(v0);
  *(unsigned int*)(xt0 + (size_t)z * XTSC_ + (size_t)(W_ + p) * 64 + c0) = pv;
}

// ------ cat + bn2 -> cat(fp32) and XTf1 (bf16 transposed, guarded) --------
__global__ void k_catbn(const float* __restrict__ o2,
                        const float* __restrict__ g, const float* __restrict__ b2,
                        const float* __restrict__ m, const float* __restrict__ v,
                        float* __restrict__ cat, u16* __restrict__ xt1) {
  int t = blockIdx.x * 256 + threadIdx.x;
  int p4 = t * 4;
  int n  = p4 % N_;
  int c2 = (p4 / N_) % (2 * C_);
  int b  = p4 / (2 * C_ * N_);
  int c  = c2 & 63;
  float4 X = *(const float4*)(o2 + (size_t)b * CN_ + (size_t)c * N_ + n);
  float4 Y = *(const float4*)(o2 + (size_t)(2 + b) * CN_ + (size_t)c * N_ + n);
  float4 val;
  if (c2 < C_) val = make_float4(X.x + Y.x, X.y + Y.y, X.z + Y.z, X.w + Y.w);
  else         val = make_float4(X.x * Y.x, X.y * Y.y, X.z * Y.z, X.w * Y.w);
  size_t co = ((size_t)b * 2 * C_ + c2) * N_ + n;
  *(float4*)(cat + co) = val;
  float s  = g[c2] * rsqrtf(v[c2] + EPS_);
  float sh = b2[c2] - m[c2] * s;
  u16* xb = xt1 + (size_t)b * XTSZ_ + (size_t)(W_ + n) * 128 + c2;
  xb[0]   = f2bf(val.x * s + sh);
  xb[128] = f2bf(val.y * s + sh);
  xb[256] = f2bf(val.z * s + sh);
  xb[384] = f2bf(val.w * s + sh);
}

// ------ zero guard rows of two XT buffers (generic) -----------------------
__global__ void k_zg(u16* __restrict__ b0, u16* __restrict__ b1,
                     int nimg, int cinc) {
  int gsz = W_ * cinc / 2;                 // u32 per guard
  int pbt = nimg * 2 * gsz;
  int idx = blockIdx.x * 256 + threadIdx.x;
  if (idx >= 2 * pbt) return;
  u16* base = (idx < pbt) ? b0 : b1;
  int r = idx % pbt;
  int img = r / (2 * gsz);
  int r2 = r % (2 * gsz);
  int hi = r2 / gsz, o = r2 % gsz;
  size_t xts = (size_t)(N_ + 2 * W_) * cinc;
  ((unsigned int*)(base + (size_t)img * xts
                   + (hi ? (size_t)(W_ + N_) * cinc : 0)))[o] = 0u;
}

// ------ convert all conv weights -> bf16 tap-major ------------------------
// wb layout: [0,147456) f1w; [147456,294912) f2w; [294912,331776) c2w1;
//            [331776,368640) c2w2.  Each: [tap][cout][ci].
__global__ void k_wcvt(const float* __restrict__ w1,
                       const float* __restrict__ w2,
                       const float* __restrict__ cw1,
                       const float* __restrict__ cw2,
                       u16* __restrict__ wb) {
  int idx = blockIdx.x * 256 + threadIdx.x;
  if (idx >= 368640) return;
  if (idx < 294912) {
    int layer = idx / 147456, rem = idx - layer * 147456;
    int t = rem / 16384, r2 = rem - t * 16384;
    int co = r2 >> 7, ci = r2 & 127;
    wb[idx] = f2bf((layer ? w2 : w1)[(size_t)co * 1152 + ci * 9 + t]);
  } else {
    int k = idx - 294912;
    int layer = k / 36864, rem = k - layer * 36864;
    int t = rem / 4096, r2 = rem - t * 4096;
    int co = r2 >> 6, ci = r2 & 63;
    wb[idx] = f2bf((layer ? cw2 : cw1)[(size_t)co * 576 + ci * 9 + t]);
  }
}

// ===== conv as 9 tap-GEMMs on MFMA (f-branch and c2-branch) ===============
// grid (N_/16, COUT/16, nimg), block 64: tile = 16 couts x 16 px.
// MODE 0: f1  (128ci, bn+relu -> bf16 XT out 128ch)
// MODE 1: f2  (128ci, raw fp32 out [b][cout][px], stride S_)
// MODE 2: c2 conv1 (64ci, +bias, bn, relu -> bf16 XT out 64ch)
// MODE 3: c2 conv2 (64ci, +bias, bn, relu, +resid -> fp32 [img][cout][px])
template<int MODE>
__global__ __launch_bounds__(64) void k_fmma(
    const u16* __restrict__ xt, const u16* __restrict__ wb,
    const float* __restrict__ cbias,
    const float* g, const float* b2, const float* m, const float* v,
    const float* __restrict__ resid,
    u16* __restrict__ xto, float* __restrict__ fo) {
  constexpr int CIN  = (MODE >= 2) ? 64 : 128;
  constexpr int NCB  = CIN / 32;
  constexpr int COUT = (MODE >= 2) ? 64 : 128;
  constexpr int TS   = CIN * COUT;
  constexpr size_t XTS = (size_t)(N_ + 2 * W_) * CIN;
  constexpr size_t XTSO = (size_t)(N_ + 2 * W_) * COUT;
  int l = threadIdx.x;
  int c = l & 15, gg = l >> 4;
  int px0 = blockIdx.x * 16;
  int ct0 = blockIdx.y * 16;
  int b = blockIdx.z;
  int x0 = px0 % W_;                       // 0, 16, or 32
  bool mL = (x0 == 0) && (c == 0);
  bool mR = (x0 == 32) && (c == 15);
  const u16* xb = xt + (size_t)b * XTS + (size_t)W_ * CIN;
  const u16* aw = wb + (size_t)(ct0 + c) * CIN + gg * 8;

  f32x4 acc = {0.f, 0.f, 0.f, 0.f};
#pragma unroll
  for (int cb = 0; cb < NCB; ++cb) {
#pragma unroll
    for (int t = 0; t < 9; ++t) {
      const int dx = t % 3 - 1, dy = t / 3 - 1;
      F8 af, bf;
      af.u4 = *(const uint4*)(aw + t * TS + cb * 32);
      int px = px0 + c + dx + dy * W_;
      px = max(px, -W_);                   // clamp into guard (no OOB)
      bf.u4 = *(const uint4*)(xb + (ptrdiff_t)px * CIN + cb * 32 + gg * 8);
      bool msk = (dx < 0 && mL) || (dx > 0 && mR);
      if (msk) bf.u4 = make_uint4(0u, 0u, 0u, 0u);
      acc = __builtin_amdgcn_mfma_f32_16x16x32_bf16(af.s, bf.s, acc, 0, 0, 0);
    }
  }
  int px = px0 + c;
  if (MODE == 0 || MODE == 2) {
    union { ushort4 u; u16 s[4]; } pk;
#pragma unroll
    for (int r = 0; r < 4; ++r) {
      int cout = ct0 + 4 * gg + r;
      float a = acc[r] + (MODE == 2 ? cbias[cout] : 0.f);
      float s = g[cout] * rsqrtf(v[cout] + EPS_);
      float sh = b2[cout] - m[cout] * s;
      pk.s[r] = f2bf(fmaxf(a * s + sh, 0.f));
    }
    *(ushort4*)(xto + (size_t)b * XTSO + (size_t)(W_ + px) * COUT
                + ct0 + 4 * gg) = pk.u;
  } else if (MODE == 1) {
#pragma unroll
    for (int r = 0; r < 4; ++r) {
      int cout = ct0 + 4 * gg + r;
      fo[(size_t)b * S_ + (size_t)cout * N_ + px] = acc[r];
    }
  } else {  // MODE 3
#pragma unroll
    for (int r = 0; r < 4; ++r) {
      int cout = ct0 + 4 * gg + r;
      float a = acc[r] + cbias[cout];
      float s = g[cout] * rsqrtf(v[cout] + EPS_);
      float sh = b2[cout] - m[cout] * s;
      size_t off = (size_t)b * CN_ + (size_t)cout * N_ + px;
      fo[off] = fmaxf(a * s + sh, 0.f) + resid[off];
    }
  }
}

// -------- final (single-input): fbn2+relu + f3 + cat add ------------------
__global__ __launch_bounds__(64) void k_final3(
    const float* __restrict__ ff, size_t strideF,
    const float* __restrict__ g2, const float* __restrict__ b2,
    const float* __restrict__ m2, const float* __restrict__ v2,
    const float* __restrict__ cat,
    const float* __restrict__ w, const float* __restrict__ fb,
    float* __restrict__ out) {
  __shared__ float fsc[2 * C_], fsh[2 * C_];
  for (int j = threadIdx.x; j < 2 * C_; j += 64) {
    float s = g2[j] * rsqrtf(v2[j] + EPS_);
    fsc[j] = s;
    fsh[j] = b2[j] - m2[j] * s;
  }
  __syncthreads();
  int p = blockIdx.x * 128 + threadIdx.x * 2;
  int c0 = blockIdx.y * 2;
  int b = blockIdx.z;
  const float* fr = ff + (size_t)b * strideF;
  const float* wr0 = w + (size_t)c0 * 2 * C_;
  const float* wr1 = wr0 + 2 * C_;
  float a00 = fb[c0], a01 = a00;
  float a10 = fb[c0 + 1], a11 = a10;
#pragma unroll 4
  for (int j = 0; j < 2 * C_; ++j) {
    float2 fa = *(const float2*)(fr + (size_t)j * N_ + p);
    float s = fsc[j], sh = fsh[j];
    float f0 = fmaxf(fa.x * s + sh, 0.f);
    float f1 = fmaxf(fa.y * s + sh, 0.f);
    float wv0 = wr0[j], wv1 = wr1[j];
    a00 += wv0 * f0; a01 += wv0 * f1;
    a10 += wv1 * f0; a11 += wv1 * f1;
  }
  size_t o = ((size_t)b * 2 * C_ + c0) * N_ + p;
  float2 cv0 = *(const float2*)(cat + o);
  float2 cv1 = *(const float2*)(cat + o + N_);
  *(float2*)(out + o)      = make_float2(a00 + cv0.x, a01 + cv0.y);
  *(float2*)(out + o + N_) = make_float2(a10 + cv1.x, a11 + cv1.y);
}

extern "C" void kernel_launch(void* const* d_in, const int* in_sizes, int n_in,
                              void* d_out, int out_size, void* d_ws, size_t ws_size,
                              hipStream_t stream) {
  const float* x       = (const float*)d_in[0];
  const float* y       = (const float*)d_in[1];
  const float* pconv_w = (const float*)d_in[2];
  const float* pconv_b = (const float*)d_in[3];
  const float* bnd_g = (const float*)d_in[4];
  const float* bnd_b = (const float*)d_in[5];
  const float* bnd_m = (const float*)d_in[6];
  const float* bnd_v = (const float*)d_in[7];
  const float* lnx_g = (const float*)d_in[8];
  const float* lnx_b = (const float*)d_in[9];
  const float* lny_g = (const float*)d_in[10];
  const float* lny_b = (const float*)d_in[11];
  const float* lnz_g = (const float*)d_in[12];
  const float* lnz_b = (const float*)d_in[13];
  const float* k_w   = (const float*)d_in[14];
  const float* k_b   = (const float*)d_in[15];
  const float* qv_w  = (const float*)d_in[16];
  const float* qv_b  = (const float*)d_in[17];
  const float* proj_w = (const float*)d_in[18];
  const float* proj_b = (const float*)d_in[19];
  const float* c2w1  = (const float*)d_in[20];
  const float* c2b1  = (const float*)d_in[21];
  const float* c2bn1_g = (const float*)d_in[22];
  const float* c2bn1_b = (const float*)d_in[23];
  const float* c2bn1_m = (const float*)d_in[24];
  const float* c2bn1_v = (const float*)d_in[25];
  const float* c2w2  = (const float*)d_in[26];
  const float* c2b2  = (const float*)d_in[27];
  const float* c2bn2_g = (const float*)d_in[28];
  const float* c2bn2_b = (const float*)d_in[29];
  const float* c2bn2_m = (const float*)d_in[30];
  const float* c2bn2_v = (const float*)d_in[31];
  const float* bn2_g = (const float*)d_in[32];
  const float* bn2_b = (const float*)d_in[33];
  const float* bn2_m = (const float*)d_in[34];
  const float* bn2_v = (const float*)d_in[35];
  const float* f1w   = (const float*)d_in[36];
  const float* fbn1_g = (const float*)d_in[37];
  const float* fbn1_b = (const float*)d_in[38];
  const float* fbn1_m = (const float*)d_in[39];
  const float* fbn1_v = (const float*)d_in[40];
  const float* f2w   = (const float*)d_in[41];
  const float* fbn2_g = (const float*)d_in[42];
  const float* fbn2_b = (const float*)d_in[43];
  const float* fbn2_m = (const float*)d_in[44];
  const float* fbn2_v = (const float*)d_in[45];
  const float* f3w   = (const float*)d_in[46];
  const float* f3b   = (const float*)d_in[47];

  // Workspace plan (float offsets, slot = S_):
  //   A: k_pre -> xl(1) yl(2) zl(3)
  //   B: qvk -> qx|qy(4), kbf(5), vt(6)
  //   C: attn8 -> att_xo(1) att_yo(2)
  //   D: proj4 -> xo4 fp32 (3,4) + XTC0 bf16 @5 (spans into 6)
  //   [wcvt -> wb @7; zgA: XTC0@5, XTC1@0 guards]
  //   E: fmma<2> conv1: XTC0 -> XTC1 bf16 @0 (spans into 1)
  //   F: fmma<3> conv2: XTC1 + resid(3,4) -> o2 fp32 @5,6
  //   [zgB: XTF1@1.5S, XTF2@0 guards]
  //   G: catbn: o2 -> cat(3,4) + XTF1 bf16 @1.5S
  //   H1: fmma<0> f1: XTF1 -> XTF2 bf16 @0
  //   H2: fmma<1> f2: XTF2 -> f2o fp32 @5,6
  //   I: final3: f2o + cat -> out
  float* ws = (float*)d_ws;
  float* sl1 = ws + 1 * S_;
  float* sl2 = ws + 2 * S_;
  float* sl3 = ws + 3 * S_;
  float* sl5 = ws + 5 * S_;
  u16* xtC0 = (u16*)sl5;
  u16* xtC1 = (u16*)ws;
  u16* xtF1 = (u16*)(ws + 3 * S_ / 2);
  u16* xtF2 = (u16*)ws;
  float* xo4 = sl3;
  float* o2  = sl5;
  float* f2o = sl5;
  u16* wb   = (u16*)(ws + 7 * S_);
  u16* wbf1 = wb;
  u16* wbf2 = wb + 147456;
  u16* wbc1 = wb + 294912;
  u16* wbc2 = wb + 331776;

  // A. fused pconv + bn + ln
  k_pre<<<B_ * N_ / 16, 1024, 0, stream>>>(x, y, pconv_w, pconv_b,
                                    bnd_g, bnd_b, bnd_m, bnd_v,
                                    lnx_g, lnx_b, lny_g, lny_b, lnz_g, lnz_b,
                                    sl1, sl2, sl3);
  // weights -> bf16 tap-major (independent)
  k_wcvt<<<1440, 256, 0, stream>>>(f1w, f2w, c2w1, c2w2, wb);
  // B. qv/k projection
  u16* qxb = (u16*)(ws + 4 * S_);
  u16* qyb = qxb + (size_t)B_ * NH_ * N_ * 8;
  u16* kbf = (u16*)sl5;
  u16* vtb = (u16*)(ws + 6 * S_);
  {
    dim3 g(B_ * N_ / 64, 20);
    k_qvk<<<g, 64, 0, stream>>>(sl1, sl2, sl3, qv_w, qv_b, k_w, k_b,
                                qxb, qyb, kbf, vtb);
  }
  // C. attention v8 (MFMA)
  {
    dim3 g(N_ / 16, B_ * NH_);
    k_attn8<<<g, 128, 0, stream>>>(qxb, qyb, kbf, vtb, sl1, sl2);
  }
  // D. proj v4 -> xo4(3,4) + XTC0 bf16
  {
    dim3 g(36, C_ / 2, 2 * B_);
    k_proj4<<<g, 64, 0, stream>>>(sl1, x, y, bnd_g, bnd_b, bnd_m, bnd_v,
                                  proj_w, proj_b, xo4, xtC0);
  }
  // guards for c2 XT buffers
  k_zg<<<96, 256, 0, stream>>>(xtC0, xtC1, 4, 64);
  // E. conv1 via MFMA -> XTC1
  {
    dim3 g(N_ / 16, 4, 4);
    k_fmma<2><<<g, 64, 0, stream>>>(xtC0, wbc1, c2b1,
        c2bn1_g, c2bn1_b, c2bn1_m, c2bn1_v, nullptr, xtC1, nullptr);
  }
  // F. conv2 via MFMA (+resid) -> o2(5,6)
  {
    dim3 g(N_ / 16, 4, 4);
    k_fmma<3><<<g, 64, 0, stream>>>(xtC1, wbc2, c2b2,
        c2bn2_g, c2bn2_b, c2bn2_m, c2bn2_v, xo4, nullptr, o2);
  }
  // guards for f XT buffers
  k_zg<<<96, 256, 0, stream>>>(xtF1, xtF2, 2, 128);
  // G. cat + bn2 -> cat(3,4) + XTF1 bf16
  k_catbn<<<576, 256, 0, stream>>>(o2, bn2_g, bn2_b, bn2_m, bn2_v,
                                   sl3, xtF1);
  // H. f-branch via MFMA tap-GEMMs
  {
    dim3 g(N_ / 16, 8, B_);
    k_fmma<0><<<g, 64, 0, stream>>>(xtF1, wbf1, nullptr,
        fbn1_g, fbn1_b, fbn1_m, fbn1_v, nullptr, xtF2, nullptr);
    k_fmma<1><<<g, 64, 0, stream>>>(xtF2, wbf2, nullptr,
        nullptr, nullptr, nullptr, nullptr, nullptr, nullptr, f2o);
  }
  // I. final (single-input) -> fp32 out
  {
    dim3 g(18, C_, B_);
    k_final3<<<g, 64, 0, stream>>>(f2o, S_,
                                   fbn2_g, fbn2_b, fbn2_m, fbn2_v,
                                   sl3, f3w, f3b, (float*)d_out);
  }
}

// Round 15
// 304.878 us; speedup vs baseline: 1.8538x; 1.0554x over previous
//
#include <hip/hip_runtime.h>
#include <hip/hip_bf16.h>

#define B_   2
#define C_   64
#define H_   48
#define W_   48
#define N_   (H_*W_)     // 2304
#define NH_  8
#define HD_  8
#define EPS_ 1e-5f
#define S2_  0.125f      // scale^2 = 1/hd
#define LOG2E_ 1.44269504f
#define FS_  (S2_ * LOG2E_)
#define S_   ((size_t)B_ * C_ * N_)   // 294912 floats per workspace slot
#define CN_  ((size_t)C_ * N_)        // 147456 floats per image
#define XTSZ_ ((size_t)(N_ + 2 * W_) * 128)  // bf16 elems per 128-ch image
#define XTSC_ ((size_t)(N_ + 2 * W_) * 64)   // bf16 elems per 64-ch image

typedef unsigned short u16;
typedef __attribute__((ext_vector_type(8))) short short8v;
typedef __attribute__((ext_vector_type(4))) float f32x4;
union F8 { uint4 u4; short8v s; unsigned int w[4]; };

__device__ __forceinline__ float wsum64(float v) {
#pragma unroll
  for (int o = 32; o > 0; o >>= 1) v += __shfl_xor(v, o, 64);
  return v;
}

__device__ __forceinline__ float ln_val(float t, float g, float b) {
  float mu  = wsum64(t) * (1.0f / 64.0f);
  float d   = t - mu;
  float var = wsum64(d * d) * (1.0f / 64.0f);
  return d * rsqrtf(var + EPS_) * g + b;
}

// round-to-nearest-even f32 -> bf16 (finite inputs only)
__device__ __forceinline__ u16 f2bf(float x) {
  union { float f; unsigned int u; } a; a.f = x;
  unsigned int r = a.u + 0x7fffu + ((a.u >> 16) & 1u);
  return (u16)(r >> 16);
}

// ---- fused 1x1 pconv + BN + 3x LayerNorm; v2: 16 rows/block, LDS pw^T ----
__global__ __launch_bounds__(1024) void k_pre(
    const float* __restrict__ x, const float* __restrict__ y,
    const float* __restrict__ pw, const float* __restrict__ pb,
    const float* g, const float* bb, const float* m, const float* v,
    const float* lnxg, const float* lnxb,
    const float* lnyg, const float* lnyb,
    const float* lnzg, const float* lnzb,
    float* __restrict__ xl, float* __restrict__ yl, float* __restrict__ zl) {
  __shared__ float4 pwT[32][64];           // pwT[i4][c] = pw[c][4*i4..+3]
  __shared__ float xs[16][64], ys[16][64];
  int w = threadIdx.x >> 6, c = threadIdx.x & 63;
  for (int idx = threadIdx.x; idx < 2048; idx += 1024) {
    int cc = idx & 63, i4 = idx >> 6;
    pwT[i4][cc] = *(const float4*)(pw + (size_t)cc * 2 * C_ + i4 * 4);
  }
  int row = blockIdx.x * 16 + w;           // b*N + n
  int b = row / N_, n = row % N_;
  float xv = x[(size_t)(b * C_ + c) * N_ + n];
  float yv = y[(size_t)(b * C_ + c) * N_ + n];
  xs[w][c] = xv; ys[w][c] = yv;
  __syncthreads();
  const float4* xw = (const float4*)xs[w];
  const float4* yw = (const float4*)ys[w];
  float acc = pb[c];
#pragma unroll
  for (int t = 0; t < 16; ++t) {
    float4 a = xw[t], wv = pwT[t][c];
    acc += a.x * wv.x + a.y * wv.y + a.z * wv.z + a.w * wv.w;
  }
#pragma unroll
  for (int t = 0; t < 16; ++t) {
    float4 a = yw[t], wv = pwT[16 + t][c];
    acc += a.x * wv.x + a.y * wv.y + a.z * wv.z + a.w * wv.w;
  }
  float s  = g[c] * rsqrtf(v[c] + EPS_);
  float sh = bb[c] - m[c] * s;
  float tx = xv * s + sh;
  xl[(size_t)row * C_ + c] = ln_val(tx, lnxg[c], lnxb[c]);
  float ty = yv * s + sh;
  yl[(size_t)row * C_ + c] = ln_val(ty, lnyg[c], lnyb[c]);
  float tz = acc * s + sh;
  zl[(size_t)row * C_ + c] = ln_val(tz, lnzg[c], lnzb[c]);
}

// ------------- qv/k projection v2: lane = row, uniform weights ------------
__global__ __launch_bounds__(64) void k_qvk(
    const float* __restrict__ xl, const float* __restrict__ yl,
    const float* __restrict__ zl,
    const float* __restrict__ qvw, const float* __restrict__ qvb,
    const float* __restrict__ kw, const float* __restrict__ kb,
    u16* __restrict__ qxb, u16* __restrict__ qyb,
    u16* __restrict__ kbf, u16* __restrict__ vt) {
  int l = threadIdx.x;
  int part = blockIdx.y >> 2;
  int j0 = (blockIdx.y & 3) * 16;
  int row = blockIdx.x * 64 + l;
  int b = row / N_, n = row % N_;
  const float* inp = (part < 2) ? xl : (part < 4) ? yl : zl;
  float4 in[16];
  const float4* ir = (const float4*)(inp + (size_t)row * C_);
#pragma unroll
  for (int t = 0; t < 16; ++t) in[t] = ir[t];

  const float* wb   = (part == 4) ? kw : qvw;
  const float* bias = (part == 4) ? kb : qvb;
  int joff = (part == 1 || part == 3) ? 64 : 0;

  if (part == 1 || part == 3) {
    int vbase = (part == 1) ? 0 : 8;
#pragma unroll
    for (int jj = 0; jj < 16; ++jj) {
      int j = j0 + jj;
      const float4* wr = (const float4*)(wb + (size_t)(joff + j) * C_);
      float acc = bias[joff + j];
#pragma unroll
      for (int t = 0; t < 16; ++t) {
        float4 a = in[t], wv = wr[t];
        acc += a.x * wv.x + a.y * wv.y + a.z * wv.z + a.w * wv.w;
      }
      int h = j >> 3, d = j & 7;
      vt[((size_t)((b * NH_ + h) * 16 + vbase + d)) * N_ + n] = f2bf(acc);
    }
  } else {
    u16* dst = (part == 0) ? qxb : (part == 2) ? qyb : kbf;
#pragma unroll
    for (int gg = 0; gg < 2; ++gg) {
      int h = (j0 >> 3) + gg;
      union { uint4 u4; u16 s[8]; } pk;
#pragma unroll
      for (int d = 0; d < 8; ++d) {
        int j = h * 8 + d;
        const float4* wr = (const float4*)(wb + (size_t)(joff + j) * C_);
        float acc = bias[joff + j];
#pragma unroll
        for (int t = 0; t < 16; ++t) {
          float4 a = in[t], wv = wr[t];
          acc += a.x * wv.x + a.y * wv.y + a.z * wv.z + a.w * wv.w;
        }
        if (part == 0) acc *= FS_;
        pk.s[d] = f2bf(acc);
      }
      *(uint4*)(dst + ((size_t)(b * NH_ + h) * N_ + n) * 8) = pk.u4;
    }
  }
}

// ---- attention v8b: MFMA flash, 16-q tile, dual-branch, bf16 att out -----
__global__ __launch_bounds__(128, 5) void k_attn8(
    const u16* __restrict__ qx, const u16* __restrict__ qy,
    const u16* __restrict__ kk, const u16* __restrict__ vt,
    u16* __restrict__ outx, u16* __restrict__ outy) {
  __shared__ float sAcc[2][4][64];
  __shared__ float sL[2][16];
  int qt = blockIdx.x, bh = blockIdx.y;
  int tid = threadIdx.x;
  int lane = tid & 63;
  int wave = tid >> 6;
  int l15 = lane & 15;
  int q0 = qt * 16;

  F8 qxf, qyf;
  size_t qoff = ((size_t)bh * N_ + q0 + l15) * 8;
  qxf.u4 = *(const uint4*)(qx + qoff);
  qyf.u4 = *(const uint4*)(qy + qoff);
  if (lane >= 16) {
    qxf.u4 = make_uint4(0u, 0u, 0u, 0u);
    qyf.u4 = make_uint4(0u, 0u, 0u, 0u);
  }

  int key0 = wave * (N_ / 2);
  const uint4* kp = (const uint4*)(kk + (size_t)bh * N_ * 8) + key0 + l15;
  const uint4* vp = (const uint4*)(vt + ((size_t)bh * 16 + l15) * N_ + key0)
                    + (lane >> 4);
  int addr0 = (((lane >> 4) & 1) * 32 + l15) * 4;
  int addr1 = addr0 + 64;
  int thi = lane >> 5;

  f32x4 acc = {0.f, 0.f, 0.f, 0.f};
  const f32x4 z4 = {0.f, 0.f, 0.f, 0.f};
  float lsum = 0.f;

  F8 ka, kb2, vf;
  ka.u4 = kp[0]; kb2.u4 = kp[16]; vf.u4 = *vp;
  for (int c = 0; c < 36; ++c) {
    F8 kaC = ka, kbC = kb2, vfC = vf;
    kp += 32; vp += 4;
    ka.u4 = kp[0]; kb2.u4 = kp[16]; vf.u4 = *vp;   // prefetch next chunk

    f32x4 s1a = __builtin_amdgcn_mfma_f32_16x16x32_bf16(kaC.s, qxf.s, z4, 0, 0, 0);
    f32x4 s2a = __builtin_amdgcn_mfma_f32_16x16x32_bf16(kaC.s, qyf.s, z4, 0, 0, 0);
    f32x4 s1b = __builtin_amdgcn_mfma_f32_16x16x32_bf16(kbC.s, qxf.s, z4, 0, 0, 0);
    f32x4 s2b = __builtin_amdgcn_mfma_f32_16x16x32_bf16(kbC.s, qyf.s, z4, 0, 0, 0);

    float p00 = exp2f(s1a[0] * s2a[0]), p01 = exp2f(s1a[1] * s2a[1]);
    float p02 = exp2f(s1a[2] * s2a[2]), p03 = exp2f(s1a[3] * s2a[3]);
    float p10 = exp2f(s1b[0] * s2b[0]), p11 = exp2f(s1b[1] * s2b[1]);
    float p12 = exp2f(s1b[2] * s2b[2]), p13 = exp2f(s1b[3] * s2b[3]);
    lsum += ((p00 + p01) + (p02 + p03)) + ((p10 + p11) + (p12 + p13));

    unsigned int pk00, pk10, pk01, pk11;
    asm("v_cvt_pk_bf16_f32 %0, %1, %2" : "=v"(pk00) : "v"(p00), "v"(p01));
    asm("v_cvt_pk_bf16_f32 %0, %1, %2" : "=v"(pk10) : "v"(p02), "v"(p03));
    asm("v_cvt_pk_bf16_f32 %0, %1, %2" : "=v"(pk01) : "v"(p10), "v"(p11));
    asm("v_cvt_pk_bf16_f32 %0, %1, %2" : "=v"(pk11) : "v"(p12), "v"(p13));

    int b00 = __builtin_amdgcn_ds_bpermute(addr0, (int)pk00);
    int b01 = __builtin_amdgcn_ds_bpermute(addr0, (int)pk01);
    int b10 = __builtin_amdgcn_ds_bpermute(addr0, (int)pk10);
    int b11 = __builtin_amdgcn_ds_bpermute(addr0, (int)pk11);
    int c00 = __builtin_amdgcn_ds_bpermute(addr1, (int)pk00);
    int c01 = __builtin_amdgcn_ds_bpermute(addr1, (int)pk01);
    int c10 = __builtin_amdgcn_ds_bpermute(addr1, (int)pk10);
    int c11 = __builtin_amdgcn_ds_bpermute(addr1, (int)pk11);

    F8 pf;
    pf.w[0] = (unsigned int)(thi ? b01 : b00);
    pf.w[1] = (unsigned int)(thi ? b11 : b10);
    pf.w[2] = (unsigned int)(thi ? c01 : c00);
    pf.w[3] = (unsigned int)(thi ? c11 : c10);
    acc = __builtin_amdgcn_mfma_f32_16x16x32_bf16(pf.s, vfC.s, acc, 0, 0, 0);
  }

  lsum += __shfl_xor(lsum, 16, 64);
  lsum += __shfl_xor(lsum, 32, 64);
  if (lane < 16) sL[wave][lane] = lsum;
#pragma unroll
  for (int r = 0; r < 4; ++r) sAcc[wave][r][lane] = acc[r];
  __syncthreads();
  if (wave == 0) {
    float Linv = 1.f / (sL[0][l15] + sL[1][l15]);
    int b = bh >> 3, h = bh & 7;
    int d = l15 & 7;
    u16* ob = (l15 < 8) ? outx : outy;
    size_t cbase = (size_t)b * N_ * C_ + (size_t)h * 8 + d;
#pragma unroll
    for (int r = 0; r < 4; ++r) {
      int qrow = 4 * (lane >> 4) + r;
      float li = __shfl(Linv, qrow, 64);
      float a = sAcc[0][r][lane] + sAcc[1][r][lane];
      ob[cbase + (size_t)(q0 + qrow) * C_] = f2bf(a * li);
    }
  }
}

// -------- proj via MFMA: K=64, 2 chunks; epilogue bnd-resid ---------------
// grid (N_/16, 4, 4), block 64. z = branch*2 + b.
__global__ __launch_bounds__(64) void k_projm(
    const u16* __restrict__ attx, const u16* __restrict__ atty,
    const float* __restrict__ x, const float* __restrict__ y,
    const float* bg, const float* bb2, const float* bm, const float* bv,
    const u16* __restrict__ pwb, const float* __restrict__ pbias,
    float* __restrict__ xo4, u16* __restrict__ xt0) {
  int l = threadIdx.x;
  int c = l & 15, gg = l >> 4;
  int px0 = blockIdx.x * 16;
  int ct0 = blockIdx.y * 16;
  int z = blockIdx.z;
  int branch = z >> 1, b = z & 1;
  const u16* att = (branch ? atty : attx) + (size_t)b * N_ * 64;
  const u16* aw = pwb + (size_t)(ct0 + c) * 64 + gg * 8;
  f32x4 acc = {0.f, 0.f, 0.f, 0.f};
#pragma unroll
  for (int cb = 0; cb < 2; ++cb) {
    F8 af, bf;
    af.u4 = *(const uint4*)(aw + cb * 32);
    bf.u4 = *(const uint4*)(att + (size_t)(px0 + c) * 64 + cb * 32 + gg * 8);
    acc = __builtin_amdgcn_mfma_f32_16x16x32_bf16(af.s, bf.s, acc, 0, 0, 0);
  }
  int px = px0 + c;
  const float* xin = branch ? y : x;
#pragma unroll
  for (int r = 0; r < 4; ++r) {
    int cout = ct0 + 4 * gg + r;
    float s  = bg[cout] * rsqrtf(bv[cout] + EPS_);
    float sh = bb2[cout] - bm[cout] * s;
    float rr = xin[((size_t)b * C_ + cout) * N_ + px];
    float vv = acc[r] + pbias[cout] + rr * s + sh;
    xo4[(size_t)z * CN_ + (size_t)cout * N_ + px] = vv;
    xt0[(size_t)z * XTSC_ + (size_t)(W_ + px) * 64 + cout] = f2bf(vv);
  }
}

// ------ cat + bn2 -> cat(fp32), XTf1 bf16, and zero XTF2 guards -----------
__global__ void k_catbn(const float* __restrict__ o2,
                        const float* __restrict__ g, const float* __restrict__ b2,
                        const float* __restrict__ m, const float* __restrict__ v,
                        float* __restrict__ cat, u16* __restrict__ xt1,
                        u16* __restrict__ xtf2) {
  int t = blockIdx.x * 256 + threadIdx.x;
  if (t < 12288) {   // zero XTF2 guard rows (2 imgs x 2 guards x 3072 u32)
    int img = t / 6144, r2 = t - img * 6144;
    int hi = r2 / 3072, o = r2 - hi * 3072;
    ((unsigned int*)(xtf2 + (size_t)img * XTSZ_
                     + (hi ? (size_t)(W_ + N_) * 128 : 0)))[o] = 0u;
  }
  int p4 = t * 4;
  int n  = p4 % N_;
  int c2 = (p4 / N_) % (2 * C_);
  int b  = p4 / (2 * C_ * N_);
  int c  = c2 & 63;
  float4 X = *(const float4*)(o2 + (size_t)b * CN_ + (size_t)c * N_ + n);
  float4 Y = *(const float4*)(o2 + (size_t)(2 + b) * CN_ + (size_t)c * N_ + n);
  float4 val;
  if (c2 < C_) val = make_float4(X.x + Y.x, X.y + Y.y, X.z + Y.z, X.w + Y.w);
  else         val = make_float4(X.x * Y.x, X.y * Y.y, X.z * Y.z, X.w * Y.w);
  size_t co = ((size_t)b * 2 * C_ + c2) * N_ + n;
  *(float4*)(cat + co) = val;
  float s  = g[c2] * rsqrtf(v[c2] + EPS_);
  float sh = b2[c2] - m[c2] * s;
  u16* xb = xt1 + (size_t)b * XTSZ_ + (size_t)(W_ + n) * 128 + c2;
  xb[0]   = f2bf(val.x * s + sh);
  xb[128] = f2bf(val.y * s + sh);
  xb[256] = f2bf(val.z * s + sh);
  xb[384] = f2bf(val.w * s + sh);
}

// ------ zero guard rows: XTC0, XTC1 (64ch, 4 imgs), XTF1 (128ch, 2 imgs) --
__global__ void k_zg1(u16* __restrict__ c0, u16* __restrict__ c1,
                      u16* __restrict__ f1) {
  int idx = blockIdx.x * 256 + threadIdx.x;
  if (idx >= 36864) return;
  int seg = idx / 12288, r = idx - seg * 12288;
  u16* base; int cinc;
  if (seg == 0)      { base = c0; cinc = 64; }
  else if (seg == 1) { base = c1; cinc = 64; }
  else               { base = f1; cinc = 128; }
  int gsz = W_ * cinc / 2;
  int img = r / (2 * gsz), r2 = r - img * (2 * gsz);
  int hi = r2 / gsz, o = r2 - hi * gsz;
  ((unsigned int*)(base + (size_t)img * (N_ + 2 * W_) * cinc
                   + (hi ? (size_t)(W_ + N_) * cinc : 0)))[o] = 0u;
}

// ------ convert conv/proj weights -> bf16 tap-major -----------------------
// wb: [0,147456) f1w; [147456,294912) f2w; [294912,331776) c2w1;
//     [331776,368640) c2w2; [368640,385024) f3w; [385024,389120) proj_w.
__global__ void k_wcvt(const float* __restrict__ w1,
                       const float* __restrict__ w2,
                       const float* __restrict__ cw1,
                       const float* __restrict__ cw2,
                       const float* __restrict__ w3,
                       const float* __restrict__ pjw,
                       u16* __restrict__ wb) {
  int idx = blockIdx.x * 256 + threadIdx.x;
  if (idx >= 389120) return;
  if (idx < 294912) {
    int layer = idx / 147456, rem = idx - layer * 147456;
    int t = rem / 16384, r2 = rem - t * 16384;
    int co = r2 >> 7, ci = r2 & 127;
    wb[idx] = f2bf((layer ? w2 : w1)[(size_t)co * 1152 + ci * 9 + t]);
  } else if (idx < 368640) {
    int k = idx - 294912;
    int layer = k / 36864, rem = k - layer * 36864;
    int t = rem / 4096, r2 = rem - t * 4096;
    int co = r2 >> 6, ci = r2 & 63;
    wb[idx] = f2bf((layer ? cw2 : cw1)[(size_t)co * 576 + ci * 9 + t]);
  } else if (idx < 385024) {
    wb[idx] = f2bf(w3[idx - 368640]);    // [cout][ci] identity
  } else {
    wb[idx] = f2bf(pjw[idx - 385024]);   // [cout][ci] identity
  }
}

// ===== conv as 9 tap-GEMMs on MFMA ========================================
// MODE 0: 128ci, bn+relu -> bf16 XT out 128ch (used for f1 AND f2)
// MODE 2: c2 conv1 (64ci, +bias, bn, relu -> bf16 XT out 64ch)
// MODE 3: c2 conv2 (64ci, +bias, bn, relu, +resid -> fp32 [img][cout][px])
template<int MODE>
__global__ __launch_bounds__(64) void k_fmma(
    const u16* __restrict__ xt, const u16* __restrict__ wb,
    const float* __restrict__ cbias,
    const float* g, const float* b2, const float* m, const float* v,
    const float* __restrict__ resid,
    u16* __restrict__ xto, float* __restrict__ fo) {
  constexpr int CIN  = (MODE >= 2) ? 64 : 128;
  constexpr int NCB  = CIN / 32;
  constexpr int COUT = (MODE >= 2) ? 64 : 128;
  constexpr int TS   = CIN * COUT;
  constexpr size_t XTS = (size_t)(N_ + 2 * W_) * CIN;
  constexpr size_t XTSO = (size_t)(N_ + 2 * W_) * COUT;
  int l = threadIdx.x;
  int c = l & 15, gg = l >> 4;
  int px0 = blockIdx.x * 16;
  int ct0 = blockIdx.y * 16;
  int b = blockIdx.z;
  int x0 = px0 % W_;                       // 0, 16, or 32
  bool mL = (x0 == 0) && (c == 0);
  bool mR = (x0 == 32) && (c == 15);
  const u16* xb = xt + (size_t)b * XTS + (size_t)W_ * CIN;
  const u16* aw = wb + (size_t)(ct0 + c) * CIN + gg * 8;

  f32x4 acc = {0.f, 0.f, 0.f, 0.f};
#pragma unroll
  for (int cb = 0; cb < NCB; ++cb) {
#pragma unroll
    for (int t = 0; t < 9; ++t) {
      const int dx = t % 3 - 1, dy = t / 3 - 1;
      F8 af, bf;
      af.u4 = *(const uint4*)(aw + t * TS + cb * 32);
      int px = px0 + c + dx + dy * W_;
      px = max(px, -W_);                   // clamp into guard (no OOB)
      bf.u4 = *(const uint4*)(xb + (ptrdiff_t)px * CIN + cb * 32 + gg * 8);
      bool msk = (dx < 0 && mL) || (dx > 0 && mR);
      if (msk) bf.u4 = make_uint4(0u, 0u, 0u, 0u);
      acc = __builtin_amdgcn_mfma_f32_16x16x32_bf16(af.s, bf.s, acc, 0, 0, 0);
    }
  }
  int px = px0 + c;
  if (MODE == 0 || MODE == 2) {
    union { ushort4 u; u16 s[4]; } pk;
#pragma unroll
    for (int r = 0; r < 4; ++r) {
      int cout = ct0 + 4 * gg + r;
      float a = acc[r] + (MODE == 2 ? cbias[cout] : 0.f);
      float s = g[cout] * rsqrtf(v[cout] + EPS_);
      float sh = b2[cout] - m[cout] * s;
      pk.s[r] = f2bf(fmaxf(a * s + sh, 0.f));
    }
    *(ushort4*)(xto + (size_t)b * XTSO + (size_t)(W_ + px) * COUT
                + ct0 + 4 * gg) = pk.u;
  } else {  // MODE 3
#pragma unroll
    for (int r = 0; r < 4; ++r) {
      int cout = ct0 + 4 * gg + r;
      float a = acc[r] + cbias[cout];
      float s = g[cout] * rsqrtf(v[cout] + EPS_);
      float sh = b2[cout] - m[cout] * s;
      size_t off = (size_t)b * CN_ + (size_t)cout * N_ + px;
      fo[off] = fmaxf(a * s + sh, 0.f) + resid[off];
    }
  }
}

// -------- f3 1x1 conv via MFMA: K=128, +f3b + cat -> out ------------------
// grid (N_/16, 8, B_), block 64.
__global__ __launch_bounds__(64) void k_f3mma(
    const u16* __restrict__ xt3, const u16* __restrict__ w3b,
    const float* __restrict__ f3b, const float* __restrict__ cat,
    float* __restrict__ out) {
  int l = threadIdx.x;
  int c = l & 15, gg = l >> 4;
  int px0 = blockIdx.x * 16;
  int ct0 = blockIdx.y * 16;
  int b = blockIdx.z;
  const u16* xb = xt3 + (size_t)b * XTSZ_ + (size_t)W_ * 128;
  const u16* aw = w3b + (size_t)(ct0 + c) * 128 + gg * 8;
  f32x4 acc = {0.f, 0.f, 0.f, 0.f};
#pragma unroll
  for (int cb = 0; cb < 4; ++cb) {
    F8 af, bf;
    af.u4 = *(const uint4*)(aw + cb * 32);
    bf.u4 = *(const uint4*)(xb + (size_t)(px0 + c) * 128 + cb * 32 + gg * 8);
    acc = __builtin_amdgcn_mfma_f32_16x16x32_bf16(af.s, bf.s, acc, 0, 0, 0);
  }
  int px = px0 + c;
#pragma unroll
  for (int r = 0; r < 4; ++r) {
    int cout = ct0 + 4 * gg + r;
    size_t off = ((size_t)b * 2 * C_ + cout) * N_ + px;
    out[off] = acc[r] + f3b[cout] + cat[off];
  }
}

extern "C" void kernel_launch(void* const* d_in, const int* in_sizes, int n_in,
                              void* d_out, int out_size, void* d_ws, size_t ws_size,
                              hipStream_t stream) {
  const float* x       = (const float*)d_in[0];
  const float* y       = (const float*)d_in[1];
  const float* pconv_w = (const float*)d_in[2];
  const float* pconv_b = (const float*)d_in[3];
  const float* bnd_g = (const float*)d_in[4];
  const float* bnd_b = (const float*)d_in[5];
  const float* bnd_m = (const float*)d_in[6];
  const float* bnd_v = (const float*)d_in[7];
  const float* lnx_g = (const float*)d_in[8];
  const float* lnx_b = (const float*)d_in[9];
  const float* lny_g = (const float*)d_in[10];
  const float* lny_b = (const float*)d_in[11];
  const float* lnz_g = (const float*)d_in[12];
  const float* lnz_b = (const float*)d_in[13];
  const float* k_w   = (const float*)d_in[14];
  const float* k_b   = (const float*)d_in[15];
  const float* qv_w  = (const float*)d_in[16];
  const float* qv_b  = (const float*)d_in[17];
  const float* proj_w = (const float*)d_in[18];
  const float* proj_b = (const float*)d_in[19];
  const float* c2w1  = (const float*)d_in[20];
  const float* c2b1  = (const float*)d_in[21];
  const float* c2bn1_g = (const float*)d_in[22];
  const float* c2bn1_b = (const float*)d_in[23];
  const float* c2bn1_m = (const float*)d_in[24];
  const float* c2bn1_v = (const float*)d_in[25];
  const float* c2w2  = (const float*)d_in[26];
  const float* c2b2  = (const float*)d_in[27];
  const float* c2bn2_g = (const float*)d_in[28];
  const float* c2bn2_b = (const float*)d_in[29];
  const float* c2bn2_m = (const float*)d_in[30];
  const float* c2bn2_v = (const float*)d_in[31];
  const float* bn2_g = (const float*)d_in[32];
  const float* bn2_b = (const float*)d_in[33];
  const float* bn2_m = (const float*)d_in[34];
  const float* bn2_v = (const float*)d_in[35];
  const float* f1w   = (const float*)d_in[36];
  const float* fbn1_g = (const float*)d_in[37];
  const float* fbn1_b = (const float*)d_in[38];
  const float* fbn1_m = (const float*)d_in[39];
  const float* fbn1_v = (const float*)d_in[40];
  const float* f2w   = (const float*)d_in[41];
  const float* fbn2_g = (const float*)d_in[42];
  const float* fbn2_b = (const float*)d_in[43];
  const float* fbn2_m = (const float*)d_in[44];
  const float* fbn2_v = (const float*)d_in[45];
  const float* f3w   = (const float*)d_in[46];
  const float* f3b   = (const float*)d_in[47];

  // Workspace plan (floats; slot = S_):
  //   A: k_pre -> xl(1) yl(2) zl(3)
  //   B: qvk -> qx[4,4.5) qy[4.5,5) kbf[5,5.5) vt[6,7)
  //   C: attn8 -> attx bf16 [1,1.5), atty [1.5,2)
  //   D: projm -> xo4 fp32 [3,5) + XTC0 bf16 [5,6.05)
  //   [zg1: XTC0, XTC1[0,1.05), XTF1[1.25,2.30) guards]
  //   E: fmma<2>: XTC0 -> XTC1 [0,1.05)
  //   F: fmma<3>: XTC1 + xo4 -> o2 [5,7)
  //   G: catbn: o2 -> cat [3,5) + XTF1 [1.25,2.30) + zero XTF2[0,1.05) guards
  //   H1: fmma<0> f1 (fbn1): XTF1 -> XTF2 [0,1.05)
  //   H2: fmma<0> f2 (fbn2): XTF2 -> xt3 [1.25,2.30)
  //   I: f3mma: xt3 + cat -> out
  //   wb @ [7, 7.67)
  float* ws = (float*)d_ws;
  float* sl1 = ws + 1 * S_;
  float* sl2 = ws + 2 * S_;
  float* sl3 = ws + 3 * S_;
  u16* attx = (u16*)(ws + 1 * S_);
  u16* atty = attx + (size_t)B_ * N_ * 64;
  u16* xtC0 = (u16*)(ws + 5 * S_);
  u16* xtC1 = (u16*)ws;
  u16* xtF1 = (u16*)(ws + 5 * S_ / 4);
  u16* xtF2 = (u16*)ws;
  u16* xt3  = (u16*)(ws + 5 * S_ / 4);
  float* xo4 = ws + 3 * S_;
  float* o2  = ws + 5 * S_;
  float* cat = ws + 3 * S_;
  u16* wb   = (u16*)(ws + 7 * S_);
  u16* wbf1 = wb;
  u16* wbf2 = wb + 147456;
  u16* wbc1 = wb + 294912;
  u16* wbc2 = wb + 331776;
  u16* wb3  = wb + 368640;
  u16* wbp  = wb + 385024;

  // A. fused pconv + bn + ln
  k_pre<<<B_ * N_ / 16, 1024, 0, stream>>>(x, y, pconv_w, pconv_b,
                                    bnd_g, bnd_b, bnd_m, bnd_v,
                                    lnx_g, lnx_b, lny_g, lny_b, lnz_g, lnz_b,
                                    sl1, sl2, sl3);
  // weights -> bf16 (independent)
  k_wcvt<<<1520, 256, 0, stream>>>(f1w, f2w, c2w1, c2w2, f3w, proj_w, wb);
  // B. qv/k projection
  u16* qxb = (u16*)(ws + 4 * S_);
  u16* qyb = qxb + (size_t)B_ * NH_ * N_ * 8;
  u16* kbf = (u16*)(ws + 5 * S_);
  u16* vtb = (u16*)(ws + 6 * S_);
  {
    dim3 g(B_ * N_ / 64, 20);
    k_qvk<<<g, 64, 0, stream>>>(sl1, sl2, sl3, qv_w, qv_b, k_w, k_b,
                                qxb, qyb, kbf, vtb);
  }
  // C. attention (bf16 att out)
  {
    dim3 g(N_ / 16, B_ * NH_);
    k_attn8<<<g, 128, 0, stream>>>(qxb, qyb, kbf, vtb, attx, atty);
  }
  // D. proj via MFMA -> xo4 + XTC0
  {
    dim3 g(N_ / 16, 4, 4);
    k_projm<<<g, 64, 0, stream>>>(attx, atty, x, y,
                                  bnd_g, bnd_b, bnd_m, bnd_v,
                                  wbp, proj_b, xo4, xtC0);
  }
  // guards: XTC0, XTC1, XTF1
  k_zg1<<<144, 256, 0, stream>>>(xtC0, xtC1, xtF1);
  // E. conv1 via MFMA -> XTC1
  {
    dim3 g(N_ / 16, 4, 4);
    k_fmma<2><<<g, 64, 0, stream>>>(xtC0, wbc1, c2b1,
        c2bn1_g, c2bn1_b, c2bn1_m, c2bn1_v, nullptr, xtC1, nullptr);
  }
  // F. conv2 via MFMA (+resid) -> o2
  {
    dim3 g(N_ / 16, 4, 4);
    k_fmma<3><<<g, 64, 0, stream>>>(xtC1, wbc2, c2b2,
        c2bn2_g, c2bn2_b, c2bn2_m, c2bn2_v, xo4, nullptr, o2);
  }
  // G. cat + bn2 -> cat + XTF1 (+ zero XTF2 guards)
  k_catbn<<<576, 256, 0, stream>>>(o2, bn2_g, bn2_b, bn2_m, bn2_v,
                                   cat, xtF1, xtF2);
  // H. f-branch via MFMA tap-GEMMs
  {
    dim3 g(N_ / 16, 8, B_);
    k_fmma<0><<<g, 64, 0, stream>>>(xtF1, wbf1, nullptr,
        fbn1_g, fbn1_b, fbn1_m, fbn1_v, nullptr, xtF2, nullptr);
    k_fmma<0><<<g, 64, 0, stream>>>(xtF2, wbf2, nullptr,
        fbn2_g, fbn2_b, fbn2_m, fbn2_v, nullptr, xt3, nullptr);
  }
  // I. f3 1x1 + cat -> out
  {
    dim3 g(N_ / 16, 8, B_);
    k_f3mma<<<g, 64, 0, stream>>>(xt3, wb3, f3b, cat, (float*)d_out);
  }
}

// Round 16
// 303.139 us; speedup vs baseline: 1.8644x; 1.0057x over previous
//
#include <hip/hip_runtime.h>
#include <hip/hip_bf16.h>

#define B_   2
#define C_   64
#define H_   48
#define W_   48
#define N_   (H_*W_)     // 2304
#define NH_  8
#define HD_  8
#define EPS_ 1e-5f
#define S2_  0.125f      // scale^2 = 1/hd
#define LOG2E_ 1.44269504f
#define FS_  (S2_ * LOG2E_)
#define S_   ((size_t)B_ * C_ * N_)   // 294912 floats per workspace slot
#define CN_  ((size_t)C_ * N_)        // 147456 floats per image
#define XTSZ_ ((size_t)(N_ + 2 * W_) * 128)  // bf16 elems per 128-ch image
#define XTSC_ ((size_t)(N_ + 2 * W_) * 64)   // bf16 elems per 64-ch image

typedef unsigned short u16;
typedef __attribute__((ext_vector_type(8))) short short8v;
typedef __attribute__((ext_vector_type(4))) float f32x4;
union F8 { uint4 u4; short8v s; unsigned int w[4]; };

__device__ __forceinline__ float wsum64(float v) {
#pragma unroll
  for (int o = 32; o > 0; o >>= 1) v += __shfl_xor(v, o, 64);
  return v;
}

__device__ __forceinline__ float ln_val(float t, float g, float b) {
  float mu  = wsum64(t) * (1.0f / 64.0f);
  float d   = t - mu;
  float var = wsum64(d * d) * (1.0f / 64.0f);
  return d * rsqrtf(var + EPS_) * g + b;
}

// round-to-nearest-even f32 -> bf16 (finite inputs only)
__device__ __forceinline__ u16 f2bf(float x) {
  union { float f; unsigned int u; } a; a.f = x;
  unsigned int r = a.u + 0x7fffu + ((a.u >> 16) & 1u);
  return (u16)(r >> 16);
}

// ---- fused 1x1 pconv + BN + 3x LayerNorm; v2: 16 rows/block, LDS pw^T ----
__global__ __launch_bounds__(1024) void k_pre(
    const float* __restrict__ x, const float* __restrict__ y,
    const float* __restrict__ pw, const float* __restrict__ pb,
    const float* g, const float* bb, const float* m, const float* v,
    const float* lnxg, const float* lnxb,
    const float* lnyg, const float* lnyb,
    const float* lnzg, const float* lnzb,
    float* __restrict__ xl, float* __restrict__ yl, float* __restrict__ zl) {
  __shared__ float4 pwT[32][64];           // pwT[i4][c] = pw[c][4*i4..+3]
  __shared__ float xs[16][64], ys[16][64];
  int w = threadIdx.x >> 6, c = threadIdx.x & 63;
  for (int idx = threadIdx.x; idx < 2048; idx += 1024) {
    int cc = idx & 63, i4 = idx >> 6;
    pwT[i4][cc] = *(const float4*)(pw + (size_t)cc * 2 * C_ + i4 * 4);
  }
  int row = blockIdx.x * 16 + w;           // b*N + n
  int b = row / N_, n = row % N_;
  float xv = x[(size_t)(b * C_ + c) * N_ + n];
  float yv = y[(size_t)(b * C_ + c) * N_ + n];
  xs[w][c] = xv; ys[w][c] = yv;
  __syncthreads();
  const float4* xw = (const float4*)xs[w];
  const float4* yw = (const float4*)ys[w];
  float acc = pb[c];
#pragma unroll
  for (int t = 0; t < 16; ++t) {
    float4 a = xw[t], wv = pwT[t][c];
    acc += a.x * wv.x + a.y * wv.y + a.z * wv.z + a.w * wv.w;
  }
#pragma unroll
  for (int t = 0; t < 16; ++t) {
    float4 a = yw[t], wv = pwT[16 + t][c];
    acc += a.x * wv.x + a.y * wv.y + a.z * wv.z + a.w * wv.w;
  }
  float s  = g[c] * rsqrtf(v[c] + EPS_);
  float sh = bb[c] - m[c] * s;
  float tx = xv * s + sh;
  xl[(size_t)row * C_ + c] = ln_val(tx, lnxg[c], lnxb[c]);
  float ty = yv * s + sh;
  yl[(size_t)row * C_ + c] = ln_val(ty, lnyg[c], lnyb[c]);
  float tz = acc * s + sh;
  zl[(size_t)row * C_ + c] = ln_val(tz, lnzg[c], lnzb[c]);
}

// ------------- qv/k projection v2: lane = row, uniform weights ------------
__global__ __launch_bounds__(64) void k_qvk(
    const float* __restrict__ xl, const float* __restrict__ yl,
    const float* __restrict__ zl,
    const float* __restrict__ qvw, const float* __restrict__ qvb,
    const float* __restrict__ kw, const float* __restrict__ kb,
    u16* __restrict__ qxb, u16* __restrict__ qyb,
    u16* __restrict__ kbf, u16* __restrict__ vt) {
  int l = threadIdx.x;
  int part = blockIdx.y >> 2;
  int j0 = (blockIdx.y & 3) * 16;
  int row = blockIdx.x * 64 + l;
  int b = row / N_, n = row % N_;
  const float* inp = (part < 2) ? xl : (part < 4) ? yl : zl;
  float4 in[16];
  const float4* ir = (const float4*)(inp + (size_t)row * C_);
#pragma unroll
  for (int t = 0; t < 16; ++t) in[t] = ir[t];

  const float* wb   = (part == 4) ? kw : qvw;
  const float* bias = (part == 4) ? kb : qvb;
  int joff = (part == 1 || part == 3) ? 64 : 0;

  if (part == 1 || part == 3) {
    int vbase = (part == 1) ? 0 : 8;
#pragma unroll
    for (int jj = 0; jj < 16; ++jj) {
      int j = j0 + jj;
      const float4* wr = (const float4*)(wb + (size_t)(joff + j) * C_);
      float acc = bias[joff + j];
#pragma unroll
      for (int t = 0; t < 16; ++t) {
        float4 a = in[t], wv = wr[t];
        acc += a.x * wv.x + a.y * wv.y + a.z * wv.z + a.w * wv.w;
      }
      int h = j >> 3, d = j & 7;
      vt[((size_t)((b * NH_ + h) * 16 + vbase + d)) * N_ + n] = f2bf(acc);
    }
  } else {
    u16* dst = (part == 0) ? qxb : (part == 2) ? qyb : kbf;
#pragma unroll
    for (int gg = 0; gg < 2; ++gg) {
      int h = (j0 >> 3) + gg;
      union { uint4 u4; u16 s[8]; } pk;
#pragma unroll
      for (int d = 0; d < 8; ++d) {
        int j = h * 8 + d;
        const float4* wr = (const float4*)(wb + (size_t)(joff + j) * C_);
        float acc = bias[joff + j];
#pragma unroll
        for (int t = 0; t < 16; ++t) {
          float4 a = in[t], wv = wr[t];
          acc += a.x * wv.x + a.y * wv.y + a.z * wv.z + a.w * wv.w;
        }
        if (part == 0) acc *= FS_;
        pk.s[d] = f2bf(acc);
      }
      *(uint4*)(dst + ((size_t)(b * NH_ + h) * N_ + n) * 8) = pk.u4;
    }
  }
}

// ---- attention v8c: MFMA flash, dual PV acc chains, bf16 att out ---------
__global__ __launch_bounds__(128, 5) void k_attn8(
    const u16* __restrict__ qx, const u16* __restrict__ qy,
    const u16* __restrict__ kk, const u16* __restrict__ vt,
    u16* __restrict__ outx, u16* __restrict__ outy) {
  __shared__ float sAcc[2][4][64];
  __shared__ float sL[2][16];
  int qt = blockIdx.x, bh = blockIdx.y;
  int tid = threadIdx.x;
  int lane = tid & 63;
  int wave = tid >> 6;
  int l15 = lane & 15;
  int q0 = qt * 16;

  F8 qxf, qyf;
  size_t qoff = ((size_t)bh * N_ + q0 + l15) * 8;
  qxf.u4 = *(const uint4*)(qx + qoff);
  qyf.u4 = *(const uint4*)(qy + qoff);
  if (lane >= 16) {
    qxf.u4 = make_uint4(0u, 0u, 0u, 0u);
    qyf.u4 = make_uint4(0u, 0u, 0u, 0u);
  }

  int key0 = wave * (N_ / 2);
  const uint4* kp = (const uint4*)(kk + (size_t)bh * N_ * 8) + key0 + l15;
  const uint4* vp = (const uint4*)(vt + ((size_t)bh * 16 + l15) * N_ + key0)
                    + (lane >> 4);
  int addr0 = (((lane >> 4) & 1) * 32 + l15) * 4;
  int addr1 = addr0 + 64;
  int thi = lane >> 5;

  f32x4 acc0 = {0.f, 0.f, 0.f, 0.f};
  f32x4 acc1 = {0.f, 0.f, 0.f, 0.f};
  const f32x4 z4 = {0.f, 0.f, 0.f, 0.f};
  float lsum = 0.f;

  F8 ka, kb2, vf;
  ka.u4 = kp[0]; kb2.u4 = kp[16]; vf.u4 = *vp;
  for (int c = 0; c < 36; ++c) {
    F8 kaC = ka, kbC = kb2, vfC = vf;
    kp += 32; vp += 4;
    ka.u4 = kp[0]; kb2.u4 = kp[16]; vf.u4 = *vp;   // prefetch next chunk

    f32x4 s1a = __builtin_amdgcn_mfma_f32_16x16x32_bf16(kaC.s, qxf.s, z4, 0, 0, 0);
    f32x4 s2a = __builtin_amdgcn_mfma_f32_16x16x32_bf16(kaC.s, qyf.s, z4, 0, 0, 0);
    f32x4 s1b = __builtin_amdgcn_mfma_f32_16x16x32_bf16(kbC.s, qxf.s, z4, 0, 0, 0);
    f32x4 s2b = __builtin_amdgcn_mfma_f32_16x16x32_bf16(kbC.s, qyf.s, z4, 0, 0, 0);

    float p00 = exp2f(s1a[0] * s2a[0]), p01 = exp2f(s1a[1] * s2a[1]);
    float p02 = exp2f(s1a[2] * s2a[2]), p03 = exp2f(s1a[3] * s2a[3]);
    float p10 = exp2f(s1b[0] * s2b[0]), p11 = exp2f(s1b[1] * s2b[1]);
    float p12 = exp2f(s1b[2] * s2b[2]), p13 = exp2f(s1b[3] * s2b[3]);
    lsum += ((p00 + p01) + (p02 + p03)) + ((p10 + p11) + (p12 + p13));

    unsigned int pk00, pk10, pk01, pk11;
    asm("v_cvt_pk_bf16_f32 %0, %1, %2" : "=v"(pk00) : "v"(p00), "v"(p01));
    asm("v_cvt_pk_bf16_f32 %0, %1, %2" : "=v"(pk10) : "v"(p02), "v"(p03));
    asm("v_cvt_pk_bf16_f32 %0, %1, %2" : "=v"(pk01) : "v"(p10), "v"(p11));
    asm("v_cvt_pk_bf16_f32 %0, %1, %2" : "=v"(pk11) : "v"(p12), "v"(p13));

    int b00 = __builtin_amdgcn_ds_bpermute(addr0, (int)pk00);
    int b01 = __builtin_amdgcn_ds_bpermute(addr0, (int)pk01);
    int b10 = __builtin_amdgcn_ds_bpermute(addr0, (int)pk10);
    int b11 = __builtin_amdgcn_ds_bpermute(addr0, (int)pk11);
    int c00 = __builtin_amdgcn_ds_bpermute(addr1, (int)pk00);
    int c01 = __builtin_amdgcn_ds_bpermute(addr1, (int)pk01);
    int c10 = __builtin_amdgcn_ds_bpermute(addr1, (int)pk10);
    int c11 = __builtin_amdgcn_ds_bpermute(addr1, (int)pk11);

    F8 pf;
    pf.w[0] = (unsigned int)(thi ? b01 : b00);
    pf.w[1] = (unsigned int)(thi ? b11 : b10);
    pf.w[2] = (unsigned int)(thi ? c01 : c00);
    pf.w[3] = (unsigned int)(thi ? c11 : c10);
    if (c & 1)
      acc1 = __builtin_amdgcn_mfma_f32_16x16x32_bf16(pf.s, vfC.s, acc1, 0, 0, 0);
    else
      acc0 = __builtin_amdgcn_mfma_f32_16x16x32_bf16(pf.s, vfC.s, acc0, 0, 0, 0);
  }
  f32x4 acc = acc0 + acc1;

  lsum += __shfl_xor(lsum, 16, 64);
  lsum += __shfl_xor(lsum, 32, 64);
  if (lane < 16) sL[wave][lane] = lsum;
#pragma unroll
  for (int r = 0; r < 4; ++r) sAcc[wave][r][lane] = acc[r];
  __syncthreads();
  if (wave == 0) {
    float Linv = 1.f / (sL[0][l15] + sL[1][l15]);
    int b = bh >> 3, h = bh & 7;
    int d = l15 & 7;
    u16* ob = (l15 < 8) ? outx : outy;
    size_t cbase = (size_t)b * N_ * C_ + (size_t)h * 8 + d;
#pragma unroll
    for (int r = 0; r < 4; ++r) {
      int qrow = 4 * (lane >> 4) + r;
      float li = __shfl(Linv, qrow, 64);
      float a = sAcc[0][r][lane] + sAcc[1][r][lane];
      ob[cbase + (size_t)(q0 + qrow) * C_] = f2bf(a * li);
    }
  }
}

// -------- proj via MFMA: K=64, 2 independent chunks; bnd-resid epilogue ---
// grid (N_/16, 4, 4), block 64. z = branch*2 + b.
__global__ __launch_bounds__(64) void k_projm(
    const u16* __restrict__ attx, const u16* __restrict__ atty,
    const float* __restrict__ x, const float* __restrict__ y,
    const float* bg, const float* bb2, const float* bm, const float* bv,
    const u16* __restrict__ pwb, const float* __restrict__ pbias,
    float* __restrict__ xo4, u16* __restrict__ xt0) {
  int l = threadIdx.x;
  int c = l & 15, gg = l >> 4;
  int px0 = blockIdx.x * 16;
  int ct0 = blockIdx.y * 16;
  int z = blockIdx.z;
  int branch = z >> 1, b = z & 1;
  const u16* att = (branch ? atty : attx) + (size_t)b * N_ * 64;
  const u16* aw = pwb + (size_t)(ct0 + c) * 64 + gg * 8;
  const f32x4 z4 = {0.f, 0.f, 0.f, 0.f};
  f32x4 acc0, acc1;
  {
    F8 af, bf;
    af.u4 = *(const uint4*)(aw);
    bf.u4 = *(const uint4*)(att + (size_t)(px0 + c) * 64 + gg * 8);
    acc0 = __builtin_amdgcn_mfma_f32_16x16x32_bf16(af.s, bf.s, z4, 0, 0, 0);
  }
  {
    F8 af, bf;
    af.u4 = *(const uint4*)(aw + 32);
    bf.u4 = *(const uint4*)(att + (size_t)(px0 + c) * 64 + 32 + gg * 8);
    acc1 = __builtin_amdgcn_mfma_f32_16x16x32_bf16(af.s, bf.s, z4, 0, 0, 0);
  }
  f32x4 acc = acc0 + acc1;
  int px = px0 + c;
  const float* xin = branch ? y : x;
#pragma unroll
  for (int r = 0; r < 4; ++r) {
    int cout = ct0 + 4 * gg + r;
    float s  = bg[cout] * rsqrtf(bv[cout] + EPS_);
    float sh = bb2[cout] - bm[cout] * s;
    float rr = xin[((size_t)b * C_ + cout) * N_ + px];
    float vv = acc[r] + pbias[cout] + rr * s + sh;
    xo4[(size_t)z * CN_ + (size_t)cout * N_ + px] = vv;
    xt0[(size_t)z * XTSC_ + (size_t)(W_ + px) * 64 + cout] = f2bf(vv);
  }
}

// ------ cat + bn2 -> cat(fp32), XTf1 bf16, and zero XTF2 guards -----------
__global__ void k_catbn(const float* __restrict__ o2,
                        const float* __restrict__ g, const float* __restrict__ b2,
                        const float* __restrict__ m, const float* __restrict__ v,
                        float* __restrict__ cat, u16* __restrict__ xt1,
                        u16* __restrict__ xtf2) {
  int t = blockIdx.x * 256 + threadIdx.x;
  if (t < 12288) {   // zero XTF2 guard rows (2 imgs x 2 guards x 3072 u32)
    int img = t / 6144, r2 = t - img * 6144;
    int hi = r2 / 3072, o = r2 - hi * 3072;
    ((unsigned int*)(xtf2 + (size_t)img * XTSZ_
                     + (hi ? (size_t)(W_ + N_) * 128 : 0)))[o] = 0u;
  }
  int p4 = t * 4;
  int n  = p4 % N_;
  int c2 = (p4 / N_) % (2 * C_);
  int b  = p4 / (2 * C_ * N_);
  int c  = c2 & 63;
  float4 X = *(const float4*)(o2 + (size_t)b * CN_ + (size_t)c * N_ + n);
  float4 Y = *(const float4*)(o2 + (size_t)(2 + b) * CN_ + (size_t)c * N_ + n);
  float4 val;
  if (c2 < C_) val = make_float4(X.x + Y.x, X.y + Y.y, X.z + Y.z, X.w + Y.w);
  else         val = make_float4(X.x * Y.x, X.y * Y.y, X.z * Y.z, X.w * Y.w);
  size_t co = ((size_t)b * 2 * C_ + c2) * N_ + n;
  *(float4*)(cat + co) = val;
  float s  = g[c2] * rsqrtf(v[c2] + EPS_);
  float sh = b2[c2] - m[c2] * s;
  u16* xb = xt1 + (size_t)b * XTSZ_ + (size_t)(W_ + n) * 128 + c2;
  xb[0]   = f2bf(val.x * s + sh);
  xb[128] = f2bf(val.y * s + sh);
  xb[256] = f2bf(val.z * s + sh);
  xb[384] = f2bf(val.w * s + sh);
}

// ------ zero guard rows: XTC0, XTC1 (64ch, 4 imgs), XTF1 (128ch, 2 imgs) --
__global__ void k_zg1(u16* __restrict__ c0, u16* __restrict__ c1,
                      u16* __restrict__ f1) {
  int idx = blockIdx.x * 256 + threadIdx.x;
  if (idx >= 36864) return;
  int seg = idx / 12288, r = idx - seg * 12288;
  u16* base; int cinc;
  if (seg == 0)      { base = c0; cinc = 64; }
  else if (seg == 1) { base = c1; cinc = 64; }
  else               { base = f1; cinc = 128; }
  int gsz = W_ * cinc / 2;
  int img = r / (2 * gsz), r2 = r - img * (2 * gsz);
  int hi = r2 / gsz, o = r2 - hi * gsz;
  ((unsigned int*)(base + (size_t)img * (N_ + 2 * W_) * cinc
                   + (hi ? (size_t)(W_ + N_) * cinc : 0)))[o] = 0u;
}

// ------ convert conv/proj weights -> bf16 tap-major -----------------------
// wb: [0,147456) f1w; [147456,294912) f2w; [294912,331776) c2w1;
//     [331776,368640) c2w2; [368640,385024) f3w; [385024,389120) proj_w.
__global__ void k_wcvt(const float* __restrict__ w1,
                       const float* __restrict__ w2,
                       const float* __restrict__ cw1,
                       const float* __restrict__ cw2,
                       const float* __restrict__ w3,
                       const float* __restrict__ pjw,
                       u16* __restrict__ wb) {
  int idx = blockIdx.x * 256 + threadIdx.x;
  if (idx >= 389120) return;
  if (idx < 294912) {
    int layer = idx / 147456, rem = idx - layer * 147456;
    int t = rem / 16384, r2 = rem - t * 16384;
    int co = r2 >> 7, ci = r2 & 127;
    wb[idx] = f2bf((layer ? w2 : w1)[(size_t)co * 1152 + ci * 9 + t]);
  } else if (idx < 368640) {
    int k = idx - 294912;
    int layer = k / 36864, rem = k - layer * 36864;
    int t = rem / 4096, r2 = rem - t * 4096;
    int co = r2 >> 6, ci = r2 & 63;
    wb[idx] = f2bf((layer ? cw2 : cw1)[(size_t)co * 576 + ci * 9 + t]);
  } else if (idx < 385024) {
    wb[idx] = f2bf(w3[idx - 368640]);    // [cout][ci] identity
  } else {
    wb[idx] = f2bf(pjw[idx - 385024]);   // [cout][ci] identity
  }
}

// ===== conv as 9 tap-GEMMs on MFMA, dual accumulator chains ===============
// MODE 0: 128ci, bn+relu -> bf16 XT out 128ch (used for f1 AND f2)
// MODE 2: c2 conv1 (64ci, +bias, bn, relu -> bf16 XT out 64ch)
// MODE 3: c2 conv2 (64ci, +bias, bn, relu, +resid -> fp32 [img][cout][px])
template<int MODE>
__global__ __launch_bounds__(64) void k_fmma(
    const u16* __restrict__ xt, const u16* __restrict__ wb,
    const float* __restrict__ cbias,
    const float* g, const float* b2, const float* m, const float* v,
    const float* __restrict__ resid,
    u16* __restrict__ xto, float* __restrict__ fo) {
  constexpr int CIN  = (MODE >= 2) ? 64 : 128;
  constexpr int NCB  = CIN / 32;
  constexpr int COUT = (MODE >= 2) ? 64 : 128;
  constexpr int TS   = CIN * COUT;
  constexpr size_t XTS = (size_t)(N_ + 2 * W_) * CIN;
  constexpr size_t XTSO = (size_t)(N_ + 2 * W_) * COUT;
  int l = threadIdx.x;
  int c = l & 15, gg = l >> 4;
  int px0 = blockIdx.x * 16;
  int ct0 = blockIdx.y * 16;
  int b = blockIdx.z;
  int x0 = px0 % W_;                       // 0, 16, or 32
  bool mL = (x0 == 0) && (c == 0);
  bool mR = (x0 == 32) && (c == 15);
  const u16* xb = xt + (size_t)b * XTS + (size_t)W_ * CIN;
  const u16* aw = wb + (size_t)(ct0 + c) * CIN + gg * 8;

  f32x4 acc0 = {0.f, 0.f, 0.f, 0.f};
  f32x4 acc1 = {0.f, 0.f, 0.f, 0.f};
#pragma unroll
  for (int cb = 0; cb < NCB; ++cb) {
#pragma unroll
    for (int t = 0; t < 9; ++t) {
      const int dx = t % 3 - 1, dy = t / 3 - 1;
      F8 af, bf;
      af.u4 = *(const uint4*)(aw + t * TS + cb * 32);
      int px = px0 + c + dx + dy * W_;
      px = max(px, -W_);                   // clamp into guard (no OOB)
      bf.u4 = *(const uint4*)(xb + (ptrdiff_t)px * CIN + cb * 32 + gg * 8);
      bool msk = (dx < 0 && mL) || (dx > 0 && mR);
      if (msk) bf.u4 = make_uint4(0u, 0u, 0u, 0u);
      if ((t ^ cb) & 1)
        acc1 = __builtin_amdgcn_mfma_f32_16x16x32_bf16(af.s, bf.s, acc1, 0, 0, 0);
      else
        acc0 = __builtin_amdgcn_mfma_f32_16x16x32_bf16(af.s, bf.s, acc0, 0, 0, 0);
    }
  }
  f32x4 acc = acc0 + acc1;
  int px = px0 + c;
  if (MODE == 0 || MODE == 2) {
    union { ushort4 u; u16 s[4]; } pk;
#pragma unroll
    for (int r = 0; r < 4; ++r) {
      int cout = ct0 + 4 * gg + r;
      float a = acc[r] + (MODE == 2 ? cbias[cout] : 0.f);
      float s = g[cout] * rsqrtf(v[cout] + EPS_);
      float sh = b2[cout] - m[cout] * s;
      pk.s[r] = f2bf(fmaxf(a * s + sh, 0.f));
    }
    *(ushort4*)(xto + (size_t)b * XTSO + (size_t)(W_ + px) * COUT
                + ct0 + 4 * gg) = pk.u;
  } else {  // MODE 3
#pragma unroll
    for (int r = 0; r < 4; ++r) {
      int cout = ct0 + 4 * gg + r;
      float a = acc[r] + cbias[cout];
      float s = g[cout] * rsqrtf(v[cout] + EPS_);
      float sh = b2[cout] - m[cout] * s;
      size_t off = (size_t)b * CN_ + (size_t)cout * N_ + px;
      fo[off] = fmaxf(a * s + sh, 0.f) + resid[off];
    }
  }
}

// -------- f3 1x1 conv via MFMA: K=128, dual chains, +f3b + cat -> out -----
// grid (N_/16, 8, B_), block 64.
__global__ __launch_bounds__(64) void k_f3mma(
    const u16* __restrict__ xt3, const u16* __restrict__ w3b,
    const float* __restrict__ f3b, const float* __restrict__ cat,
    float* __restrict__ out) {
  int l = threadIdx.x;
  int c = l & 15, gg = l >> 4;
  int px0 = blockIdx.x * 16;
  int ct0 = blockIdx.y * 16;
  int b = blockIdx.z;
  const u16* xb = xt3 + (size_t)b * XTSZ_ + (size_t)W_ * 128;
  const u16* aw = w3b + (size_t)(ct0 + c) * 128 + gg * 8;
  f32x4 acc0 = {0.f, 0.f, 0.f, 0.f};
  f32x4 acc1 = {0.f, 0.f, 0.f, 0.f};
#pragma unroll
  for (int cb = 0; cb < 4; ++cb) {
    F8 af, bf;
    af.u4 = *(const uint4*)(aw + cb * 32);
    bf.u4 = *(const uint4*)(xb + (size_t)(px0 + c) * 128 + cb * 32 + gg * 8);
    if (cb & 1)
      acc1 = __builtin_amdgcn_mfma_f32_16x16x32_bf16(af.s, bf.s, acc1, 0, 0, 0);
    else
      acc0 = __builtin_amdgcn_mfma_f32_16x16x32_bf16(af.s, bf.s, acc0, 0, 0, 0);
  }
  f32x4 acc = acc0 + acc1;
  int px = px0 + c;
#pragma unroll
  for (int r = 0; r < 4; ++r) {
    int cout = ct0 + 4 * gg + r;
    size_t off = ((size_t)b * 2 * C_ + cout) * N_ + px;
    out[off] = acc[r] + f3b[cout] + cat[off];
  }
}

extern "C" void kernel_launch(void* const* d_in, const int* in_sizes, int n_in,
                              void* d_out, int out_size, void* d_ws, size_t ws_size,
                              hipStream_t stream) {
  const float* x       = (const float*)d_in[0];
  const float* y       = (const float*)d_in[1];
  const float* pconv_w = (const float*)d_in[2];
  const float* pconv_b = (const float*)d_in[3];
  const float* bnd_g = (const float*)d_in[4];
  const float* bnd_b = (const float*)d_in[5];
  const float* bnd_m = (const float*)d_in[6];
  const float* bnd_v = (const float*)d_in[7];
  const float* lnx_g = (const float*)d_in[8];
  const float* lnx_b = (const float*)d_in[9];
  const float* lny_g = (const float*)d_in[10];
  const float* lny_b = (const float*)d_in[11];
  const float* lnz_g = (const float*)d_in[12];
  const float* lnz_b = (const float*)d_in[13];
  const float* k_w   = (const float*)d_in[14];
  const float* k_b   = (const float*)d_in[15];
  const float* qv_w  = (const float*)d_in[16];
  const float* qv_b  = (const float*)d_in[17];
  const float* proj_w = (const float*)d_in[18];
  const float* proj_b = (const float*)d_in[19];
  const float* c2w1  = (const float*)d_in[20];
  const float* c2b1  = (const float*)d_in[21];
  const float* c2bn1_g = (const float*)d_in[22];
  const float* c2bn1_b = (const float*)d_in[23];
  const float* c2bn1_m = (const float*)d_in[24];
  const float* c2bn1_v = (const float*)d_in[25];
  const float* c2w2  = (const float*)d_in[26];
  const float* c2b2  = (const float*)d_in[27];
  const float* c2bn2_g = (const float*)d_in[28];
  const float* c2bn2_b = (const float*)d_in[29];
  const float* c2bn2_m = (const float*)d_in[30];
  const float* c2bn2_v = (const float*)d_in[31];
  const float* bn2_g = (const float*)d_in[32];
  const float* bn2_b = (const float*)d_in[33];
  const float* bn2_m = (const float*)d_in[34];
  const float* bn2_v = (const float*)d_in[35];
  const float* f1w   = (const float*)d_in[36];
  const float* fbn1_g = (const float*)d_in[37];
  const float* fbn1_b = (const float*)d_in[38];
  const float* fbn1_m = (const float*)d_in[39];
  const float* fbn1_v = (const float*)d_in[40];
  const float* f2w   = (const float*)d_in[41];
  const float* fbn2_g = (const float*)d_in[42];
  const float* fbn2_b = (const float*)d_in[43];
  const float* fbn2_m = (const float*)d_in[44];
  const float* fbn2_v = (const float*)d_in[45];
  const float* f3w   = (const float*)d_in[46];
  const float* f3b   = (const float*)d_in[47];

  // Workspace plan (floats; slot = S_):
  //   A: k_pre -> xl(1) yl(2) zl(3)
  //   B: qvk -> qx[4,4.5) qy[4.5,5) kbf[5,5.5) vt[6,7)
  //   C: attn8 -> attx bf16 [1,1.5), atty [1.5,2)
  //   D: projm -> xo4 fp32 [3,5) + XTC0 bf16 [5,6.05)
  //   [zg1: XTC0, XTC1[0,1.05), XTF1[1.25,2.30) guards]
  //   E: fmma<2>: XTC0 -> XTC1 [0,1.05)
  //   F: fmma<3>: XTC1 + xo4 -> o2 [5,7)
  //   G: catbn: o2 -> cat [3,5) + XTF1 [1.25,2.30) + zero XTF2[0,1.05) guards
  //   H1: fmma<0> f1 (fbn1): XTF1 -> XTF2 [0,1.05)
  //   H2: fmma<0> f2 (fbn2): XTF2 -> xt3 [1.25,2.30)
  //   I: f3mma: xt3 + cat -> out
  //   wb @ [7, 7.67)
  float* ws = (float*)d_ws;
  float* sl1 = ws + 1 * S_;
  float* sl2 = ws + 2 * S_;
  float* sl3 = ws + 3 * S_;
  u16* attx = (u16*)(ws + 1 * S_);
  u16* atty = attx + (size_t)B_ * N_ * 64;
  u16* xtC0 = (u16*)(ws + 5 * S_);
  u16* xtC1 = (u16*)ws;
  u16* xtF1 = (u16*)(ws + 5 * S_ / 4);
  u16* xtF2 = (u16*)ws;
  u16* xt3  = (u16*)(ws + 5 * S_ / 4);
  float* xo4 = ws + 3 * S_;
  float* o2  = ws + 5 * S_;
  float* cat = ws + 3 * S_;
  u16* wb   = (u16*)(ws + 7 * S_);
  u16* wbf1 = wb;
  u16* wbf2 = wb + 147456;
  u16* wbc1 = wb + 294912;
  u16* wbc2 = wb + 331776;
  u16* wb3  = wb + 368640;
  u16* wbp  = wb + 385024;

  // A. fused pconv + bn + ln
  k_pre<<<B_ * N_ / 16, 1024, 0, stream>>>(x, y, pconv_w, pconv_b,
                                    bnd_g, bnd_b, bnd_m, bnd_v,
                                    lnx_g, lnx_b, lny_g, lny_b, lnz_g, lnz_b,
                                    sl1, sl2, sl3);
  // weights -> bf16 (independent)
  k_wcvt<<<1520, 256, 0, stream>>>(f1w, f2w, c2w1, c2w2, f3w, proj_w, wb);
  // B. qv/k projection
  u16* qxb = (u16*)(ws + 4 * S_);
  u16* qyb = qxb + (size_t)B_ * NH_ * N_ * 8;
  u16* kbf = (u16*)(ws + 5 * S_);
  u16* vtb = (u16*)(ws + 6 * S_);
  {
    dim3 g(B_ * N_ / 64, 20);
    k_qvk<<<g, 64, 0, stream>>>(sl1, sl2, sl3, qv_w, qv_b, k_w, k_b,
                                qxb, qyb, kbf, vtb);
  }
  // C. attention (bf16 att out)
  {
    dim3 g(N_ / 16, B_ * NH_);
    k_attn8<<<g, 128, 0, stream>>>(qxb, qyb, kbf, vtb, attx, atty);
  }
  // D. proj via MFMA -> xo4 + XTC0
  {
    dim3 g(N_ / 16, 4, 4);
    k_projm<<<g, 64, 0, stream>>>(attx, atty, x, y,
                                  bnd_g, bnd_b, bnd_m, bnd_v,
                                  wbp, proj_b, xo4, xtC0);
  }
  // guards: XTC0, XTC1, XTF1
  k_zg1<<<144, 256, 0, stream>>>(xtC0, xtC1, xtF1);
  // E. conv1 via MFMA -> XTC1
  {
    dim3 g(N_ / 16, 4, 4);
    k_fmma<2><<<g, 64, 0, stream>>>(xtC0, wbc1, c2b1,
        c2bn1_g, c2bn1_b, c2bn1_m, c2bn1_v, nullptr, xtC1, nullptr);
  }
  // F. conv2 via MFMA (+resid) -> o2
  {
    dim3 g(N_ / 16, 4, 4);
    k_fmma<3><<<g, 64, 0, stream>>>(xtC1, wbc2, c2b2,
        c2bn2_g, c2bn2_b, c2bn2_m, c2bn2_v, xo4, nullptr, o2);
  }
  // G. cat + bn2 -> cat + XTF1 (+ zero XTF2 guards)
  k_catbn<<<576, 256, 0, stream>>>(o2, bn2_g, bn2_b, bn2_m, bn2_v,
                                   cat, xtF1, xtF2);
  // H. f-branch via MFMA tap-GEMMs
  {
    dim3 g(N_ / 16, 8, B_);
    k_fmma<0><<<g, 64, 0, stream>>>(xtF1, wbf1, nullptr,
        fbn1_g, fbn1_b, fbn1_m, fbn1_v, nullptr, xtF2, nullptr);
    k_fmma<0><<<g, 64, 0, stream>>>(xtF2, wbf2, nullptr,
        fbn2_g, fbn2_b, fbn2_m, fbn2_v, nullptr, xt3, nullptr);
  }
  // I. f3 1x1 + cat -> out
  {
    dim3 g(N_ / 16, 8, B_);
    k_f3mma<<<g, 64, 0, stream>>>(xt3, wb3, f3b, cat, (float*)d_out);
  }
}

// Round 17
// 297.116 us; speedup vs baseline: 1.9022x; 1.0203x over previous
//
#include <hip/hip_runtime.h>
#include <hip/hip_bf16.h>

#define B_   2
#define C_   64
#define H_   48
#define W_   48
#define N_   (H_*W_)     // 2304
#define NH_  8
#define HD_  8
#define EPS_ 1e-5f
#define S2_  0.125f      // scale^2 = 1/hd
#define LOG2E_ 1.44269504f
#define FS_  (S2_ * LOG2E_)
#define S_   ((size_t)B_ * C_ * N_)   // 294912 floats per workspace slot
#define CN_  ((size_t)C_ * N_)        // 147456 floats per image
#define XTSZ_ ((size_t)(N_ + 2 * W_) * 128)  // bf16 elems per 128-ch image
#define XTSC_ ((size_t)(N_ + 2 * W_) * 64)   // bf16 elems per 64-ch image
#define PREB_ (B_ * N_ / 16)                 // 288 pre blocks

typedef unsigned short u16;
typedef __attribute__((ext_vector_type(8))) short short8v;
typedef __attribute__((ext_vector_type(4))) float f32x4;
union F8 { uint4 u4; short8v s; unsigned int w[4]; };

__device__ __forceinline__ float wsum64(float v) {
#pragma unroll
  for (int o = 32; o > 0; o >>= 1) v += __shfl_xor(v, o, 64);
  return v;
}

__device__ __forceinline__ float ln_val(float t, float g, float b) {
  float mu  = wsum64(t) * (1.0f / 64.0f);
  float d   = t - mu;
  float var = wsum64(d * d) * (1.0f / 64.0f);
  return d * rsqrtf(var + EPS_) * g + b;
}

// round-to-nearest-even f32 -> bf16 (finite inputs only)
__device__ __forceinline__ u16 f2bf(float x) {
  union { float f; unsigned int u; } a; a.f = x;
  unsigned int r = a.u + 0x7fffu + ((a.u >> 16) & 1u);
  return (u16)(r >> 16);
}

// ---- fused 1x1 pconv + BN + 3x LN (blocks < PREB_) + weight cvt (rest) ---
// grid 288+380, block 1024.
__global__ __launch_bounds__(1024) void k_pre(
    const float* __restrict__ x, const float* __restrict__ y,
    const float* __restrict__ pw, const float* __restrict__ pb,
    const float* g, const float* bb, const float* m, const float* v,
    const float* lnxg, const float* lnxb,
    const float* lnyg, const float* lnyb,
    const float* lnzg, const float* lnzb,
    float* __restrict__ xl, float* __restrict__ yl, float* __restrict__ zl,
    const float* __restrict__ w1, const float* __restrict__ w2,
    const float* __restrict__ cw1, const float* __restrict__ cw2,
    const float* __restrict__ w3, const float* __restrict__ pjw,
    u16* __restrict__ wbo) {
  __shared__ float4 pwT[32][64];           // pwT[i4][c] = pw[c][4*i4..+3]
  __shared__ float xs[16][64], ys[16][64];
  if (blockIdx.x >= PREB_) {
    // ---- weight conversion path (no LDS, no syncthreads) ----
    int idx = (blockIdx.x - PREB_) * 1024 + threadIdx.x;
    if (idx >= 389120) return;
    if (idx < 294912) {
      int layer = idx / 147456, rem = idx - layer * 147456;
      int t = rem / 16384, r2 = rem - t * 16384;
      int co = r2 >> 7, ci = r2 & 127;
      wbo[idx] = f2bf((layer ? w2 : w1)[(size_t)co * 1152 + ci * 9 + t]);
    } else if (idx < 368640) {
      int k = idx - 294912;
      int layer = k / 36864, rem = k - layer * 36864;
      int t = rem / 4096, r2 = rem - t * 4096;
      int co = r2 >> 6, ci = r2 & 63;
      wbo[idx] = f2bf((layer ? cw2 : cw1)[(size_t)co * 576 + ci * 9 + t]);
    } else if (idx < 385024) {
      wbo[idx] = f2bf(w3[idx - 368640]);    // [cout][ci] identity
    } else {
      wbo[idx] = f2bf(pjw[idx - 385024]);   // [cout][ci] identity
    }
    return;
  }
  int w = threadIdx.x >> 6, c = threadIdx.x & 63;
  for (int idx = threadIdx.x; idx < 2048; idx += 1024) {
    int cc = idx & 63, i4 = idx >> 6;
    pwT[i4][cc] = *(const float4*)(pw + (size_t)cc * 2 * C_ + i4 * 4);
  }
  int row = blockIdx.x * 16 + w;           // b*N + n
  int b = row / N_, n = row % N_;
  float xv = x[(size_t)(b * C_ + c) * N_ + n];
  float yv = y[(size_t)(b * C_ + c) * N_ + n];
  xs[w][c] = xv; ys[w][c] = yv;
  __syncthreads();
  const float4* xw = (const float4*)xs[w];
  const float4* yw = (const float4*)ys[w];
  float acc = pb[c];
#pragma unroll
  for (int t = 0; t < 16; ++t) {
    float4 a = xw[t], wv = pwT[t][c];
    acc += a.x * wv.x + a.y * wv.y + a.z * wv.z + a.w * wv.w;
  }
#pragma unroll
  for (int t = 0; t < 16; ++t) {
    float4 a = yw[t], wv = pwT[16 + t][c];
    acc += a.x * wv.x + a.y * wv.y + a.z * wv.z + a.w * wv.w;
  }
  float s  = g[c] * rsqrtf(v[c] + EPS_);
  float sh = bb[c] - m[c] * s;
  float tx = xv * s + sh;
  xl[(size_t)row * C_ + c] = ln_val(tx, lnxg[c], lnxb[c]);
  float ty = yv * s + sh;
  yl[(size_t)row * C_ + c] = ln_val(ty, lnyg[c], lnyb[c]);
  float tz = acc * s + sh;
  zl[(size_t)row * C_ + c] = ln_val(tz, lnzg[c], lnzb[c]);
}

// ------------- qv/k projection v2: lane = row, uniform weights ------------
__global__ __launch_bounds__(64) void k_qvk(
    const float* __restrict__ xl, const float* __restrict__ yl,
    const float* __restrict__ zl,
    const float* __restrict__ qvw, const float* __restrict__ qvb,
    const float* __restrict__ kw, const float* __restrict__ kb,
    u16* __restrict__ qxb, u16* __restrict__ qyb,
    u16* __restrict__ kbf, u16* __restrict__ vt) {
  int l = threadIdx.x;
  int part = blockIdx.y >> 2;
  int j0 = (blockIdx.y & 3) * 16;
  int row = blockIdx.x * 64 + l;
  int b = row / N_, n = row % N_;
  const float* inp = (part < 2) ? xl : (part < 4) ? yl : zl;
  float4 in[16];
  const float4* ir = (const float4*)(inp + (size_t)row * C_);
#pragma unroll
  for (int t = 0; t < 16; ++t) in[t] = ir[t];

  const float* wb   = (part == 4) ? kw : qvw;
  const float* bias = (part == 4) ? kb : qvb;
  int joff = (part == 1 || part == 3) ? 64 : 0;

  if (part == 1 || part == 3) {
    int vbase = (part == 1) ? 0 : 8;
#pragma unroll
    for (int jj = 0; jj < 16; ++jj) {
      int j = j0 + jj;
      const float4* wr = (const float4*)(wb + (size_t)(joff + j) * C_);
      float acc = bias[joff + j];
#pragma unroll
      for (int t = 0; t < 16; ++t) {
        float4 a = in[t], wv = wr[t];
        acc += a.x * wv.x + a.y * wv.y + a.z * wv.z + a.w * wv.w;
      }
      int h = j >> 3, d = j & 7;
      vt[((size_t)((b * NH_ + h) * 16 + vbase + d)) * N_ + n] = f2bf(acc);
    }
  } else {
    u16* dst = (part == 0) ? qxb : (part == 2) ? qyb : kbf;
#pragma unroll
    for (int gg = 0; gg < 2; ++gg) {
      int h = (j0 >> 3) + gg;
      union { uint4 u4; u16 s[8]; } pk;
#pragma unroll
      for (int d = 0; d < 8; ++d) {
        int j = h * 8 + d;
        const float4* wr = (const float4*)(wb + (size_t)(joff + j) * C_);
        float acc = bias[joff + j];
#pragma unroll
        for (int t = 0; t < 16; ++t) {
          float4 a = in[t], wv = wr[t];
          acc += a.x * wv.x + a.y * wv.y + a.z * wv.z + a.w * wv.w;
        }
        if (part == 0) acc *= FS_;
        pk.s[d] = f2bf(acc);
      }
      *(uint4*)(dst + ((size_t)(b * NH_ + h) * N_ + n) * 8) = pk.u4;
    }
  }
}

// ---- attention v8c: MFMA flash, dual PV acc chains, bf16 att out ---------
__global__ __launch_bounds__(128, 5) void k_attn8(
    const u16* __restrict__ qx, const u16* __restrict__ qy,
    const u16* __restrict__ kk, const u16* __restrict__ vt,
    u16* __restrict__ outx, u16* __restrict__ outy) {
  __shared__ float sAcc[2][4][64];
  __shared__ float sL[2][16];
  int qt = blockIdx.x, bh = blockIdx.y;
  int tid = threadIdx.x;
  int lane = tid & 63;
  int wave = tid >> 6;
  int l15 = lane & 15;
  int q0 = qt * 16;

  F8 qxf, qyf;
  size_t qoff = ((size_t)bh * N_ + q0 + l15) * 8;
  qxf.u4 = *(const uint4*)(qx + qoff);
  qyf.u4 = *(const uint4*)(qy + qoff);
  if (lane >= 16) {
    qxf.u4 = make_uint4(0u, 0u, 0u, 0u);
    qyf.u4 = make_uint4(0u, 0u, 0u, 0u);
  }

  int key0 = wave * (N_ / 2);
  const uint4* kp = (const uint4*)(kk + (size_t)bh * N_ * 8) + key0 + l15;
  const uint4* vp = (const uint4*)(vt + ((size_t)bh * 16 + l15) * N_ + key0)
                    + (lane >> 4);
  int addr0 = (((lane >> 4) & 1) * 32 + l15) * 4;
  int addr1 = addr0 + 64;
  int thi = lane >> 5;

  f32x4 acc0 = {0.f, 0.f, 0.f, 0.f};
  f32x4 acc1 = {0.f, 0.f, 0.f, 0.f};
  const f32x4 z4 = {0.f, 0.f, 0.f, 0.f};
  float lsum = 0.f;

  F8 ka, kb2, vf;
  ka.u4 = kp[0]; kb2.u4 = kp[16]; vf.u4 = *vp;
  for (int c = 0; c < 36; ++c) {
    F8 kaC = ka, kbC = kb2, vfC = vf;
    kp += 32; vp += 4;
    ka.u4 = kp[0]; kb2.u4 = kp[16]; vf.u4 = *vp;   // prefetch next chunk

    f32x4 s1a = __builtin_amdgcn_mfma_f32_16x16x32_bf16(kaC.s, qxf.s, z4, 0, 0, 0);
    f32x4 s2a = __builtin_amdgcn_mfma_f32_16x16x32_bf16(kaC.s, qyf.s, z4, 0, 0, 0);
    f32x4 s1b = __builtin_amdgcn_mfma_f32_16x16x32_bf16(kbC.s, qxf.s, z4, 0, 0, 0);
    f32x4 s2b = __builtin_amdgcn_mfma_f32_16x16x32_bf16(kbC.s, qyf.s, z4, 0, 0, 0);

    float p00 = exp2f(s1a[0] * s2a[0]), p01 = exp2f(s1a[1] * s2a[1]);
    float p02 = exp2f(s1a[2] * s2a[2]), p03 = exp2f(s1a[3] * s2a[3]);
    float p10 = exp2f(s1b[0] * s2b[0]), p11 = exp2f(s1b[1] * s2b[1]);
    float p12 = exp2f(s1b[2] * s2b[2]), p13 = exp2f(s1b[3] * s2b[3]);
    lsum += ((p00 + p01) + (p02 + p03)) + ((p10 + p11) + (p12 + p13));

    unsigned int pk00, pk10, pk01, pk11;
    asm("v_cvt_pk_bf16_f32 %0, %1, %2" : "=v"(pk00) : "v"(p00), "v"(p01));
    asm("v_cvt_pk_bf16_f32 %0, %1, %2" : "=v"(pk10) : "v"(p02), "v"(p03));
    asm("v_cvt_pk_bf16_f32 %0, %1, %2" : "=v"(pk01) : "v"(p10), "v"(p11));
    asm("v_cvt_pk_bf16_f32 %0, %1, %2" : "=v"(pk11) : "v"(p12), "v"(p13));

    int b00 = __builtin_amdgcn_ds_bpermute(addr0, (int)pk00);
    int b01 = __builtin_amdgcn_ds_bpermute(addr0, (int)pk01);
    int b10 = __builtin_amdgcn_ds_bpermute(addr0, (int)pk10);
    int b11 = __builtin_amdgcn_ds_bpermute(addr0, (int)pk11);
    int c00 = __builtin_amdgcn_ds_bpermute(addr1, (int)pk00);
    int c01 = __builtin_amdgcn_ds_bpermute(addr1, (int)pk01);
    int c10 = __builtin_amdgcn_ds_bpermute(addr1, (int)pk10);
    int c11 = __builtin_amdgcn_ds_bpermute(addr1, (int)pk11);

    F8 pf;
    pf.w[0] = (unsigned int)(thi ? b01 : b00);
    pf.w[1] = (unsigned int)(thi ? b11 : b10);
    pf.w[2] = (unsigned int)(thi ? c01 : c00);
    pf.w[3] = (unsigned int)(thi ? c11 : c10);
    if (c & 1)
      acc1 = __builtin_amdgcn_mfma_f32_16x16x32_bf16(pf.s, vfC.s, acc1, 0, 0, 0);
    else
      acc0 = __builtin_amdgcn_mfma_f32_16x16x32_bf16(pf.s, vfC.s, acc0, 0, 0, 0);
  }
  f32x4 acc = acc0 + acc1;

  lsum += __shfl_xor(lsum, 16, 64);
  lsum += __shfl_xor(lsum, 32, 64);
  if (lane < 16) sL[wave][lane] = lsum;
#pragma unroll
  for (int r = 0; r < 4; ++r) sAcc[wave][r][lane] = acc[r];
  __syncthreads();
  if (wave == 0) {
    float Linv = 1.f / (sL[0][l15] + sL[1][l15]);
    int b = bh >> 3, h = bh & 7;
    int d = l15 & 7;
    u16* ob = (l15 < 8) ? outx : outy;
    size_t cbase = (size_t)b * N_ * C_ + (size_t)h * 8 + d;
#pragma unroll
    for (int r = 0; r < 4; ++r) {
      int qrow = 4 * (lane >> 4) + r;
      float li = __shfl(Linv, qrow, 64);
      float a = sAcc[0][r][lane] + sAcc[1][r][lane];
      ob[cbase + (size_t)(q0 + qrow) * C_] = f2bf(a * li);
    }
  }
}

// -------- proj via MFMA: K=64; bnd-resid epilogue; zeroes XTC0 guards -----
// grid (N_/16, 4, 4), block 64. z = branch*2 + b.
__global__ __launch_bounds__(64) void k_projm(
    const u16* __restrict__ attx, const u16* __restrict__ atty,
    const float* __restrict__ x, const float* __restrict__ y,
    const float* bg, const float* bb2, const float* bm, const float* bv,
    const u16* __restrict__ pwb, const float* __restrict__ pbias,
    float* __restrict__ xo4, u16* __restrict__ xt0) {
  if (blockIdx.x == 0) {   // 16 blocks x 64 thr zero XTC0 guard rows
    int tg = (blockIdx.z * 4 + blockIdx.y) * 64 + threadIdx.x;
#pragma unroll
    for (int i = tg; i < 12288; i += 1024) {
      int img = i / 3072, r2 = i - img * 3072;
      int hi = r2 / 1536, o = r2 - hi * 1536;
      ((unsigned int*)(xt0 + (size_t)img * XTSC_
                       + (hi ? (size_t)(W_ + N_) * 64 : 0)))[o] = 0u;
    }
  }
  int l = threadIdx.x;
  int c = l & 15, gg = l >> 4;
  int px0 = blockIdx.x * 16;
  int ct0 = blockIdx.y * 16;
  int z = blockIdx.z;
  int branch = z >> 1, b = z & 1;
  const u16* att = (branch ? atty : attx) + (size_t)b * N_ * 64;
  const u16* aw = pwb + (size_t)(ct0 + c) * 64 + gg * 8;
  const f32x4 z4 = {0.f, 0.f, 0.f, 0.f};
  f32x4 acc0, acc1;
  {
    F8 af, bf;
    af.u4 = *(const uint4*)(aw);
    bf.u4 = *(const uint4*)(att + (size_t)(px0 + c) * 64 + gg * 8);
    acc0 = __builtin_amdgcn_mfma_f32_16x16x32_bf16(af.s, bf.s, z4, 0, 0, 0);
  }
  {
    F8 af, bf;
    af.u4 = *(const uint4*)(aw + 32);
    bf.u4 = *(const uint4*)(att + (size_t)(px0 + c) * 64 + 32 + gg * 8);
    acc1 = __builtin_amdgcn_mfma_f32_16x16x32_bf16(af.s, bf.s, z4, 0, 0, 0);
  }
  f32x4 acc = acc0 + acc1;
  int px = px0 + c;
  const float* xin = branch ? y : x;
#pragma unroll
  for (int r = 0; r < 4; ++r) {
    int cout = ct0 + 4 * gg + r;
    float s  = bg[cout] * rsqrtf(bv[cout] + EPS_);
    float sh = bb2[cout] - bm[cout] * s;
    float rr = xin[((size_t)b * C_ + cout) * N_ + px];
    float vv = acc[r] + pbias[cout] + rr * s + sh;
    xo4[(size_t)z * CN_ + (size_t)cout * N_ + px] = vv;
    xt0[(size_t)z * XTSC_ + (size_t)(W_ + px) * 64 + cout] = f2bf(vv);
  }
}

// ------ cat + bn2 -> cat(fp32), XTf1 bf16; zero XTF1+XTF2 guards ----------
__global__ void k_catbn(const float* __restrict__ o2,
                        const float* __restrict__ g, const float* __restrict__ b2,
                        const float* __restrict__ m, const float* __restrict__ v,
                        float* __restrict__ cat, u16* __restrict__ xt1,
                        u16* __restrict__ xtf2) {
  int t = blockIdx.x * 256 + threadIdx.x;
  if (t < 12288) {   // zero XTF2 guard rows (2 imgs x 2 guards x 3072 u32)
    int img = t / 6144, r2 = t - img * 6144;
    int hi = r2 / 3072, o = r2 - hi * 3072;
    ((unsigned int*)(xtf2 + (size_t)img * XTSZ_
                     + (hi ? (size_t)(W_ + N_) * 128 : 0)))[o] = 0u;
  } else if (t < 24576) {   // zero XTF1 guard rows (same geometry)
    int i = t - 12288;
    int img = i / 6144, r2 = i - img * 6144;
    int hi = r2 / 3072, o = r2 - hi * 3072;
    ((unsigned int*)(xt1 + (size_t)img * XTSZ_
                     + (hi ? (size_t)(W_ + N_) * 128 : 0)))[o] = 0u;
  }
  int p4 = t * 4;
  int n  = p4 % N_;
  int c2 = (p4 / N_) % (2 * C_);
  int b  = p4 / (2 * C_ * N_);
  int c  = c2 & 63;
  float4 X = *(const float4*)(o2 + (size_t)b * CN_ + (size_t)c * N_ + n);
  float4 Y = *(const float4*)(o2 + (size_t)(2 + b) * CN_ + (size_t)c * N_ + n);
  float4 val;
  if (c2 < C_) val = make_float4(X.x + Y.x, X.y + Y.y, X.z + Y.z, X.w + Y.w);
  else         val = make_float4(X.x * Y.x, X.y * Y.y, X.z * Y.z, X.w * Y.w);
  size_t co = ((size_t)b * 2 * C_ + c2) * N_ + n;
  *(float4*)(cat + co) = val;
  float s  = g[c2] * rsqrtf(v[c2] + EPS_);
  float sh = b2[c2] - m[c2] * s;
  u16* xb = xt1 + (size_t)b * XTSZ_ + (size_t)(W_ + n) * 128 + c2;
  xb[0]   = f2bf(val.x * s + sh);
  xb[128] = f2bf(val.y * s + sh);
  xb[256] = f2bf(val.z * s + sh);
  xb[384] = f2bf(val.w * s + sh);
}

// ===== conv as 9 tap-GEMMs on MFMA, dual accumulator chains ===============
// MODE 0: 128ci, bn+relu -> bf16 XT out 128ch (used for f1 AND f2)
// MODE 2: c2 conv1 (64ci, +bias, bn, relu -> bf16 XT out 64ch; zeroes
//         guards of its own output for the next fmma<3> pass)
// MODE 3: c2 conv2 (64ci, +bias, bn, relu, +resid -> fp32 [img][cout][px])
template<int MODE>
__global__ __launch_bounds__(64) void k_fmma(
    const u16* __restrict__ xt, const u16* __restrict__ wb,
    const float* __restrict__ cbias,
    const float* g, const float* b2, const float* m, const float* v,
    const float* __restrict__ resid,
    u16* __restrict__ xto, float* __restrict__ fo) {
  constexpr int CIN  = (MODE >= 2) ? 64 : 128;
  constexpr int NCB  = CIN / 32;
  constexpr int COUT = (MODE >= 2) ? 64 : 128;
  constexpr int TS   = CIN * COUT;
  constexpr size_t XTS = (size_t)(N_ + 2 * W_) * CIN;
  constexpr size_t XTSO = (size_t)(N_ + 2 * W_) * COUT;
  if (MODE == 2 && blockIdx.x == 0) {  // zero XTC1 guards for fmma<3>
    int tg = (blockIdx.z * 4 + blockIdx.y) * 64 + threadIdx.x;
#pragma unroll
    for (int i = tg; i < 12288; i += 1024) {
      int img = i / 3072, r2 = i - img * 3072;
      int hi = r2 / 1536, o = r2 - hi * 1536;
      ((unsigned int*)(xto + (size_t)img * XTSO
                       + (hi ? (size_t)(W_ + N_) * COUT : 0)))[o] = 0u;
    }
  }
  int l = threadIdx.x;
  int c = l & 15, gg = l >> 4;
  int px0 = blockIdx.x * 16;
  int ct0 = blockIdx.y * 16;
  int b = blockIdx.z;
  int x0 = px0 % W_;                       // 0, 16, or 32
  bool mL = (x0 == 0) && (c == 0);
  bool mR = (x0 == 32) && (c == 15);
  const u16* xb = xt + (size_t)b * XTS + (size_t)W_ * CIN;
  const u16* aw = wb + (size_t)(ct0 + c) * CIN + gg * 8;

  f32x4 acc0 = {0.f, 0.f, 0.f, 0.f};
  f32x4 acc1 = {0.f, 0.f, 0.f, 0.f};
#pragma unroll
  for (int cb = 0; cb < NCB; ++cb) {
#pragma unroll
    for (int t = 0; t < 9; ++t) {
      const int dx = t % 3 - 1, dy = t / 3 - 1;
      F8 af, bf;
      af.u4 = *(const uint4*)(aw + t * TS + cb * 32);
      int px = px0 + c + dx + dy * W_;
      px = max(px, -W_);                   // clamp into guard (no OOB)
      bf.u4 = *(const uint4*)(xb + (ptrdiff_t)px * CIN + cb * 32 + gg * 8);
      bool msk = (dx < 0 && mL) || (dx > 0 && mR);
      if (msk) bf.u4 = make_uint4(0u, 0u, 0u, 0u);
      if ((t ^ cb) & 1)
        acc1 = __builtin_amdgcn_mfma_f32_16x16x32_bf16(af.s, bf.s, acc1, 0, 0, 0);
      else
        acc0 = __builtin_amdgcn_mfma_f32_16x16x32_bf16(af.s, bf.s, acc0, 0, 0, 0);
    }
  }
  f32x4 acc = acc0 + acc1;
  int px = px0 + c;
  if (MODE == 0 || MODE == 2) {
    union { ushort4 u; u16 s[4]; } pk;
#pragma unroll
    for (int r = 0; r < 4; ++r) {
      int cout = ct0 + 4 * gg + r;
      float a = acc[r] + (MODE == 2 ? cbias[cout] : 0.f);
      float s = g[cout] * rsqrtf(v[cout] + EPS_);
      float sh = b2[cout] - m[cout] * s;
      pk.s[r] = f2bf(fmaxf(a * s + sh, 0.f));
    }
    *(ushort4*)(xto + (size_t)b * XTSO + (size_t)(W_ + px) * COUT
                + ct0 + 4 * gg) = pk.u;
  } else {  // MODE 3
#pragma unroll
    for (int r = 0; r < 4; ++r) {
      int cout = ct0 + 4 * gg + r;
      float a = acc[r] + cbias[cout];
      float s = g[cout] * rsqrtf(v[cout] + EPS_);
      float sh = b2[cout] - m[cout] * s;
      size_t off = (size_t)b * CN_ + (size_t)cout * N_ + px;
      fo[off] = fmaxf(a * s + sh, 0.f) + resid[off];
    }
  }
}

// -------- f3 1x1 conv via MFMA: K=128, dual chains, +f3b + cat -> out -----
// grid (N_/16, 8, B_), block 64.
__global__ __launch_bounds__(64) void k_f3mma(
    const u16* __restrict__ xt3, const u16* __restrict__ w3b,
    const float* __restrict__ f3b, const float* __restrict__ cat,
    float* __restrict__ out) {
  int l = threadIdx.x;
  int c = l & 15, gg = l >> 4;
  int px0 = blockIdx.x * 16;
  int ct0 = blockIdx.y * 16;
  int b = blockIdx.z;
  const u16* xb = xt3 + (size_t)b * XTSZ_ + (size_t)W_ * 128;
  const u16* aw = w3b + (size_t)(ct0 + c) * 128 + gg * 8;
  f32x4 acc0 = {0.f, 0.f, 0.f, 0.f};
  f32x4 acc1 = {0.f, 0.f, 0.f, 0.f};
#pragma unroll
  for (int cb = 0; cb < 4; ++cb) {
    F8 af, bf;
    af.u4 = *(const uint4*)(aw + cb * 32);
    bf.u4 = *(const uint4*)(xb + (size_t)(px0 + c) * 128 + cb * 32 + gg * 8);
    if (cb & 1)
      acc1 = __builtin_amdgcn_mfma_f32_16x16x32_bf16(af.s, bf.s, acc1, 0, 0, 0);
    else
      acc0 = __builtin_amdgcn_mfma_f32_16x16x32_bf16(af.s, bf.s, acc0, 0, 0, 0);
  }
  f32x4 acc = acc0 + acc1;
  int px = px0 + c;
#pragma unroll
  for (int r = 0; r < 4; ++r) {
    int cout = ct0 + 4 * gg + r;
    size_t off = ((size_t)b * 2 * C_ + cout) * N_ + px;
    out[off] = acc[r] + f3b[cout] + cat[off];
  }
}

extern "C" void kernel_launch(void* const* d_in, const int* in_sizes, int n_in,
                              void* d_out, int out_size, void* d_ws, size_t ws_size,
                              hipStream_t stream) {
  const float* x       = (const float*)d_in[0];
  const float* y       = (const float*)d_in[1];
  const float* pconv_w = (const float*)d_in[2];
  const float* pconv_b = (const float*)d_in[3];
  const float* bnd_g = (const float*)d_in[4];
  const float* bnd_b = (const float*)d_in[5];
  const float* bnd_m = (const float*)d_in[6];
  const float* bnd_v = (const float*)d_in[7];
  const float* lnx_g = (const float*)d_in[8];
  const float* lnx_b = (const float*)d_in[9];
  const float* lny_g = (const float*)d_in[10];
  const float* lny_b = (const float*)d_in[11];
  const float* lnz_g = (const float*)d_in[12];
  const float* lnz_b = (const float*)d_in[13];
  const float* k_w   = (const float*)d_in[14];
  const float* k_b   = (const float*)d_in[15];
  const float* qv_w  = (const float*)d_in[16];
  const float* qv_b  = (const float*)d_in[17];
  const float* proj_w = (const float*)d_in[18];
  const float* proj_b = (const float*)d_in[19];
  const float* c2w1  = (const float*)d_in[20];
  const float* c2b1  = (const float*)d_in[21];
  const float* c2bn1_g = (const float*)d_in[22];
  const float* c2bn1_b = (const float*)d_in[23];
  const float* c2bn1_m = (const float*)d_in[24];
  const float* c2bn1_v = (const float*)d_in[25];
  const float* c2w2  = (const float*)d_in[26];
  const float* c2b2  = (const float*)d_in[27];
  const float* c2bn2_g = (const float*)d_in[28];
  const float* c2bn2_b = (const float*)d_in[29];
  const float* c2bn2_m = (const float*)d_in[30];
  const float* c2bn2_v = (const float*)d_in[31];
  const float* bn2_g = (const float*)d_in[32];
  const float* bn2_b = (const float*)d_in[33];
  const float* bn2_m = (const float*)d_in[34];
  const float* bn2_v = (const float*)d_in[35];
  const float* f1w   = (const float*)d_in[36];
  const float* fbn1_g = (const float*)d_in[37];
  const float* fbn1_b = (const float*)d_in[38];
  const float* fbn1_m = (const float*)d_in[39];
  const float* fbn1_v = (const float*)d_in[40];
  const float* f2w   = (const float*)d_in[41];
  const float* fbn2_g = (const float*)d_in[42];
  const float* fbn2_b = (const float*)d_in[43];
  const float* fbn2_m = (const float*)d_in[44];
  const float* fbn2_v = (const float*)d_in[45];
  const float* f3w   = (const float*)d_in[46];
  const float* f3b   = (const float*)d_in[47];

  // Workspace plan (floats; slot = S_):
  //   A: k_pre (+wcvt tail blocks) -> xl(1) yl(2) zl(3); wb @ [7, 7.67)
  //   B: qvk -> qx[4,4.5) qy[4.5,5) kbf[5,5.5) vt[6,7)
  //   C: attn8 -> attx bf16 [1,1.5), atty [1.5,2)
  //   D: projm -> xo4 fp32 [3,5) + XTC0 bf16 [5,6.05) (+XTC0 guards)
  //   E: fmma<2>: XTC0 -> XTC1 [0,1.05) (+XTC1 guards)
  //   F: fmma<3>: XTC1 + xo4 -> o2 [5,7)
  //   G: catbn: o2 -> cat [3,5) + XTF1 [1.25,2.30) (+XTF1/XTF2 guards)
  //   H1: fmma<0> f1 (fbn1): XTF1 -> XTF2 [0,1.05)
  //   H2: fmma<0> f2 (fbn2): XTF2 -> xt3 [1.25,2.30)
  //   I: f3mma: xt3 + cat -> out
  float* ws = (float*)d_ws;
  float* sl1 = ws + 1 * S_;
  float* sl2 = ws + 2 * S_;
  float* sl3 = ws + 3 * S_;
  u16* attx = (u16*)(ws + 1 * S_);
  u16* atty = attx + (size_t)B_ * N_ * 64;
  u16* xtC0 = (u16*)(ws + 5 * S_);
  u16* xtC1 = (u16*)ws;
  u16* xtF1 = (u16*)(ws + 5 * S_ / 4);
  u16* xtF2 = (u16*)ws;
  u16* xt3  = (u16*)(ws + 5 * S_ / 4);
  float* xo4 = ws + 3 * S_;
  float* o2  = ws + 5 * S_;
  float* cat = ws + 3 * S_;
  u16* wb   = (u16*)(ws + 7 * S_);
  u16* wbf1 = wb;
  u16* wbf2 = wb + 147456;
  u16* wbc1 = wb + 294912;
  u16* wbc2 = wb + 331776;
  u16* wb3  = wb + 368640;
  u16* wbp  = wb + 385024;

  // A. fused pconv + bn + ln (+ weight conversion tail blocks)
  k_pre<<<PREB_ + 380, 1024, 0, stream>>>(x, y, pconv_w, pconv_b,
                                    bnd_g, bnd_b, bnd_m, bnd_v,
                                    lnx_g, lnx_b, lny_g, lny_b, lnz_g, lnz_b,
                                    sl1, sl2, sl3,
                                    f1w, f2w, c2w1, c2w2, f3w, proj_w, wb);
  // B. qv/k projection
  u16* qxb = (u16*)(ws + 4 * S_);
  u16* qyb = qxb + (size_t)B_ * NH_ * N_ * 8;
  u16* kbf = (u16*)(ws + 5 * S_);
  u16* vtb = (u16*)(ws + 6 * S_);
  {
    dim3 g(B_ * N_ / 64, 20);
    k_qvk<<<g, 64, 0, stream>>>(sl1, sl2, sl3, qv_w, qv_b, k_w, k_b,
                                qxb, qyb, kbf, vtb);
  }
  // C. attention (bf16 att out)
  {
    dim3 g(N_ / 16, B_ * NH_);
    k_attn8<<<g, 128, 0, stream>>>(qxb, qyb, kbf, vtb, attx, atty);
  }
  // D. proj via MFMA -> xo4 + XTC0 (+guards)
  {
    dim3 g(N_ / 16, 4, 4);
    k_projm<<<g, 64, 0, stream>>>(attx, atty, x, y,
                                  bnd_g, bnd_b, bnd_m, bnd_v,
                                  wbp, proj_b, xo4, xtC0);
  }
  // E. conv1 via MFMA -> XTC1 (+guards)
  {
    dim3 g(N_ / 16, 4, 4);
    k_fmma<2><<<g, 64, 0, stream>>>(xtC0, wbc1, c2b1,
        c2bn1_g, c2bn1_b, c2bn1_m, c2bn1_v, nullptr, xtC1, nullptr);
  }
  // F. conv2 via MFMA (+resid) -> o2
  {
    dim3 g(N_ / 16, 4, 4);
    k_fmma<3><<<g, 64, 0, stream>>>(xtC1, wbc2, c2b2,
        c2bn2_g, c2bn2_b, c2bn2_m, c2bn2_v, xo4, nullptr, o2);
  }
  // G. cat + bn2 -> cat + XTF1 (+ XTF1/XTF2 guards)
  k_catbn<<<576, 256, 0, stream>>>(o2, bn2_g, bn2_b, bn2_m, bn2_v,
                                   cat, xtF1, xtF2);
  // H. f-branch via MFMA tap-GEMMs
  {
    dim3 g(N_ / 16, 8, B_);
    k_fmma<0><<<g, 64, 0, stream>>>(xtF1, wbf1, nullptr,
        fbn1_g, fbn1_b, fbn1_m, fbn1_v, nullptr, xtF2, nullptr);
    k_fmma<0><<<g, 64, 0, stream>>>(xtF2, wbf2, nullptr,
        fbn2_g, fbn2_b, fbn2_m, fbn2_v, nullptr, xt3, nullptr);
  }
  // I. f3 1x1 + cat -> out
  {
    dim3 g(N_ / 16, 8, B_);
    k_f3mma<<<g, 64, 0, stream>>>(xt3, wb3, f3b, cat, (float*)d_out);
  }
}

// Round 18
// 294.701 us; speedup vs baseline: 1.9178x; 1.0082x over previous
//
#include <hip/hip_runtime.h>
#include <hip/hip_bf16.h>

#define B_   2
#define C_   64
#define H_   48
#define W_   48
#define N_   (H_*W_)     // 2304
#define NH_  8
#define HD_  8
#define EPS_ 1e-5f
#define S2_  0.125f      // scale^2 = 1/hd
#define LOG2E_ 1.44269504f
#define FS_  (S2_ * LOG2E_)
#define S_   ((size_t)B_ * C_ * N_)   // 294912 floats per workspace slot
#define CN_  ((size_t)C_ * N_)        // 147456 floats per image
#define XTSZ_ ((size_t)(N_ + 2 * W_) * 128)  // bf16 elems per 128-ch image
#define XTSC_ ((size_t)(N_ + 2 * W_) * 64)   // bf16 elems per 64-ch image
#define PREB_ (B_ * N_ / 16)                 // 288 pre blocks
#define AWV_ 4                               // attn waves per block

typedef unsigned short u16;
typedef __attribute__((ext_vector_type(8))) short short8v;
typedef __attribute__((ext_vector_type(4))) float f32x4;
union F8 { uint4 u4; short8v s; unsigned int w[4]; };

__device__ __forceinline__ float wsum64(float v) {
#pragma unroll
  for (int o = 32; o > 0; o >>= 1) v += __shfl_xor(v, o, 64);
  return v;
}

__device__ __forceinline__ float ln_val(float t, float g, float b) {
  float mu  = wsum64(t) * (1.0f / 64.0f);
  float d   = t - mu;
  float var = wsum64(d * d) * (1.0f / 64.0f);
  return d * rsqrtf(var + EPS_) * g + b;
}

// round-to-nearest-even f32 -> bf16 (finite inputs only)
__device__ __forceinline__ u16 f2bf(float x) {
  union { float f; unsigned int u; } a; a.f = x;
  unsigned int r = a.u + 0x7fffu + ((a.u >> 16) & 1u);
  return (u16)(r >> 16);
}

// ---- fused 1x1 pconv + BN + 3x LN (blocks < PREB_) + weight cvt (rest) ---
// grid 288+380, block 1024.
__global__ __launch_bounds__(1024) void k_pre(
    const float* __restrict__ x, const float* __restrict__ y,
    const float* __restrict__ pw, const float* __restrict__ pb,
    const float* g, const float* bb, const float* m, const float* v,
    const float* lnxg, const float* lnxb,
    const float* lnyg, const float* lnyb,
    const float* lnzg, const float* lnzb,
    float* __restrict__ xl, float* __restrict__ yl, float* __restrict__ zl,
    const float* __restrict__ w1, const float* __restrict__ w2,
    const float* __restrict__ cw1, const float* __restrict__ cw2,
    const float* __restrict__ w3, const float* __restrict__ pjw,
    u16* __restrict__ wbo) {
  __shared__ float4 pwT[32][64];           // pwT[i4][c] = pw[c][4*i4..+3]
  __shared__ float xs[16][64], ys[16][64];
  if (blockIdx.x >= PREB_) {
    // ---- weight conversion path (no LDS, no syncthreads) ----
    int idx = (blockIdx.x - PREB_) * 1024 + threadIdx.x;
    if (idx >= 389120) return;
    if (idx < 294912) {
      int layer = idx / 147456, rem = idx - layer * 147456;
      int t = rem / 16384, r2 = rem - t * 16384;
      int co = r2 >> 7, ci = r2 & 127;
      wbo[idx] = f2bf((layer ? w2 : w1)[(size_t)co * 1152 + ci * 9 + t]);
    } else if (idx < 368640) {
      int k = idx - 294912;
      int layer = k / 36864, rem = k - layer * 36864;
      int t = rem / 4096, r2 = rem - t * 4096;
      int co = r2 >> 6, ci = r2 & 63;
      wbo[idx] = f2bf((layer ? cw2 : cw1)[(size_t)co * 576 + ci * 9 + t]);
    } else if (idx < 385024) {
      wbo[idx] = f2bf(w3[idx - 368640]);    // [cout][ci] identity
    } else {
      wbo[idx] = f2bf(pjw[idx - 385024]);   // [cout][ci] identity
    }
    return;
  }
  int w = threadIdx.x >> 6, c = threadIdx.x & 63;
  for (int idx = threadIdx.x; idx < 2048; idx += 1024) {
    int cc = idx & 63, i4 = idx >> 6;
    pwT[i4][cc] = *(const float4*)(pw + (size_t)cc * 2 * C_ + i4 * 4);
  }
  int row = blockIdx.x * 16 + w;           // b*N + n
  int b = row / N_, n = row % N_;
  float xv = x[(size_t)(b * C_ + c) * N_ + n];
  float yv = y[(size_t)(b * C_ + c) * N_ + n];
  xs[w][c] = xv; ys[w][c] = yv;
  __syncthreads();
  const float4* xw = (const float4*)xs[w];
  const float4* yw = (const float4*)ys[w];
  float acc = pb[c];
#pragma unroll
  for (int t = 0; t < 16; ++t) {
    float4 a = xw[t], wv = pwT[t][c];
    acc += a.x * wv.x + a.y * wv.y + a.z * wv.z + a.w * wv.w;
  }
#pragma unroll
  for (int t = 0; t < 16; ++t) {
    float4 a = yw[t], wv = pwT[16 + t][c];
    acc += a.x * wv.x + a.y * wv.y + a.z * wv.z + a.w * wv.w;
  }
  float s  = g[c] * rsqrtf(v[c] + EPS_);
  float sh = bb[c] - m[c] * s;
  float tx = xv * s + sh;
  xl[(size_t)row * C_ + c] = ln_val(tx, lnxg[c], lnxb[c]);
  float ty = yv * s + sh;
  yl[(size_t)row * C_ + c] = ln_val(ty, lnyg[c], lnyb[c]);
  float tz = acc * s + sh;
  zl[(size_t)row * C_ + c] = ln_val(tz, lnzg[c], lnzb[c]);
}

// ------------- qv/k projection v2: lane = row, uniform weights ------------
__global__ __launch_bounds__(64) void k_qvk(
    const float* __restrict__ xl, const float* __restrict__ yl,
    const float* __restrict__ zl,
    const float* __restrict__ qvw, const float* __restrict__ qvb,
    const float* __restrict__ kw, const float* __restrict__ kb,
    u16* __restrict__ qxb, u16* __restrict__ qyb,
    u16* __restrict__ kbf, u16* __restrict__ vt) {
  int l = threadIdx.x;
  int part = blockIdx.y >> 2;
  int j0 = (blockIdx.y & 3) * 16;
  int row = blockIdx.x * 64 + l;
  int b = row / N_, n = row % N_;
  const float* inp = (part < 2) ? xl : (part < 4) ? yl : zl;
  float4 in[16];
  const float4* ir = (const float4*)(inp + (size_t)row * C_);
#pragma unroll
  for (int t = 0; t < 16; ++t) in[t] = ir[t];

  const float* wb   = (part == 4) ? kw : qvw;
  const float* bias = (part == 4) ? kb : qvb;
  int joff = (part == 1 || part == 3) ? 64 : 0;

  if (part == 1 || part == 3) {
    int vbase = (part == 1) ? 0 : 8;
#pragma unroll
    for (int jj = 0; jj < 16; ++jj) {
      int j = j0 + jj;
      const float4* wr = (const float4*)(wb + (size_t)(joff + j) * C_);
      float acc = bias[joff + j];
#pragma unroll
      for (int t = 0; t < 16; ++t) {
        float4 a = in[t], wv = wr[t];
        acc += a.x * wv.x + a.y * wv.y + a.z * wv.z + a.w * wv.w;
      }
      int h = j >> 3, d = j & 7;
      vt[((size_t)((b * NH_ + h) * 16 + vbase + d)) * N_ + n] = f2bf(acc);
    }
  } else {
    u16* dst = (part == 0) ? qxb : (part == 2) ? qyb : kbf;
#pragma unroll
    for (int gg = 0; gg < 2; ++gg) {
      int h = (j0 >> 3) + gg;
      union { uint4 u4; u16 s[8]; } pk;
#pragma unroll
      for (int d = 0; d < 8; ++d) {
        int j = h * 8 + d;
        const float4* wr = (const float4*)(wb + (size_t)(joff + j) * C_);
        float acc = bias[joff + j];
#pragma unroll
        for (int t = 0; t < 16; ++t) {
          float4 a = in[t], wv = wr[t];
          acc += a.x * wv.x + a.y * wv.y + a.z * wv.z + a.w * wv.w;
        }
        if (part == 0) acc *= FS_;
        pk.s[d] = f2bf(acc);
      }
      *(uint4*)(dst + ((size_t)(b * NH_ + h) * N_ + n) * 8) = pk.u4;
    }
  }
}

// ---- attention v9: 4 waves/block, unroll-2 dbuf regs, bf16 att out -------
#define ATT_CHUNK(KA, KB, VF, ACC)                                          \
  {                                                                         \
    f32x4 s1a = __builtin_amdgcn_mfma_f32_16x16x32_bf16(KA.s, qxf.s, z4, 0, 0, 0); \
    f32x4 s2a = __builtin_amdgcn_mfma_f32_16x16x32_bf16(KA.s, qyf.s, z4, 0, 0, 0); \
    f32x4 s1b = __builtin_amdgcn_mfma_f32_16x16x32_bf16(KB.s, qxf.s, z4, 0, 0, 0); \
    f32x4 s2b = __builtin_amdgcn_mfma_f32_16x16x32_bf16(KB.s, qyf.s, z4, 0, 0, 0); \
    float p00 = exp2f(s1a[0] * s2a[0]), p01 = exp2f(s1a[1] * s2a[1]);       \
    float p02 = exp2f(s1a[2] * s2a[2]), p03 = exp2f(s1a[3] * s2a[3]);       \
    float p10 = exp2f(s1b[0] * s2b[0]), p11 = exp2f(s1b[1] * s2b[1]);       \
    float p12 = exp2f(s1b[2] * s2b[2]), p13 = exp2f(s1b[3] * s2b[3]);       \
    lsum += ((p00 + p01) + (p02 + p03)) + ((p10 + p11) + (p12 + p13));      \
    unsigned int pk00, pk10, pk01, pk11;                                    \
    asm("v_cvt_pk_bf16_f32 %0, %1, %2" : "=v"(pk00) : "v"(p00), "v"(p01));  \
    asm("v_cvt_pk_bf16_f32 %0, %1, %2" : "=v"(pk10) : "v"(p02), "v"(p03));  \
    asm("v_cvt_pk_bf16_f32 %0, %1, %2" : "=v"(pk01) : "v"(p10), "v"(p11));  \
    asm("v_cvt_pk_bf16_f32 %0, %1, %2" : "=v"(pk11) : "v"(p12), "v"(p13));  \
    int b00 = __builtin_amdgcn_ds_bpermute(addr0, (int)pk00);               \
    int b01 = __builtin_amdgcn_ds_bpermute(addr0, (int)pk01);               \
    int b10 = __builtin_amdgcn_ds_bpermute(addr0, (int)pk10);               \
    int b11 = __builtin_amdgcn_ds_bpermute(addr0, (int)pk11);               \
    int c00 = __builtin_amdgcn_ds_bpermute(addr1, (int)pk00);               \
    int c01 = __builtin_amdgcn_ds_bpermute(addr1, (int)pk01);               \
    int c10 = __builtin_amdgcn_ds_bpermute(addr1, (int)pk10);               \
    int c11 = __builtin_amdgcn_ds_bpermute(addr1, (int)pk11);               \
    F8 pf;                                                                  \
    pf.w[0] = (unsigned int)(thi ? b01 : b00);                              \
    pf.w[1] = (unsigned int)(thi ? b11 : b10);                              \
    pf.w[2] = (unsigned int)(thi ? c01 : c00);                              \
    pf.w[3] = (unsigned int)(thi ? c11 : c10);                              \
    ACC = __builtin_amdgcn_mfma_f32_16x16x32_bf16(pf.s, VF.s, ACC, 0, 0, 0);\
  }

__global__ __launch_bounds__(256, 4) void k_attn9(
    const u16* __restrict__ qx, const u16* __restrict__ qy,
    const u16* __restrict__ kk, const u16* __restrict__ vt,
    u16* __restrict__ outx, u16* __restrict__ outy) {
  __shared__ float sAcc[AWV_][4][64];
  __shared__ float sL[AWV_][16];
  int qt = blockIdx.x, bh = blockIdx.y;
  int tid = threadIdx.x;
  int lane = tid & 63;
  int wave = tid >> 6;
  int l15 = lane & 15;
  int q0 = qt * 16;

  F8 qxf, qyf;
  size_t qoff = ((size_t)bh * N_ + q0 + l15) * 8;
  qxf.u4 = *(const uint4*)(qx + qoff);
  qyf.u4 = *(const uint4*)(qy + qoff);
  if (lane >= 16) {
    qxf.u4 = make_uint4(0u, 0u, 0u, 0u);
    qyf.u4 = make_uint4(0u, 0u, 0u, 0u);
  }

  int key0 = wave * (N_ / AWV_);           // 576 keys per wave
  const uint4* kp = (const uint4*)(kk + (size_t)bh * N_ * 8) + key0 + l15;
  const uint4* vp = (const uint4*)(vt + ((size_t)bh * 16 + l15) * N_ + key0)
                    + (lane >> 4);
  int addr0 = (((lane >> 4) & 1) * 32 + l15) * 4;
  int addr1 = addr0 + 64;
  int thi = lane >> 5;

  f32x4 acc0 = {0.f, 0.f, 0.f, 0.f};
  f32x4 acc1 = {0.f, 0.f, 0.f, 0.f};
  const f32x4 z4 = {0.f, 0.f, 0.f, 0.f};
  float lsum = 0.f;

  // register double-buffer: set0 = even chunk, set1 = odd chunk
  F8 ka0, kb0, vf0, ka1, kb1, vf1;
  ka0.u4 = kp[0];  kb0.u4 = kp[16]; vf0.u4 = vp[0];
  ka1.u4 = kp[32]; kb1.u4 = kp[48]; vf1.u4 = vp[4];
  for (int c = 0; c < N_ / AWV_ / 32; c += 2) {   // 18 chunks, 9 iters
    ATT_CHUNK(ka0, kb0, vf0, acc0);
    ka0.u4 = kp[64]; kb0.u4 = kp[80]; vf0.u4 = vp[8];   // load chunk c+2
    ATT_CHUNK(ka1, kb1, vf1, acc1);
    kp += 64; vp += 8;
    ka1.u4 = kp[32]; kb1.u4 = kp[48]; vf1.u4 = vp[4];   // load chunk c+3
  }
  f32x4 acc = acc0 + acc1;

  lsum += __shfl_xor(lsum, 16, 64);
  lsum += __shfl_xor(lsum, 32, 64);
  if (lane < 16) sL[wave][lane] = lsum;
#pragma unroll
  for (int r = 0; r < 4; ++r) sAcc[wave][r][lane] = acc[r];
  __syncthreads();
  if (wave == 0) {
    float L = 0.f;
#pragma unroll
    for (int w2 = 0; w2 < AWV_; ++w2) L += sL[w2][l15];
    float Linv = 1.f / L;
    int b = bh >> 3, h = bh & 7;
    int d = l15 & 7;
    u16* ob = (l15 < 8) ? outx : outy;
    size_t cbase = (size_t)b * N_ * C_ + (size_t)h * 8 + d;
#pragma unroll
    for (int r = 0; r < 4; ++r) {
      int qrow = 4 * (lane >> 4) + r;
      float li = __shfl(Linv, qrow, 64);
      float a = 0.f;
#pragma unroll
      for (int w2 = 0; w2 < AWV_; ++w2) a += sAcc[w2][r][lane];
      ob[cbase + (size_t)(q0 + qrow) * C_] = f2bf(a * li);
    }
  }
}

// -------- proj via MFMA: K=64; bnd-resid epilogue; zeroes XTC0 guards -----
// grid (N_/16, 4, 4), block 64. z = branch*2 + b.
__global__ __launch_bounds__(64) void k_projm(
    const u16* __restrict__ attx, const u16* __restrict__ atty,
    const float* __restrict__ x, const float* __restrict__ y,
    const float* bg, const float* bb2, const float* bm, const float* bv,
    const u16* __restrict__ pwb, const float* __restrict__ pbias,
    float* __restrict__ xo4, u16* __restrict__ xt0) {
  if (blockIdx.x == 0) {   // 16 blocks x 64 thr zero XTC0 guard rows
    int tg = (blockIdx.z * 4 + blockIdx.y) * 64 + threadIdx.x;
#pragma unroll
    for (int i = tg; i < 12288; i += 1024) {
      int img = i / 3072, r2 = i - img * 3072;
      int hi = r2 / 1536, o = r2 - hi * 1536;
      ((unsigned int*)(xt0 + (size_t)img * XTSC_
                       + (hi ? (size_t)(W_ + N_) * 64 : 0)))[o] = 0u;
    }
  }
  int l = threadIdx.x;
  int c = l & 15, gg = l >> 4;
  int px0 = blockIdx.x * 16;
  int ct0 = blockIdx.y * 16;
  int z = blockIdx.z;
  int branch = z >> 1, b = z & 1;
  const u16* att = (branch ? atty : attx) + (size_t)b * N_ * 64;
  const u16* aw = pwb + (size_t)(ct0 + c) * 64 + gg * 8;
  const f32x4 z4 = {0.f, 0.f, 0.f, 0.f};
  f32x4 acc0, acc1;
  {
    F8 af, bf;
    af.u4 = *(const uint4*)(aw);
    bf.u4 = *(const uint4*)(att + (size_t)(px0 + c) * 64 + gg * 8);
    acc0 = __builtin_amdgcn_mfma_f32_16x16x32_bf16(af.s, bf.s, z4, 0, 0, 0);
  }
  {
    F8 af, bf;
    af.u4 = *(const uint4*)(aw + 32);
    bf.u4 = *(const uint4*)(att + (size_t)(px0 + c) * 64 + 32 + gg * 8);
    acc1 = __builtin_amdgcn_mfma_f32_16x16x32_bf16(af.s, bf.s, z4, 0, 0, 0);
  }
  f32x4 acc = acc0 + acc1;
  int px = px0 + c;
  const float* xin = branch ? y : x;
#pragma unroll
  for (int r = 0; r < 4; ++r) {
    int cout = ct0 + 4 * gg + r;
    float s  = bg[cout] * rsqrtf(bv[cout] + EPS_);
    float sh = bb2[cout] - bm[cout] * s;
    float rr = xin[((size_t)b * C_ + cout) * N_ + px];
    float vv = acc[r] + pbias[cout] + rr * s + sh;
    xo4[(size_t)z * CN_ + (size_t)cout * N_ + px] = vv;
    xt0[(size_t)z * XTSC_ + (size_t)(W_ + px) * 64 + cout] = f2bf(vv);
  }
}

// ------ cat + bn2 -> cat(fp32), XTf1 bf16; zero XTF1+XTF2 guards ----------
__global__ void k_catbn(const float* __restrict__ o2,
                        const float* __restrict__ g, const float* __restrict__ b2,
                        const float* __restrict__ m, const float* __restrict__ v,
                        float* __restrict__ cat, u16* __restrict__ xt1,
                        u16* __restrict__ xtf2) {
  int t = blockIdx.x * 256 + threadIdx.x;
  if (t < 12288) {   // zero XTF2 guard rows (2 imgs x 2 guards x 3072 u32)
    int img = t / 6144, r2 = t - img * 6144;
    int hi = r2 / 3072, o = r2 - hi * 3072;
    ((unsigned int*)(xtf2 + (size_t)img * XTSZ_
                     + (hi ? (size_t)(W_ + N_) * 128 : 0)))[o] = 0u;
  } else if (t < 24576) {   // zero XTF1 guard rows (same geometry)
    int i = t - 12288;
    int img = i / 6144, r2 = i - img * 6144;
    int hi = r2 / 3072, o = r2 - hi * 3072;
    ((unsigned int*)(xt1 + (size_t)img * XTSZ_
                     + (hi ? (size_t)(W_ + N_) * 128 : 0)))[o] = 0u;
  }
  int p4 = t * 4;
  int n  = p4 % N_;
  int c2 = (p4 / N_) % (2 * C_);
  int b  = p4 / (2 * C_ * N_);
  int c  = c2 & 63;
  float4 X = *(const float4*)(o2 + (size_t)b * CN_ + (size_t)c * N_ + n);
  float4 Y = *(const float4*)(o2 + (size_t)(2 + b) * CN_ + (size_t)c * N_ + n);
  float4 val;
  if (c2 < C_) val = make_float4(X.x + Y.x, X.y + Y.y, X.z + Y.z, X.w + Y.w);
  else         val = make_float4(X.x * Y.x, X.y * Y.y, X.z * Y.z, X.w * Y.w);
  size_t co = ((size_t)b * 2 * C_ + c2) * N_ + n;
  *(float4*)(cat + co) = val;
  float s  = g[c2] * rsqrtf(v[c2] + EPS_);
  float sh = b2[c2] - m[c2] * s;
  u16* xb = xt1 + (size_t)b * XTSZ_ + (size_t)(W_ + n) * 128 + c2;
  xb[0]   = f2bf(val.x * s + sh);
  xb[128] = f2bf(val.y * s + sh);
  xb[256] = f2bf(val.z * s + sh);
  xb[384] = f2bf(val.w * s + sh);
}

// ===== conv as 9 tap-GEMMs on MFMA, dual accumulator chains ===============
// MODE 0: 128ci, bn+relu -> bf16 XT out 128ch (used for f1 AND f2)
// MODE 2: c2 conv1 (64ci, +bias, bn, relu -> bf16 XT out 64ch; zeroes
//         guards of its own output for the next fmma<3> pass)
// MODE 3: c2 conv2 (64ci, +bias, bn, relu, +resid -> fp32 [img][cout][px])
template<int MODE>
__global__ __launch_bounds__(64) void k_fmma(
    const u16* __restrict__ xt, const u16* __restrict__ wb,
    const float* __restrict__ cbias,
    const float* g, const float* b2, const float* m, const float* v,
    const float* __restrict__ resid,
    u16* __restrict__ xto, float* __restrict__ fo) {
  constexpr int CIN  = (MODE >= 2) ? 64 : 128;
  constexpr int NCB  = CIN / 32;
  constexpr int COUT = (MODE >= 2) ? 64 : 128;
  constexpr int TS   = CIN * COUT;
  constexpr size_t XTS = (size_t)(N_ + 2 * W_) * CIN;
  constexpr size_t XTSO = (size_t)(N_ + 2 * W_) * COUT;
  if (MODE == 2 && blockIdx.x == 0) {  // zero XTC1 guards for fmma<3>
    int tg = (blockIdx.z * 4 + blockIdx.y) * 64 + threadIdx.x;
#pragma unroll
    for (int i = tg; i < 12288; i += 1024) {
      int img = i / 3072, r2 = i - img * 3072;
      int hi = r2 / 1536, o = r2 - hi * 1536;
      ((unsigned int*)(xto + (size_t)img * XTSO
                       + (hi ? (size_t)(W_ + N_) * COUT : 0)))[o] = 0u;
    }
  }
  int l = threadIdx.x;
  int c = l & 15, gg = l >> 4;
  int px0 = blockIdx.x * 16;
  int ct0 = blockIdx.y * 16;
  int b = blockIdx.z;
  int x0 = px0 % W_;                       // 0, 16, or 32
  bool mL = (x0 == 0) && (c == 0);
  bool mR = (x0 == 32) && (c == 15);
  const u16* xb = xt + (size_t)b * XTS + (size_t)W_ * CIN;
  const u16* aw = wb + (size_t)(ct0 + c) * CIN + gg * 8;

  f32x4 acc0 = {0.f, 0.f, 0.f, 0.f};
  f32x4 acc1 = {0.f, 0.f, 0.f, 0.f};
#pragma unroll
  for (int cb = 0; cb < NCB; ++cb) {
#pragma unroll
    for (int t = 0; t < 9; ++t) {
      const int dx = t % 3 - 1, dy = t / 3 - 1;
      F8 af, bf;
      af.u4 = *(const uint4*)(aw + t * TS + cb * 32);
      int px = px0 + c + dx + dy * W_;
      px = max(px, -W_);                   // clamp into guard (no OOB)
      bf.u4 = *(const uint4*)(xb + (ptrdiff_t)px * CIN + cb * 32 + gg * 8);
      bool msk = (dx < 0 && mL) || (dx > 0 && mR);
      if (msk) bf.u4 = make_uint4(0u, 0u, 0u, 0u);
      if ((t ^ cb) & 1)
        acc1 = __builtin_amdgcn_mfma_f32_16x16x32_bf16(af.s, bf.s, acc1, 0, 0, 0);
      else
        acc0 = __builtin_amdgcn_mfma_f32_16x16x32_bf16(af.s, bf.s, acc0, 0, 0, 0);
    }
  }
  f32x4 acc = acc0 + acc1;
  int px = px0 + c;
  if (MODE == 0 || MODE == 2) {
    union { ushort4 u; u16 s[4]; } pk;
#pragma unroll
    for (int r = 0; r < 4; ++r) {
      int cout = ct0 + 4 * gg + r;
      float a = acc[r] + (MODE == 2 ? cbias[cout] : 0.f);
      float s = g[cout] * rsqrtf(v[cout] + EPS_);
      float sh = b2[cout] - m[cout] * s;
      pk.s[r] = f2bf(fmaxf(a * s + sh, 0.f));
    }
    *(ushort4*)(xto + (size_t)b * XTSO + (size_t)(W_ + px) * COUT
                + ct0 + 4 * gg) = pk.u;
  } else {  // MODE 3
#pragma unroll
    for (int r = 0; r < 4; ++r) {
      int cout = ct0 + 4 * gg + r;
      float a = acc[r] + cbias[cout];
      float s = g[cout] * rsqrtf(v[cout] + EPS_);
      float sh = b2[cout] - m[cout] * s;
      size_t off = (size_t)b * CN_ + (size_t)cout * N_ + px;
      fo[off] = fmaxf(a * s + sh, 0.f) + resid[off];
    }
  }
}

// -------- f3 1x1 conv via MFMA: K=128, dual chains, +f3b + cat -> out -----
// grid (N_/16, 8, B_), block 64.
__global__ __launch_bounds__(64) void k_f3mma(
    const u16* __restrict__ xt3, const u16* __restrict__ w3b,
    const float* __restrict__ f3b, const float* __restrict__ cat,
    float* __restrict__ out) {
  int l = threadIdx.x;
  int c = l & 15, gg = l >> 4;
  int px0 = blockIdx.x * 16;
  int ct0 = blockIdx.y * 16;
  int b = blockIdx.z;
  const u16* xb = xt3 + (size_t)b * XTSZ_ + (size_t)W_ * 128;
  const u16* aw = w3b + (size_t)(ct0 + c) * 128 + gg * 8;
  f32x4 acc0 = {0.f, 0.f, 0.f, 0.f};
  f32x4 acc1 = {0.f, 0.f, 0.f, 0.f};
#pragma unroll
  for (int cb = 0; cb < 4; ++cb) {
    F8 af, bf;
    af.u4 = *(const uint4*)(aw + cb * 32);
    bf.u4 = *(const uint4*)(xb + (size_t)(px0 + c) * 128 + cb * 32 + gg * 8);
    if (cb & 1)
      acc1 = __builtin_amdgcn_mfma_f32_16x16x32_bf16(af.s, bf.s, acc1, 0, 0, 0);
    else
      acc0 = __builtin_amdgcn_mfma_f32_16x16x32_bf16(af.s, bf.s, acc0, 0, 0, 0);
  }
  f32x4 acc = acc0 + acc1;
  int px = px0 + c;
#pragma unroll
  for (int r = 0; r < 4; ++r) {
    int cout = ct0 + 4 * gg + r;
    size_t off = ((size_t)b * 2 * C_ + cout) * N_ + px;
    out[off] = acc[r] + f3b[cout] + cat[off];
  }
}

extern "C" void kernel_launch(void* const* d_in, const int* in_sizes, int n_in,
                              void* d_out, int out_size, void* d_ws, size_t ws_size,
                              hipStream_t stream) {
  const float* x       = (const float*)d_in[0];
  const float* y       = (const float*)d_in[1];
  const float* pconv_w = (const float*)d_in[2];
  const float* pconv_b = (const float*)d_in[3];
  const float* bnd_g = (const float*)d_in[4];
  const float* bnd_b = (const float*)d_in[5];
  const float* bnd_m = (const float*)d_in[6];
  const float* bnd_v = (const float*)d_in[7];
  const float* lnx_g = (const float*)d_in[8];
  const float* lnx_b = (const float*)d_in[9];
  const float* lny_g = (const float*)d_in[10];
  const float* lny_b = (const float*)d_in[11];
  const float* lnz_g = (const float*)d_in[12];
  const float* lnz_b = (const float*)d_in[13];
  const float* k_w   = (const float*)d_in[14];
  const float* k_b   = (const float*)d_in[15];
  const float* qv_w  = (const float*)d_in[16];
  const float* qv_b  = (const float*)d_in[17];
  const float* proj_w = (const float*)d_in[18];
  const float* proj_b = (const float*)d_in[19];
  const float* c2w1  = (const float*)d_in[20];
  const float* c2b1  = (const float*)d_in[21];
  const float* c2bn1_g = (const float*)d_in[22];
  const float* c2bn1_b = (const float*)d_in[23];
  const float* c2bn1_m = (const float*)d_in[24];
  const float* c2bn1_v = (const float*)d_in[25];
  const float* c2w2  = (const float*)d_in[26];
  const float* c2b2  = (const float*)d_in[27];
  const float* c2bn2_g = (const float*)d_in[28];
  const float* c2bn2_b = (const float*)d_in[29];
  const float* c2bn2_m = (const float*)d_in[30];
  const float* c2bn2_v = (const float*)d_in[31];
  const float* bn2_g = (const float*)d_in[32];
  const float* bn2_b = (const float*)d_in[33];
  const float* bn2_m = (const float*)d_in[34];
  const float* bn2_v = (const float*)d_in[35];
  const float* f1w   = (const float*)d_in[36];
  const float* fbn1_g = (const float*)d_in[37];
  const float* fbn1_b = (const float*)d_in[38];
  const float* fbn1_m = (const float*)d_in[39];
  const float* fbn1_v = (const float*)d_in[40];
  const float* f2w   = (const float*)d_in[41];
  const float* fbn2_g = (const float*)d_in[42];
  const float* fbn2_b = (const float*)d_in[43];
  const float* fbn2_m = (const float*)d_in[44];
  const float* fbn2_v = (const float*)d_in[45];
  const float* f3w   = (const float*)d_in[46];
  const float* f3b   = (const float*)d_in[47];

  // Workspace plan (floats; slot = S_):
  //   A: k_pre (+wcvt tail blocks) -> xl(1) yl(2) zl(3); wb @ [7, 7.67)
  //   B: qvk -> qx[4,4.5) qy[4.5,5) kbf[5,5.5) vt[6,7)
  //   C: attn9 -> attx bf16 [1,1.5), atty [1.5,2)
  //   D: projm -> xo4 fp32 [3,5) + XTC0 bf16 [5,6.05) (+XTC0 guards)
  //   E: fmma<2>: XTC0 -> XTC1 [0,1.05) (+XTC1 guards)
  //   F: fmma<3>: XTC1 + xo4 -> o2 [5,7)
  //   G: catbn: o2 -> cat [3,5) + XTF1 [1.25,2.30) (+XTF1/XTF2 guards)
  //   H1: fmma<0> f1 (fbn1): XTF1 -> XTF2 [0,1.05)
  //   H2: fmma<0> f2 (fbn2): XTF2 -> xt3 [1.25,2.30)
  //   I: f3mma: xt3 + cat -> out
  float* ws = (float*)d_ws;
  float* sl1 = ws + 1 * S_;
  float* sl2 = ws + 2 * S_;
  float* sl3 = ws + 3 * S_;
  u16* attx = (u16*)(ws + 1 * S_);
  u16* atty = attx + (size_t)B_ * N_ * 64;
  u16* xtC0 = (u16*)(ws + 5 * S_);
  u16* xtC1 = (u16*)ws;
  u16* xtF1 = (u16*)(ws + 5 * S_ / 4);
  u16* xtF2 = (u16*)ws;
  u16* xt3  = (u16*)(ws + 5 * S_ / 4);
  float* xo4 = ws + 3 * S_;
  float* o2  = ws + 5 * S_;
  float* cat = ws + 3 * S_;
  u16* wb   = (u16*)(ws + 7 * S_);
  u16* wbf1 = wb;
  u16* wbf2 = wb + 147456;
  u16* wbc1 = wb + 294912;
  u16* wbc2 = wb + 331776;
  u16* wb3  = wb + 368640;
  u16* wbp  = wb + 385024;

  // A. fused pconv + bn + ln (+ weight conversion tail blocks)
  k_pre<<<PREB_ + 380, 1024, 0, stream>>>(x, y, pconv_w, pconv_b,
                                    bnd_g, bnd_b, bnd_m, bnd_v,
                                    lnx_g, lnx_b, lny_g, lny_b, lnz_g, lnz_b,
                                    sl1, sl2, sl3,
                                    f1w, f2w, c2w1, c2w2, f3w, proj_w, wb);
  // B. qv/k projection
  u16* qxb = (u16*)(ws + 4 * S_);
  u16* qyb = qxb + (size_t)B_ * NH_ * N_ * 8;
  u16* kbf = (u16*)(ws + 5 * S_);
  u16* vtb = (u16*)(ws + 6 * S_);
  {
    dim3 g(B_ * N_ / 64, 20);
    k_qvk<<<g, 64, 0, stream>>>(sl1, sl2, sl3, qv_w, qv_b, k_w, k_b,
                                qxb, qyb, kbf, vtb);
  }
  // C. attention v9 (4 waves, unroll-2)
  {
    dim3 g(N_ / 16, B_ * NH_);
    k_attn9<<<g, 256, 0, stream>>>(qxb, qyb, kbf, vtb, attx, atty);
  }
  // D. proj via MFMA -> xo4 + XTC0 (+guards)
  {
    dim3 g(N_ / 16, 4, 4);
    k_projm<<<g, 64, 0, stream>>>(attx, atty, x, y,
                                  bnd_g, bnd_b, bnd_m, bnd_v,
                                  wbp, proj_b, xo4, xtC0);
  }
  // E. conv1 via MFMA -> XTC1 (+guards)
  {
    dim3 g(N_ / 16, 4, 4);
    k_fmma<2><<<g, 64, 0, stream>>>(xtC0, wbc1, c2b1,
        c2bn1_g, c2bn1_b, c2bn1_m, c2bn1_v, nullptr, xtC1, nullptr);
  }
  // F. conv2 via MFMA (+resid) -> o2
  {
    dim3 g(N_ / 16, 4, 4);
    k_fmma<3><<<g, 64, 0, stream>>>(xtC1, wbc2, c2b2,
        c2bn2_g, c2bn2_b, c2bn2_m, c2bn2_v, xo4, nullptr, o2);
  }
  // G. cat + bn2 -> cat + XTF1 (+ XTF1/XTF2 guards)
  k_catbn<<<576, 256, 0, stream>>>(o2, bn2_g, bn2_b, bn2_m, bn2_v,
                                   cat, xtF1, xtF2);
  // H. f-branch via MFMA tap-GEMMs
  {
    dim3 g(N_ / 16, 8, B_);
    k_fmma<0><<<g, 64, 0, stream>>>(xtF1, wbf1, nullptr,
        fbn1_g, fbn1_b, fbn1_m, fbn1_v, nullptr, xtF2, nullptr);
    k_fmma<0><<<g, 64, 0, stream>>>(xtF2, wbf2, nullptr,
        fbn2_g, fbn2_b, fbn2_m, fbn2_v, nullptr, xt3, nullptr);
  }
  // I. f3 1x1 + cat -> out
  {
    dim3 g(N_ / 16, 8, B_);
    k_f3mma<<<g, 64, 0, stream>>>(xt3, wb3, f3b, cat, (float*)d_out);
  }
}